// Round 1
// baseline (872.298 us; speedup 1.0000x reference)
//
#include <hip/hip_runtime.h>
#include <math.h>

// Wavelet scattering, T=16384, radix-4 in-LDS FFT pipelines.
// Chain per channel: spectral mul -> DIF-IFFT (scrambled) -> |.|/N -> DIT-FFT
// (natural) -> Gaussian lowpass via 256-bin frequency fold, downsample 256.

#define T_N   16384
#define NT    512          // threads per block (8 waves)
#define B_SZ  16
#define N1    64
#define NPAIR 224
#define FOLD_F 256         // phi is numerically zero past bin ~190 (sigma=22.4 bins)
#define USTRIDE 8208       // float2 row stride for half-spectrum (8193 used)
#define INV_N (1.0f/16384.0f)
#define TWO_PI 6.283185307179586f

__device__ __forceinline__ int pad(int i) { return i + (i >> 4); }  // LDS bank-conflict pad
__device__ __forceinline__ float2 f2add(float2 a, float2 b){ return make_float2(a.x+b.x, a.y+b.y); }
__device__ __forceinline__ float2 f2sub(float2 a, float2 b){ return make_float2(a.x-b.x, a.y-b.y); }
__device__ __forceinline__ float2 cmul_cs(float2 a, float c, float s){
  return make_float2(a.x*c - a.y*s, a.x*s + a.y*c);
}
// reverse 7 base-4 digits of a 14-bit index
__device__ __forceinline__ int rev4_14(int p){
  unsigned r = __brev((unsigned)p) >> 18;
  return (int)(((r & 0x2AAAu) >> 1) | ((r & 0x1555u) << 1));
}

// In-place radix-4 DIF stages, mbits = mb_hi down to mb_lo (step -2).
// sgn = +1: inverse transform (unnormalized), sgn = -1: forward.
// Natural-order input -> digit-reversed output (when run 12..0).
__device__ void dif_sweep(float2* d, int tid, float sgn, int mb_hi, int mb_lo)
{
  const float ang = sgn * (TWO_PI / (float)T_N);
  for (int mbits = mb_hi; mbits >= mb_lo; mbits -= 2) {
    const int M = 1 << mbits;
#pragma unroll 8
    for (int v = tid; v < T_N/4; v += NT) {
      const int j = v & (M-1);
      const int base = ((v >> mbits) << (mbits+2)) | j;
      const int i0 = pad(base), i1 = pad(base+M), i2 = pad(base+2*M), i3 = pad(base+3*M);
      float2 a0=d[i0], a1=d[i1], a2=d[i2], a3=d[i3];
      float2 t0=f2add(a0,a2), t1=f2sub(a0,a2), t2=f2add(a1,a3), t3=f2sub(a1,a3);
      float2 y0=f2add(t0,t2), y2=f2sub(t0,t2);
      float2 y1=make_float2(t1.x - sgn*t3.y, t1.y + sgn*t3.x);   // t1 + sgn*i*t3
      float2 y3=make_float2(t1.x + sgn*t3.y, t1.y - sgn*t3.x);
      float s1,c1;
      __sincosf(ang * (float)(j << (12-mbits)), &s1, &c1);       // W^j
      float c2=c1*c1-s1*s1, s2=2.f*c1*s1;                        // W^2j
      float c3=c1*c2-s1*s2, s3=c1*s2+s1*c2;                      // W^3j
      d[i0]=y0;
      d[i1]=cmul_cs(y1,c1,s1);
      d[i2]=cmul_cs(y2,c2,s2);
      d[i3]=cmul_cs(y3,c3,s3);
    }
    __syncthreads();
  }
}

// In-place radix-4 DIT stages, mbits = mb_lo up to mb_hi (step +2).
// Digit-reversed input -> natural output (when run 0..12). Twiddle-before-combine.
__device__ void dit_sweep(float2* d, int tid, float sgn, int mb_lo, int mb_hi)
{
  const float ang = sgn * (TWO_PI / (float)T_N);
  for (int mbits = mb_lo; mbits <= mb_hi; mbits += 2) {
    const int M = 1 << mbits;
#pragma unroll 8
    for (int v = tid; v < T_N/4; v += NT) {
      const int j = v & (M-1);
      const int base = ((v >> mbits) << (mbits+2)) | j;
      const int i0 = pad(base), i1 = pad(base+M), i2 = pad(base+2*M), i3 = pad(base+3*M);
      float2 a0=d[i0], a1=d[i1], a2=d[i2], a3=d[i3];
      float s1,c1;
      __sincosf(ang * (float)(j << (12-mbits)), &s1, &c1);
      float c2=c1*c1-s1*s1, s2=2.f*c1*s1;
      float c3=c1*c2-s1*s2, s3=c1*s2+s1*c2;
      a1 = cmul_cs(a1,c1,s1);
      a2 = cmul_cs(a2,c2,s2);
      a3 = cmul_cs(a3,c3,s3);
      float2 t0=f2add(a0,a2), t1=f2sub(a0,a2), t2=f2add(a1,a3), t3=f2sub(a1,a3);
      float2 y0=f2add(t0,t2), y2=f2sub(t0,t2);
      float2 y1=make_float2(t1.x - sgn*t3.y, t1.y + sgn*t3.x);
      float2 y3=make_float2(t1.x + sgn*t3.y, t1.y - sgn*t3.x);
      d[i0]=y0; d[i1]=y1; d[i2]=y2; d[i3]=y3;
    }
    __syncthreads();
  }
}

// Fused: last inverse-DIF stage (M=1, unit twiddles) + modulus*1/N +
// first forward-DIT stage (M=1, unit twiddles). Same 4 consecutive slots.
__device__ void fused_mid(float2* d, int tid)
{
#pragma unroll 8
  for (int v = tid; v < T_N/4; v += NT) {
    const int base = 4*v;
    const int i0 = pad(base), i1 = pad(base+1), i2 = pad(base+2), i3 = pad(base+3);
    float2 a0=d[i0], a1=d[i1], a2=d[i2], a3=d[i3];
    float2 t0=f2add(a0,a2), t1=f2sub(a0,a2), t2=f2add(a1,a3), t3=f2sub(a1,a3);
    // inverse butterfly (sgn=+1)
    float2 y0=f2add(t0,t2), y2=f2sub(t0,t2);
    float2 y1=make_float2(t1.x - t3.y, t1.y + t3.x);
    float2 y3=make_float2(t1.x + t3.y, t1.y - t3.x);
    float m0 = INV_N * sqrtf(y0.x*y0.x + y0.y*y0.y);
    float m1 = INV_N * sqrtf(y1.x*y1.x + y1.y*y1.y);
    float m2 = INV_N * sqrtf(y2.x*y2.x + y2.y*y2.y);
    float m3 = INV_N * sqrtf(y3.x*y3.x + y3.y*y3.y);
    // forward DIT M=1 butterfly on reals
    float p0=m0+m2, p1=m0-m2, p2=m1+m3, p3=m1-m3;
    d[i0]=make_float2(p0+p2, 0.f);
    d[i1]=make_float2(p1, -p3);
    d[i2]=make_float2(p0-p2, 0.f);
    d[i3]=make_float2(p1, p3);
  }
  __syncthreads();
}

// S[k] = (1/N) * Re sum_f spec[f]*phi[f]*e^{+2pi i f k/64}, Hermitian-doubled,
// phi support truncated to f < FOLD_F. 8 threads per output k.
__device__ void fold_store(const float2* d, const float* __restrict__ phi, float* outp, int tid)
{
  const int k = tid >> 3, g = tid & 7;
  float acc = 0.f;
  for (int f = g; f < FOLD_F; f += 8) {
    float2 u = d[pad(f)];
    float w = phi[f] * ((f == 0) ? 1.f : 2.f);
    float sv, cv;
    __sincosf((TWO_PI/64.f) * (float)((f*k) & 63), &sv, &cv);
    acc += w * (u.x*cv - u.y*sv);
  }
  acc += __shfl_xor(acc, 1);
  acc += __shfl_xor(acc, 2);
  acc += __shfl_xor(acc, 4);
  if (g == 0) outp[k] = acc * INV_N;
}

// K1: xh = FFT(x) (natural order, to ws) + S0 fold. 16 blocks.
__global__ void __launch_bounds__(NT) k_fft_x(const float* __restrict__ x, const float* __restrict__ phi,
                                              float2* __restrict__ xh, float* __restrict__ out)
{
  extern __shared__ float2 d[];
  const int tid = threadIdx.x;
  const int b = blockIdx.x;
  const float* xr = x + b * T_N;
  for (int i = tid; i < T_N; i += NT) d[pad(i)] = make_float2(xr[i], 0.f);
  __syncthreads();
  dif_sweep(d, tid, -1.f, 12, 0);      // forward FFT, digit-reversed result
  for (int p = tid; p < T_N; p += NT) { // unscramble in place (involution)
    int r = rev4_14(p);
    if (p < r) { int ip = pad(p), ir = pad(r); float2 t = d[ip]; d[ip] = d[ir]; d[ir] = t; }
  }
  __syncthreads();
  float2* xrow = xh + (size_t)b * T_N;
  for (int i = tid; i < T_N; i += NT) xrow[i] = d[pad(i)];
  fold_store(d, phi, out + b * 64, tid);   // S0
}

// K2: per (b,j1): Z = xh*psi1 -> IFFT -> |.| -> FFT -> store half-spectrum U1h + S1 fold.
__global__ void __launch_bounds__(NT) k_order1(const float2* __restrict__ xh, const float* __restrict__ psi1,
                                               const float* __restrict__ phi, float2* __restrict__ u1h,
                                               float* __restrict__ out)
{
  extern __shared__ float2 d[];
  const int tid = threadIdx.x;
  const int b = blockIdx.x >> 6, j1 = blockIdx.x & 63;
  const float2* xrow = xh + (size_t)b * T_N;
  const float* prow = psi1 + j1 * T_N;
  for (int i = tid; i < T_N; i += NT) {
    float2 v = xrow[i];
    float p = prow[i];
    d[pad(i)] = make_float2(v.x*p, v.y*p);
  }
  __syncthreads();
  dif_sweep(d, tid, +1.f, 12, 2);
  fused_mid(d, tid);
  dit_sweep(d, tid, -1.f, 2, 12);      // natural-order U1h in LDS
  float2* urow = u1h + (size_t)(b * N1 + j1) * USTRIDE;
  for (int i = tid; i <= T_N/2; i += NT) urow[i] = d[pad(i)];   // bins 0..8192
  fold_store(d, phi, out + 1024 + (size_t)(b * N1 + j1) * 64, tid);  // S1
}

// K4: per (b,pair): Z = U1h[j1]*psi2[j2] (Hermitian-extend) -> IFFT -> |.| -> FFT -> S2 fold.
__global__ void __launch_bounds__(NT) k_order2(const float2* __restrict__ u1h, const float* __restrict__ psi2,
                                               const float* __restrict__ phi, const int* __restrict__ pj1,
                                               const int* __restrict__ pj2, float* __restrict__ out)
{
  extern __shared__ float2 d[];
  const int tid = threadIdx.x;
  const int b = blockIdx.x / NPAIR, p = blockIdx.x % NPAIR;
  const int j1 = pj1[p], j2 = pj2[p];
  const float2* urow = u1h + (size_t)(b * N1 + j1) * USTRIDE;
  const float* prow = psi2 + j2 * T_N;
  for (int i = tid; i < T_N; i += NT) {
    float2 u;
    if (i <= T_N/2) u = urow[i];
    else { float2 t = urow[T_N - i]; u = make_float2(t.x, -t.y); }  // conj mirror
    float ps = prow[i];
    d[pad(i)] = make_float2(u.x*ps, u.y*ps);
  }
  __syncthreads();
  dif_sweep(d, tid, +1.f, 12, 2);
  fused_mid(d, tid);
  dit_sweep(d, tid, -1.f, 2, 12);
  fold_store(d, phi, out + 66560 + (size_t)(b * NPAIR + p) * 64, tid); // S2
}

extern "C" void kernel_launch(void* const* d_in, const int* in_sizes, int n_in,
                              void* d_out, int out_size, void* d_ws, size_t ws_size,
                              hipStream_t stream)
{
  const float* x    = (const float*)d_in[0];
  const float* psi1 = (const float*)d_in[1];
  const float* psi2 = (const float*)d_in[2];
  const float* phi  = (const float*)d_in[3];
  const int*   pj1  = (const int*)d_in[4];
  const int*   pj2  = (const int*)d_in[5];
  float* out = (float*)d_out;

  float2* xh  = (float2*)d_ws;                  // [16][16384] = 2 MB
  float2* u1h = xh + (size_t)B_SZ * T_N;        // [1024][USTRIDE] ~ 67 MB

  const size_t lds = (size_t)(T_N + (T_N >> 4)) * sizeof(float2);  // 139264 B

  // opt-in for >64KB dynamic LDS (no-op where not required; ignore errors)
  (void)hipFuncSetAttribute((const void*)k_fft_x,  hipFuncAttributeMaxDynamicSharedMemorySize, (int)lds);
  (void)hipFuncSetAttribute((const void*)k_order1, hipFuncAttributeMaxDynamicSharedMemorySize, (int)lds);
  (void)hipFuncSetAttribute((const void*)k_order2, hipFuncAttributeMaxDynamicSharedMemorySize, (int)lds);

  hipLaunchKernelGGL(k_fft_x,  dim3(B_SZ),         dim3(NT), lds, stream, x, phi, xh, out);
  hipLaunchKernelGGL(k_order1, dim3(B_SZ * N1),    dim3(NT), lds, stream, xh, psi1, phi, u1h, out);
  hipLaunchKernelGGL(k_order2, dim3(B_SZ * NPAIR), dim3(NT), lds, stream, u1h, psi2, phi, pj1, pj2, out);
}

// Round 2
// 542.444 us; speedup vs baseline: 1.6081x; 1.6081x over previous
//
#include <hip/hip_runtime.h>
#include <math.h>

// Wavelet scattering, T=16384. Register-blocked radix-32 in-LDS FFT:
// DIF(32,512) -> DIF(32,16) -> fused[DFT16+|.|/N+DFT16] -> DIT(32,16) -> DIT(32,512).
// 5 LDS sweeps per channel instead of 13 radix-4 stages.

#define T_N   16384
#define NT    512          // threads per block (8 waves); N/32 == NT
#define B_SZ  16
#define N1    64
#define NPAIR 224
#define FOLD_F 256         // phi numerically zero past bin ~190 (sigma=22.4 bins)
#define USTRIDE 8208       // float2 row stride for half-spectrum (8193 used)
#define INV_N (1.0f/16384.0f)
#define TWO_PI 6.283185307179586f

__device__ __forceinline__ int pad(int i) { return i + (i >> 4); }  // LDS pad
__device__ __forceinline__ float2 f2add(float2 a, float2 b){ return make_float2(a.x+b.x, a.y+b.y); }
__device__ __forceinline__ float2 f2sub(float2 a, float2 b){ return make_float2(a.x-b.x, a.y-b.y); }
__device__ __forceinline__ float2 cmul_cs(float2 a, float c, float s){
  return make_float2(a.x*c - a.y*s, a.x*s + a.y*c);
}
__device__ __forceinline__ constexpr int br5(int x){
  return ((x&1)<<4)|((x&2)<<2)|(x&4)|((x&8)>>2)|((x&16)>>4);
}
__device__ __forceinline__ constexpr int br4(int x){
  return ((x&1)<<3)|((x&2)<<1)|((x&4)>>1)|((x&8)>>3);
}
// reverse 7 base-4 digits of a 14-bit index (k_fft_x unscramble)
__device__ __forceinline__ int rev4_14(int p){
  unsigned r = __brev((unsigned)p) >> 18;
  return (int)(((r & 0x2AAAu) >> 1) | ((r & 0x1555u) << 1));
}

// Fully-unrolled in-register DFT of size 2^LOGN (LOGN<=5), sign SGN:
// y[r] = sum_k a[k] e^{SGN*2pi*i*rk/N}. Result y[r] lands at a[bitrev(r)].
template<int SGN, int LOGN>
__device__ __forceinline__ void dft_reg(float2* a){
  constexpr int N = 1 << LOGN;
  static constexpr float C16[16] = {
    1.f, 0.98078528f, 0.92387953f, 0.83146961f, 0.70710678f, 0.55557023f,
    0.38268343f, 0.19509032f, 0.f, -0.19509032f, -0.38268343f, -0.55557023f,
    -0.70710678f, -0.83146961f, -0.92387953f, -0.98078528f };
  static constexpr float S16[16] = {
    0.f, 0.19509032f, 0.38268343f, 0.55557023f, 0.70710678f, 0.83146961f,
    0.92387953f, 0.98078528f, 1.f, 0.98078528f, 0.92387953f, 0.83146961f,
    0.70710678f, 0.55557023f, 0.38268343f, 0.19509032f };
#pragma unroll
  for (int m = N/2; m >= 1; m >>= 1) {
#pragma unroll
    for (int base = 0; base < N; base += 2*m) {
#pragma unroll
      for (int j = 0; j < m; ++j) {
        float2 u = a[base+j], v = a[base+j+m];
        a[base+j] = f2add(u,v);
        float2 w = f2sub(u,v);
        const int ti = (j*16)/m;                 // angle = pi*j/m = pi*ti/16
        const float c = C16[ti];
        const float s = (float)SGN * S16[ti];
        a[base+j+m] = make_float2(w.x*c - w.y*s, w.x*s + w.y*c);
      }
    }
  }
}

// DIF super-stage radix-32 at stride M (M in {512,16}), one group per thread.
// a[k]=d[base+kM]; y[r]=DFT32(a); d[base+rM]=y[r]*e^{SGN*2pi*i*r*j/(32M)}.
template<int SGN, int M, int LOGM>
__device__ __forceinline__ void super_dif32(float2* d, int tid)
{
  const int j = tid & (M-1);
  const int base = ((tid >> LOGM) << (LOGM+5)) | j;
  float2* dp = d + pad(base);
  constexpr int PSTR = M + (M>>4);          // pad(base+kM)=pad(base)+k*PSTR (exact, M>=16)
  float2 a[32];
#pragma unroll
  for (int k = 0; k < 32; ++k) a[k] = dp[k*PSTR];
  dft_reg<SGN,5>(a);
  const float ang = (float)SGN * (TWO_PI / (float)(32*M)) * (float)j;
  dp[0] = a[0];
#pragma unroll
  for (int r = 1; r < 32; ++r) {
    float s,c; __sincosf(ang*(float)r, &s, &c);
    dp[r*PSTR] = cmul_cs(a[br5(r)], c, s);
  }
}

// DIT super-stage radix-32 at stride M (twiddle-before-combine).
template<int SGN, int M, int LOGM>
__device__ __forceinline__ void super_dit32(float2* d, int tid)
{
  const int j = tid & (M-1);
  const int base = ((tid >> LOGM) << (LOGM+5)) | j;
  float2* dp = d + pad(base);
  constexpr int PSTR = M + (M>>4);
  const float ang = (float)SGN * (TWO_PI / (float)(32*M)) * (float)j;
  float2 a[32];
  a[0] = dp[0];
#pragma unroll
  for (int k = 1; k < 32; ++k) {
    float s,c; __sincosf(ang*(float)k, &s, &c);
    a[k] = cmul_cs(dp[k*PSTR], c, s);
  }
  dft_reg<SGN,5>(a);
#pragma unroll
  for (int r = 0; r < 32; ++r) dp[r*PSTR] = a[br5(r)];
}

// Fused middle on one contiguous-16 group: inverse DFT16 (unit twiddles at M=1),
// modulus * 1/N, forward DFT16. pad(16v+i) = 17v+i.
__device__ __forceinline__ void fused_mid16(float2* d, int v)
{
  float2* dp = d + 17*v;
  float2 a[16];
#pragma unroll
  for (int i = 0; i < 16; ++i) a[i] = dp[i];
  dft_reg<+1,4>(a);                       // y[r] at a[br4(r)]
  float2 b[16];
#pragma unroll
  for (int r = 0; r < 16; ++r) {
    float2 y = a[br4(r)];
    b[r] = make_float2(INV_N * sqrtf(y.x*y.x + y.y*y.y), 0.f);
  }
  dft_reg<-1,4>(b);
#pragma unroll
  for (int r = 0; r < 16; ++r) dp[r] = b[br4(r)];
}

// Inverse(+modulus)+forward pipeline on natural-order LDS contents.
__device__ __forceinline__ void mod_pipeline(float2* d, int tid)
{
  super_dif32<+1, 512, 9>(d, tid);  __syncthreads();
  super_dif32<+1, 16, 4>(d, tid);   __syncthreads();
  fused_mid16(d, tid); fused_mid16(d, tid + NT); __syncthreads();
  super_dit32<-1, 16, 4>(d, tid);   __syncthreads();
  super_dit32<-1, 512, 9>(d, tid);  __syncthreads();
}

// S[k] = (1/N) * Re sum_f spec[f]*phi[f]*e^{+2pi i f k/64}, Hermitian-doubled,
// phi support truncated to f < FOLD_F. 8 threads per output k.
__device__ void fold_store(const float2* d, const float* __restrict__ phi, float* outp, int tid)
{
  const int k = tid >> 3, g = tid & 7;
  float acc = 0.f;
  for (int f = g; f < FOLD_F; f += 8) {
    float2 u = d[pad(f)];
    float w = phi[f] * ((f == 0) ? 1.f : 2.f);
    float sv, cv;
    __sincosf((TWO_PI/64.f) * (float)((f*k) & 63), &sv, &cv);
    acc += w * (u.x*cv - u.y*sv);
  }
  acc += __shfl_xor(acc, 1);
  acc += __shfl_xor(acc, 2);
  acc += __shfl_xor(acc, 4);
  if (g == 0) outp[k] = acc * INV_N;
}

// ---- radix-4 path kept only for k_fft_x (16 blocks, proven) ----
__device__ void dif_sweep(float2* d, int tid, float sgn, int mb_hi, int mb_lo)
{
  const float ang = sgn * (TWO_PI / (float)T_N);
  for (int mbits = mb_hi; mbits >= mb_lo; mbits -= 2) {
    const int M = 1 << mbits;
#pragma unroll 8
    for (int v = tid; v < T_N/4; v += NT) {
      const int j = v & (M-1);
      const int base = ((v >> mbits) << (mbits+2)) | j;
      const int i0 = pad(base), i1 = pad(base+M), i2 = pad(base+2*M), i3 = pad(base+3*M);
      float2 a0=d[i0], a1=d[i1], a2=d[i2], a3=d[i3];
      float2 t0=f2add(a0,a2), t1=f2sub(a0,a2), t2=f2add(a1,a3), t3=f2sub(a1,a3);
      float2 y0=f2add(t0,t2), y2=f2sub(t0,t2);
      float2 y1=make_float2(t1.x - sgn*t3.y, t1.y + sgn*t3.x);
      float2 y3=make_float2(t1.x + sgn*t3.y, t1.y - sgn*t3.x);
      float s1,c1;
      __sincosf(ang * (float)(j << (12-mbits)), &s1, &c1);
      float c2=c1*c1-s1*s1, s2=2.f*c1*s1;
      float c3=c1*c2-s1*s2, s3=c1*s2+s1*c2;
      d[i0]=y0;
      d[i1]=cmul_cs(y1,c1,s1);
      d[i2]=cmul_cs(y2,c2,s2);
      d[i3]=cmul_cs(y3,c3,s3);
    }
    __syncthreads();
  }
}

// K1: xh = FFT(x) (natural order, to ws) + S0 fold. 16 blocks.
__global__ void __launch_bounds__(NT) k_fft_x(const float* __restrict__ x, const float* __restrict__ phi,
                                              float2* __restrict__ xh, float* __restrict__ out)
{
  extern __shared__ float2 d[];
  const int tid = threadIdx.x;
  const int b = blockIdx.x;
  const float* xr = x + b * T_N;
  for (int i = tid; i < T_N; i += NT) d[pad(i)] = make_float2(xr[i], 0.f);
  __syncthreads();
  dif_sweep(d, tid, -1.f, 12, 0);      // forward FFT, digit-reversed result
  for (int p = tid; p < T_N; p += NT) { // unscramble in place (involution)
    int r = rev4_14(p);
    if (p < r) { int ip = pad(p), ir = pad(r); float2 t = d[ip]; d[ip] = d[ir]; d[ir] = t; }
  }
  __syncthreads();
  float2* xrow = xh + (size_t)b * T_N;
  for (int i = tid; i < T_N; i += NT) xrow[i] = d[pad(i)];
  fold_store(d, phi, out + b * 64, tid);   // S0
}

// K2: per (b,j1): Z = xh*psi1 -> IFFT -> |.| -> FFT -> store half-spectrum U1h + S1 fold.
__global__ void __launch_bounds__(NT) k_order1(const float2* __restrict__ xh, const float* __restrict__ psi1,
                                               const float* __restrict__ phi, float2* __restrict__ u1h,
                                               float* __restrict__ out)
{
  extern __shared__ float2 d[];
  const int tid = threadIdx.x;
  const int b = blockIdx.x >> 6, j1 = blockIdx.x & 63;
  const float2* xrow = xh + (size_t)b * T_N;
  const float* prow = psi1 + j1 * T_N;
#pragma unroll
  for (int s = 0; s < T_N/NT; ++s) {
    int i = tid + s*NT;
    float2 v = xrow[i];
    float p = prow[i];
    d[pad(i)] = make_float2(v.x*p, v.y*p);
  }
  __syncthreads();
  mod_pipeline(d, tid);                 // natural-order U1h in LDS
  float2* urow = u1h + (size_t)(b * N1 + j1) * USTRIDE;
  for (int i = tid; i <= T_N/2; i += NT) urow[i] = d[pad(i)];   // bins 0..8192
  fold_store(d, phi, out + 1024 + (size_t)(b * N1 + j1) * 64, tid);  // S1
}

// K3: per (b,pair): Z = U1h[j1]*psi2[j2] (Hermitian-extend) -> IFFT -> |.| -> FFT -> S2 fold.
__global__ void __launch_bounds__(NT) k_order2(const float2* __restrict__ u1h, const float* __restrict__ psi2,
                                               const float* __restrict__ phi, const int* __restrict__ pj1,
                                               const int* __restrict__ pj2, float* __restrict__ out)
{
  extern __shared__ float2 d[];
  const int tid = threadIdx.x;
  const int b = blockIdx.x / NPAIR, p = blockIdx.x % NPAIR;
  const int j1 = pj1[p], j2 = pj2[p];
  const float2* urow = u1h + (size_t)(b * N1 + j1) * USTRIDE;
  const float* prow = psi2 + j2 * T_N;
#pragma unroll
  for (int s = 0; s < T_N/NT; ++s) {
    int i = tid + s*NT;
    float2 u;
    if (i <= T_N/2) u = urow[i];
    else { float2 t = urow[T_N - i]; u = make_float2(t.x, -t.y); }  // conj mirror
    float ps = prow[i];
    d[pad(i)] = make_float2(u.x*ps, u.y*ps);
  }
  __syncthreads();
  mod_pipeline(d, tid);
  fold_store(d, phi, out + 66560 + (size_t)(b * NPAIR + p) * 64, tid); // S2
}

extern "C" void kernel_launch(void* const* d_in, const int* in_sizes, int n_in,
                              void* d_out, int out_size, void* d_ws, size_t ws_size,
                              hipStream_t stream)
{
  const float* x    = (const float*)d_in[0];
  const float* psi1 = (const float*)d_in[1];
  const float* psi2 = (const float*)d_in[2];
  const float* phi  = (const float*)d_in[3];
  const int*   pj1  = (const int*)d_in[4];
  const int*   pj2  = (const int*)d_in[5];
  float* out = (float*)d_out;

  float2* xh  = (float2*)d_ws;                  // [16][16384] = 2 MB
  float2* u1h = xh + (size_t)B_SZ * T_N;        // [1024][USTRIDE] ~ 67 MB

  const size_t lds = (size_t)(T_N + (T_N >> 4)) * sizeof(float2);  // 139264 B

  (void)hipFuncSetAttribute((const void*)k_fft_x,  hipFuncAttributeMaxDynamicSharedMemorySize, (int)lds);
  (void)hipFuncSetAttribute((const void*)k_order1, hipFuncAttributeMaxDynamicSharedMemorySize, (int)lds);
  (void)hipFuncSetAttribute((const void*)k_order2, hipFuncAttributeMaxDynamicSharedMemorySize, (int)lds);

  hipLaunchKernelGGL(k_fft_x,  dim3(B_SZ),         dim3(NT), lds, stream, x, phi, xh, out);
  hipLaunchKernelGGL(k_order1, dim3(B_SZ * N1),    dim3(NT), lds, stream, xh, psi1, phi, u1h, out);
  hipLaunchKernelGGL(k_order2, dim3(B_SZ * NPAIR), dim3(NT), lds, stream, u1h, psi2, phi, pj1, pj2, out);
}

// Round 4
// 516.292 us; speedup vs baseline: 1.6895x; 1.0507x over previous
//
#include <hip/hip_runtime.h>
#include <math.h>

// Wavelet scattering, T=16384. Register-blocked radix-16 in-LDS FFT with
// packed-fp32 (v_pk_*) complex math, 1024 threads/block (16 waves -> 4/SIMD).
// Pipeline: DIF16(1024) -> DIF16(64) -> DIF16(4) -> [DFT4 + |.|/N + DFT4]
//           -> DIT16(4) -> DIT16(64) -> DIT16(1024).   7 LDS sweeps.

#define T_N   16384
#define NT    512          // threads for k_fft_x (radix-4 path)
#define NT2   1024         // threads for pipeline kernels; T_N/16 == NT2
#define B_SZ  16
#define N1    64
#define NPAIR 224
#define FOLD_F 256         // phi numerically zero past bin ~190 (sigma=22.4 bins)
#define USTRIDE 8208       // float2 row stride for half-spectrum (8193 used)
#define INV_N (1.0f/16384.0f)
#define TWO_PI 6.283185307179586f

typedef float v2f __attribute__((ext_vector_type(2)));

__device__ __forceinline__ int pad(int i) { return i + (i >> 4); }  // LDS pad

// complex a*w where w=(c,s): 2 packed ops (pk_mul + pk_fma)
__device__ __forceinline__ v2f cmulw(v2f a, v2f w){
  v2f n; n.x = -a.y; n.y = a.x;
  return w.x * a + w.y * n;
}
__device__ __forceinline__ constexpr int br4(int x){
  return ((x&1)<<3)|((x&2)<<1)|((x&4)>>1)|((x&8)>>3);
}
// reverse 7 base-4 digits of a 14-bit index (k_fft_x unscramble)
__device__ __forceinline__ int rev4_14(int p){
  unsigned r = __brev((unsigned)p) >> 18;
  return (int)(((r & 0x2AAAu) >> 1) | ((r & 0x1555u) << 1));
}

// Fully-unrolled in-register DFT16, sign SGN; result y[r] lands at a[br4(r)].
template<int SGN>
__device__ __forceinline__ void dft16(v2f* a){
  static constexpr float C16[16] = {
    1.f, 0.98078528f, 0.92387953f, 0.83146961f, 0.70710678f, 0.55557023f,
    0.38268343f, 0.19509032f, 0.f, -0.19509032f, -0.38268343f, -0.55557023f,
    -0.70710678f, -0.83146961f, -0.92387953f, -0.98078528f };
  static constexpr float S16[16] = {
    0.f, 0.19509032f, 0.38268343f, 0.55557023f, 0.70710678f, 0.83146961f,
    0.92387953f, 0.98078528f, 1.f, 0.98078528f, 0.92387953f, 0.83146961f,
    0.70710678f, 0.55557023f, 0.38268343f, 0.19509032f };
#pragma unroll
  for (int m = 8; m >= 1; m >>= 1) {
#pragma unroll
    for (int base = 0; base < 16; base += 2*m) {
#pragma unroll
      for (int j = 0; j < m; ++j) {
        v2f u = a[base+j], v = a[base+j+m];
        a[base+j] = u + v;
        v2f w = u - v;
        const int ti = (j*16)/m;               // angle = pi*j/m = pi*ti/16
        v2f tw; tw.x = C16[ti]; tw.y = (float)SGN * S16[ti];
        a[base+j+m] = cmulw(w, tw);
      }
    }
  }
}

// DIF super-stage radix-16 at stride M (M in {1024,64,4}), one group/thread.
// pad(base+kM) == pad(base) + kM + ((kM)>>4) exactly for these M (base's
// intervening bits are zero). Twiddles via recurrence from one __sincosf.
template<int SGN, int M, int LOGM>
__device__ __forceinline__ void super_dif16(v2f* d, int g)
{
  const int j = g & (M-1);
  const int base = ((g >> LOGM) << (LOGM+4)) | j;
  v2f* dp = d + pad(base);
  v2f a[16];
#pragma unroll
  for (int k = 0; k < 16; ++k) a[k] = dp[k*M + ((k*M)>>4)];
  dft16<SGN>(a);
  float sj, cj;
  __sincosf((float)SGN * (TWO_PI / (16.f*(float)M)) * (float)j, &sj, &cj);
  v2f w; w.x = cj; w.y = sj;
  v2f t = w;
  dp[0] = a[0];
#pragma unroll
  for (int r = 1; r < 16; ++r) {
    dp[r*M + ((r*M)>>4)] = cmulw(a[br4(r)], t);
    t = cmulw(t, w);
  }
}

// DIT super-stage radix-16 at stride M (twiddle-before-combine).
template<int SGN, int M, int LOGM>
__device__ __forceinline__ void super_dit16(v2f* d, int g)
{
  const int j = g & (M-1);
  const int base = ((g >> LOGM) << (LOGM+4)) | j;
  v2f* dp = d + pad(base);
  float sj, cj;
  __sincosf((float)SGN * (TWO_PI / (16.f*(float)M)) * (float)j, &sj, &cj);
  v2f w; w.x = cj; w.y = sj;
  v2f a[16];
  a[0] = dp[0];
  v2f t = w;
#pragma unroll
  for (int k = 1; k < 16; ++k) {
    a[k] = cmulw(dp[k*M + ((k*M)>>4)], t);
    t = cmulw(t, w);
  }
  dft16<SGN>(a);
#pragma unroll
  for (int r = 0; r < 16; ++r) dp[r*M + ((r*M)>>4)] = a[br4(r)];
}

// Fused middle: per contiguous-4 group (unit twiddles at stride 1):
// inverse DFT4 -> modulus*1/N -> forward DFT4. Thread t handles the 16
// contiguous values [16t,16t+16): pad(16t+i) = 17t+i.
__device__ __forceinline__ void fused_mid4(v2f* d, int t)
{
  v2f* dp = d + 17*t;
#pragma unroll
  for (int q = 0; q < 4; ++q) {
    v2f a0=dp[4*q], a1=dp[4*q+1], a2=dp[4*q+2], a3=dp[4*q+3];
    v2f t0=a0+a2, t1=a0-a2, t2=a1+a3, t3=a1-a3;
    v2f it3; it3.x = -t3.y; it3.y = t3.x;           // i*t3
    v2f y0=t0+t2, y2=t0-t2, y1=t1+it3, y3=t1-it3;   // inverse (sgn=+1)
    float m0 = INV_N * sqrtf(y0.x*y0.x + y0.y*y0.y);
    float m1 = INV_N * sqrtf(y1.x*y1.x + y1.y*y1.y);
    float m2 = INV_N * sqrtf(y2.x*y2.x + y2.y*y2.y);
    float m3 = INV_N * sqrtf(y3.x*y3.x + y3.y*y3.y);
    float p0=m0+m2, p1=m0-m2, p2=m1+m3, p3=m1-m3;   // forward DFT4 on reals
    v2f o0; o0.x = p0+p2; o0.y = 0.f;
    v2f o1; o1.x = p1;    o1.y = -p3;
    v2f o2; o2.x = p0-p2; o2.y = 0.f;
    v2f o3; o3.x = p1;    o3.y = p3;
    dp[4*q]=o0; dp[4*q+1]=o1; dp[4*q+2]=o2; dp[4*q+3]=o3;
  }
}

// Inverse(+modulus)+forward pipeline on natural-order LDS contents. NT2 thr.
__device__ __forceinline__ void mod_pipeline(v2f* d, int tid)
{
  super_dif16<+1, 1024, 10>(d, tid); __syncthreads();
  super_dif16<+1,   64,  6>(d, tid); __syncthreads();
  super_dif16<+1,    4,  2>(d, tid); __syncthreads();
  fused_mid4(d, tid);                __syncthreads();
  super_dit16<-1,    4,  2>(d, tid); __syncthreads();
  super_dit16<-1,   64,  6>(d, tid); __syncthreads();
  super_dit16<-1, 1024, 10>(d, tid); __syncthreads();
}

// S[k] = (1/N) * Re sum_f spec[f]*phi[f]*e^{+2pi i f k/64}, Hermitian-doubled,
// phi support truncated to f < FOLD_F. 16 threads per output k (NT2 threads).
__device__ void fold_store16(const v2f* d, const float* __restrict__ phi, float* outp, int tid)
{
  const int k = tid >> 4, g = tid & 15;
  float acc = 0.f;
#pragma unroll
  for (int f = g; f < FOLD_F; f += 16) {
    v2f u = d[pad(f)];
    float w = phi[f] * ((f == 0) ? 1.f : 2.f);
    float sv, cv;
    __sincosf((TWO_PI/64.f) * (float)((f*k) & 63), &sv, &cv);
    acc += w * (u.x*cv - u.y*sv);
  }
  acc += __shfl_xor(acc, 1);
  acc += __shfl_xor(acc, 2);
  acc += __shfl_xor(acc, 4);
  acc += __shfl_xor(acc, 8);
  if (g == 0) outp[k] = acc * INV_N;
}

// ---- radix-4 float2 path kept only for k_fft_x (16 blocks, proven) ----
__device__ __forceinline__ float2 f2add(float2 a, float2 b){ return make_float2(a.x+b.x, a.y+b.y); }
__device__ __forceinline__ float2 f2sub(float2 a, float2 b){ return make_float2(a.x-b.x, a.y-b.y); }
__device__ __forceinline__ float2 cmul_cs(float2 a, float c, float s){
  return make_float2(a.x*c - a.y*s, a.x*s + a.y*c);
}
__device__ void dif_sweep(float2* d, int tid, float sgn, int mb_hi, int mb_lo)
{
  const float ang = sgn * (TWO_PI / (float)T_N);
  for (int mbits = mb_hi; mbits >= mb_lo; mbits -= 2) {
    const int M = 1 << mbits;
#pragma unroll 8
    for (int v = tid; v < T_N/4; v += NT) {
      const int j = v & (M-1);
      const int base = ((v >> mbits) << (mbits+2)) | j;
      const int i0 = pad(base), i1 = pad(base+M), i2 = pad(base+2*M), i3 = pad(base+3*M);
      float2 a0=d[i0], a1=d[i1], a2=d[i2], a3=d[i3];
      float2 t0=f2add(a0,a2), t1=f2sub(a0,a2), t2=f2add(a1,a3), t3=f2sub(a1,a3);
      float2 y0=f2add(t0,t2), y2=f2sub(t0,t2);
      float2 y1=make_float2(t1.x - sgn*t3.y, t1.y + sgn*t3.x);
      float2 y3=make_float2(t1.x + sgn*t3.y, t1.y - sgn*t3.x);
      float s1,c1;
      __sincosf(ang * (float)(j << (12-mbits)), &s1, &c1);
      float c2=c1*c1-s1*s1, s2=2.f*c1*s1;
      float c3=c1*c2-s1*s2, s3=c1*s2+s1*c2;
      d[i0]=y0;
      d[i1]=cmul_cs(y1,c1,s1);
      d[i2]=cmul_cs(y2,c2,s2);
      d[i3]=cmul_cs(y3,c3,s3);
    }
    __syncthreads();
  }
}
__device__ void fold_store8(const float2* d, const float* __restrict__ phi, float* outp, int tid)
{
  const int k = tid >> 3, g = tid & 7;
  float acc = 0.f;
  for (int f = g; f < FOLD_F; f += 8) {
    float2 u = d[pad(f)];
    float w = phi[f] * ((f == 0) ? 1.f : 2.f);
    float sv, cv;
    __sincosf((TWO_PI/64.f) * (float)((f*k) & 63), &sv, &cv);
    acc += w * (u.x*cv - u.y*sv);
  }
  acc += __shfl_xor(acc, 1);
  acc += __shfl_xor(acc, 2);
  acc += __shfl_xor(acc, 4);
  if (g == 0) outp[k] = acc * INV_N;
}

// K1: xh = FFT(x) (natural order, to ws) + S0 fold. 16 blocks, 512 thr.
__global__ void __launch_bounds__(NT) k_fft_x(const float* __restrict__ x, const float* __restrict__ phi,
                                              float2* __restrict__ xh, float* __restrict__ out)
{
  extern __shared__ char smem[];
  float2* d = (float2*)smem;
  const int tid = threadIdx.x;
  const int b = blockIdx.x;
  const float* xr = x + b * T_N;
  for (int i = tid; i < T_N; i += NT) d[pad(i)] = make_float2(xr[i], 0.f);
  __syncthreads();
  dif_sweep(d, tid, -1.f, 12, 0);      // forward FFT, digit-reversed result
  for (int p = tid; p < T_N; p += NT) { // unscramble in place (involution)
    int r = rev4_14(p);
    if (p < r) { int ip = pad(p), ir = pad(r); float2 t = d[ip]; d[ip] = d[ir]; d[ir] = t; }
  }
  __syncthreads();
  float2* xrow = xh + (size_t)b * T_N;
  for (int i = tid; i < T_N; i += NT) xrow[i] = d[pad(i)];
  fold_store8(d, phi, out + b * 64, tid);   // S0
}

// K2: per (b,j1): Z = xh*psi1 -> IFFT -> |.| -> FFT -> store half-spectrum U1h + S1 fold.
__global__ void __launch_bounds__(NT2) k_order1(const float2* __restrict__ xh, const float* __restrict__ psi1,
                                                const float* __restrict__ phi, float2* __restrict__ u1h,
                                                float* __restrict__ out)
{
  extern __shared__ char smem[];
  v2f* d = (v2f*)smem;
  const int tid = threadIdx.x;
  const int b = blockIdx.x >> 6, j1 = blockIdx.x & 63;
  const float2* xrow = xh + (size_t)b * T_N;
  const float* prow = psi1 + j1 * T_N;
#pragma unroll
  for (int s = 0; s < T_N/NT2; ++s) {
    int i = tid + s*NT2;
    float2 v = xrow[i];
    float p = prow[i];
    v2f z; z.x = v.x*p; z.y = v.y*p;
    d[pad(i)] = z;
  }
  __syncthreads();
  mod_pipeline(d, tid);                 // natural-order U1h in LDS
  float2* urow = u1h + (size_t)(b * N1 + j1) * USTRIDE;
  for (int i = tid; i <= T_N/2; i += NT2) {
    v2f u = d[pad(i)];
    urow[i] = make_float2(u.x, u.y);    // bins 0..8192
  }
  fold_store16(d, phi, out + 1024 + (size_t)(b * N1 + j1) * 64, tid);  // S1
}

// K3: per (b,pair): Z = U1h[j1]*psi2[j2] (Hermitian-extend) -> IFFT -> |.| -> FFT -> S2 fold.
__global__ void __launch_bounds__(NT2) k_order2(const float2* __restrict__ u1h, const float* __restrict__ psi2,
                                                const float* __restrict__ phi, const int* __restrict__ pj1,
                                                const int* __restrict__ pj2, float* __restrict__ out)
{
  extern __shared__ char smem[];
  v2f* d = (v2f*)smem;
  const int tid = threadIdx.x;
  const int b = blockIdx.x / NPAIR, p = blockIdx.x % NPAIR;
  const int j1 = pj1[p], j2 = pj2[p];
  const float2* urow = u1h + (size_t)(b * N1 + j1) * USTRIDE;
  const float* prow = psi2 + j2 * T_N;
#pragma unroll
  for (int s = 0; s < T_N/NT2; ++s) {
    int i = tid + s*NT2;
    float2 u;
    if (i <= T_N/2) u = urow[i];
    else { float2 t = urow[T_N - i]; u = make_float2(t.x, -t.y); }  // conj mirror
    float ps = prow[i];
    v2f z; z.x = u.x*ps; z.y = u.y*ps;
    d[pad(i)] = z;
  }
  __syncthreads();
  mod_pipeline(d, tid);
  fold_store16(d, phi, out + 66560 + (size_t)(b * NPAIR + p) * 64, tid); // S2
}

extern "C" void kernel_launch(void* const* d_in, const int* in_sizes, int n_in,
                              void* d_out, int out_size, void* d_ws, size_t ws_size,
                              hipStream_t stream)
{
  const float* x    = (const float*)d_in[0];
  const float* psi1 = (const float*)d_in[1];
  const float* psi2 = (const float*)d_in[2];
  const float* phi  = (const float*)d_in[3];
  const int*   pj1  = (const int*)d_in[4];
  const int*   pj2  = (const int*)d_in[5];
  float* out = (float*)d_out;

  float2* xh  = (float2*)d_ws;                  // [16][16384] = 2 MB
  float2* u1h = xh + (size_t)B_SZ * T_N;        // [1024][USTRIDE] ~ 67 MB

  const size_t lds = (size_t)(T_N + (T_N >> 4)) * sizeof(float2);  // 139264 B

  (void)hipFuncSetAttribute((const void*)k_fft_x,  hipFuncAttributeMaxDynamicSharedMemorySize, (int)lds);
  (void)hipFuncSetAttribute((const void*)k_order1, hipFuncAttributeMaxDynamicSharedMemorySize, (int)lds);
  (void)hipFuncSetAttribute((const void*)k_order2, hipFuncAttributeMaxDynamicSharedMemorySize, (int)lds);

  hipLaunchKernelGGL(k_fft_x,  dim3(B_SZ),         dim3(NT),  lds, stream, x, phi, xh, out);
  hipLaunchKernelGGL(k_order1, dim3(B_SZ * N1),    dim3(NT2), lds, stream, xh, psi1, phi, u1h, out);
  hipLaunchKernelGGL(k_order2, dim3(B_SZ * NPAIR), dim3(NT2), lds, stream, u1h, psi2, phi, pj1, pj2, out);
}

// Round 5
// 502.252 us; speedup vs baseline: 1.7368x; 1.0280x over previous
//
#include <hip/hip_runtime.h>
#include <math.h>

// Wavelet scattering, T=16384. Register-blocked radix-16 in-LDS FFT with
// packed-fp32 complex math, 1024 threads/block (16 waves, LDS-capped 1 blk/CU).
// __launch_bounds__(1024,4) -> 128 VGPR budget so a[16]+tw[16] stay in regs.
// Pipeline: DIF16(1024) -> DIF16(64) -> DIF16(4) -> [DFT4 + |.|/N + DFT4]
//           -> DIT16(4) -> DIT16(64) -> DIT16(1024).   7 LDS sweeps.

#define T_N   16384
#define NT    512          // threads for k_fft_x (radix-4 path)
#define NT2   1024         // threads for pipeline kernels; T_N/16 == NT2
#define B_SZ  16
#define N1    64
#define NPAIR 224
#define FOLD_F 256         // phi numerically zero past bin ~190 (sigma=22.4 bins)
#define USTRIDE 8208       // float2 row stride for half-spectrum (8193 used)
#define INV_N (1.0f/16384.0f)
#define TWO_PI 6.283185307179586f

typedef float v2f __attribute__((ext_vector_type(2)));

__device__ __forceinline__ int pad(int i) { return i + (i >> 4); }  // LDS pad

// full complex multiply a*w (2 packed ops: pk_mul + pk_fma with swizzle)
__device__ __forceinline__ v2f cmulw(v2f a, v2f w){
  v2f n; n.x = -a.y; n.y = a.x;
  return w.x * a + w.y * n;
}
__device__ __forceinline__ constexpr int br4(int x){
  return ((x&1)<<3)|((x&2)<<1)|((x&4)>>1)|((x&8)>>3);
}
// reverse 7 base-4 digits of a 14-bit index (k_fft_x unscramble)
__device__ __forceinline__ int rev4_14(int p){
  unsigned r = __brev((unsigned)p) >> 18;
  return (int)(((r & 0x2AAAu) >> 1) | ((r & 0x1555u) << 1));
}

// Depth-4 product tree: tw[r] = w^r, r in [0,16). 14 cmuls, dep depth 4.
__device__ __forceinline__ void twiddle_tree(v2f w, v2f* tw){
  tw[0].x = 1.f; tw[0].y = 0.f;
  tw[1] = w;
  tw[2] = cmulw(w, w);
  tw[4] = cmulw(tw[2], tw[2]);
  tw[8] = cmulw(tw[4], tw[4]);
  tw[3] = cmulw(tw[2], w);
  tw[5] = cmulw(tw[4], w);
  tw[6] = cmulw(tw[4], tw[2]);
  tw[7] = cmulw(tw[4], tw[3]);
  tw[9]  = cmulw(tw[8], w);
  tw[10] = cmulw(tw[8], tw[2]);
  tw[11] = cmulw(tw[8], tw[3]);
  tw[12] = cmulw(tw[8], tw[4]);
  tw[13] = cmulw(tw[8], tw[5]);
  tw[14] = cmulw(tw[8], tw[6]);
  tw[15] = cmulw(tw[8], tw[7]);
}

// Fully-unrolled in-register DFT16, sign SGN; result y[r] lands at a[br4(r)].
template<int SGN>
__device__ __forceinline__ void dft16(v2f* a){
  static constexpr float C16[16] = {
    1.f, 0.98078528f, 0.92387953f, 0.83146961f, 0.70710678f, 0.55557023f,
    0.38268343f, 0.19509032f, 0.f, -0.19509032f, -0.38268343f, -0.55557023f,
    -0.70710678f, -0.83146961f, -0.92387953f, -0.98078528f };
  static constexpr float S16[16] = {
    0.f, 0.19509032f, 0.38268343f, 0.55557023f, 0.70710678f, 0.83146961f,
    0.92387953f, 0.98078528f, 1.f, 0.98078528f, 0.92387953f, 0.83146961f,
    0.70710678f, 0.55557023f, 0.38268343f, 0.19509032f };
#pragma unroll
  for (int m = 8; m >= 1; m >>= 1) {
#pragma unroll
    for (int base = 0; base < 16; base += 2*m) {
#pragma unroll
      for (int j = 0; j < m; ++j) {
        v2f u = a[base+j], v = a[base+j+m];
        a[base+j] = u + v;
        v2f w = u - v;
        const int ti = (j*16)/m;               // angle = pi*j/m = pi*ti/16
        v2f tw; tw.x = C16[ti]; tw.y = (float)SGN * S16[ti];
        a[base+j+m] = cmulw(w, tw);
      }
    }
  }
}

// DIF super-stage radix-16 at stride M (M in {1024,64,4}), one group/thread.
// pad(base+kM) == pad(base) + kM + ((kM)>>4) exactly for these M.
template<int SGN, int M, int LOGM>
__device__ __forceinline__ void super_dif16(v2f* d, int g)
{
  const int j = g & (M-1);
  const int base = ((g >> LOGM) << (LOGM+4)) | j;
  v2f* dp = d + pad(base);
  v2f a[16];
#pragma unroll
  for (int k = 0; k < 16; ++k) a[k] = dp[k*M + ((k*M)>>4)];
  dft16<SGN>(a);
  float sj, cj;
  __sincosf((float)SGN * (TWO_PI / (16.f*(float)M)) * (float)j, &sj, &cj);
  v2f w; w.x = cj; w.y = sj;
  v2f tw[16];
  twiddle_tree(w, tw);
  dp[0] = a[0];
#pragma unroll
  for (int r = 1; r < 16; ++r)
    dp[r*M + ((r*M)>>4)] = cmulw(a[br4(r)], tw[r]);
}

// DIT super-stage radix-16 at stride M (twiddle-before-combine).
template<int SGN, int M, int LOGM>
__device__ __forceinline__ void super_dit16(v2f* d, int g)
{
  const int j = g & (M-1);
  const int base = ((g >> LOGM) << (LOGM+4)) | j;
  v2f* dp = d + pad(base);
  float sj, cj;
  __sincosf((float)SGN * (TWO_PI / (16.f*(float)M)) * (float)j, &sj, &cj);
  v2f w; w.x = cj; w.y = sj;
  v2f tw[16];
  twiddle_tree(w, tw);
  v2f a[16];
  a[0] = dp[0];
#pragma unroll
  for (int k = 1; k < 16; ++k)
    a[k] = cmulw(dp[k*M + ((k*M)>>4)], tw[k]);
  dft16<SGN>(a);
#pragma unroll
  for (int r = 0; r < 16; ++r) dp[r*M + ((r*M)>>4)] = a[br4(r)];
}

// Fused middle: per contiguous-4 group (unit twiddles at stride 1):
// inverse DFT4 -> modulus*1/N -> forward DFT4. Thread t handles the 16
// contiguous values [16t,16t+16): pad(16t+i) = 17t+i.
__device__ __forceinline__ void fused_mid4(v2f* d, int t)
{
  v2f* dp = d + 17*t;
#pragma unroll
  for (int q = 0; q < 4; ++q) {
    v2f a0=dp[4*q], a1=dp[4*q+1], a2=dp[4*q+2], a3=dp[4*q+3];
    v2f t0=a0+a2, t1=a0-a2, t2=a1+a3, t3=a1-a3;
    v2f it3; it3.x = -t3.y; it3.y = t3.x;           // i*t3
    v2f y0=t0+t2, y2=t0-t2, y1=t1+it3, y3=t1-it3;   // inverse (sgn=+1)
    float m0 = INV_N * sqrtf(y0.x*y0.x + y0.y*y0.y);
    float m1 = INV_N * sqrtf(y1.x*y1.x + y1.y*y1.y);
    float m2 = INV_N * sqrtf(y2.x*y2.x + y2.y*y2.y);
    float m3 = INV_N * sqrtf(y3.x*y3.x + y3.y*y3.y);
    float p0=m0+m2, p1=m0-m2, p2=m1+m3, p3=m1-m3;   // forward DFT4 on reals
    v2f o0; o0.x = p0+p2; o0.y = 0.f;
    v2f o1; o1.x = p1;    o1.y = -p3;
    v2f o2; o2.x = p0-p2; o2.y = 0.f;
    v2f o3; o3.x = p1;    o3.y = p3;
    dp[4*q]=o0; dp[4*q+1]=o1; dp[4*q+2]=o2; dp[4*q+3]=o3;
  }
}

// Inverse(+modulus)+forward pipeline on natural-order LDS contents. NT2 thr.
__device__ __forceinline__ void mod_pipeline(v2f* d, int tid)
{
  super_dif16<+1, 1024, 10>(d, tid); __syncthreads();
  super_dif16<+1,   64,  6>(d, tid); __syncthreads();
  super_dif16<+1,    4,  2>(d, tid); __syncthreads();
  fused_mid4(d, tid);                __syncthreads();
  super_dit16<-1,    4,  2>(d, tid); __syncthreads();
  super_dit16<-1,   64,  6>(d, tid); __syncthreads();
  super_dit16<-1, 1024, 10>(d, tid); __syncthreads();
}

// S[k] = (1/N) * Re sum_f spec[f]*phi[f]*e^{+2pi i f k/64}, Hermitian-doubled,
// phi support truncated to f < FOLD_F. 16 threads per output k (NT2 threads).
__device__ void fold_store16(const v2f* d, const float* __restrict__ phi, float* outp, int tid)
{
  const int k = tid >> 4, g = tid & 15;
  float acc = 0.f;
#pragma unroll
  for (int f = g; f < FOLD_F; f += 16) {
    v2f u = d[pad(f)];
    float w = phi[f] * ((f == 0) ? 1.f : 2.f);
    float sv, cv;
    __sincosf((TWO_PI/64.f) * (float)((f*k) & 63), &sv, &cv);
    acc += w * (u.x*cv - u.y*sv);
  }
  acc += __shfl_xor(acc, 1);
  acc += __shfl_xor(acc, 2);
  acc += __shfl_xor(acc, 4);
  acc += __shfl_xor(acc, 8);
  if (g == 0) outp[k] = acc * INV_N;
}

// ---- radix-4 float2 path kept only for k_fft_x (16 blocks, proven) ----
__device__ __forceinline__ float2 f2add(float2 a, float2 b){ return make_float2(a.x+b.x, a.y+b.y); }
__device__ __forceinline__ float2 f2sub(float2 a, float2 b){ return make_float2(a.x-b.x, a.y-b.y); }
__device__ __forceinline__ float2 cmul_cs(float2 a, float c, float s){
  return make_float2(a.x*c - a.y*s, a.x*s + a.y*c);
}
__device__ void dif_sweep(float2* d, int tid, float sgn, int mb_hi, int mb_lo)
{
  const float ang = sgn * (TWO_PI / (float)T_N);
  for (int mbits = mb_hi; mbits >= mb_lo; mbits -= 2) {
    const int M = 1 << mbits;
#pragma unroll 8
    for (int v = tid; v < T_N/4; v += NT) {
      const int j = v & (M-1);
      const int base = ((v >> mbits) << (mbits+2)) | j;
      const int i0 = pad(base), i1 = pad(base+M), i2 = pad(base+2*M), i3 = pad(base+3*M);
      float2 a0=d[i0], a1=d[i1], a2=d[i2], a3=d[i3];
      float2 t0=f2add(a0,a2), t1=f2sub(a0,a2), t2=f2add(a1,a3), t3=f2sub(a1,a3);
      float2 y0=f2add(t0,t2), y2=f2sub(t0,t2);
      float2 y1=make_float2(t1.x - sgn*t3.y, t1.y + sgn*t3.x);
      float2 y3=make_float2(t1.x + sgn*t3.y, t1.y - sgn*t3.x);
      float s1,c1;
      __sincosf(ang * (float)(j << (12-mbits)), &s1, &c1);
      float c2=c1*c1-s1*s1, s2=2.f*c1*s1;
      float c3=c1*c2-s1*s2, s3=c1*s2+s1*c2;
      d[i0]=y0;
      d[i1]=cmul_cs(y1,c1,s1);
      d[i2]=cmul_cs(y2,c2,s2);
      d[i3]=cmul_cs(y3,c3,s3);
    }
    __syncthreads();
  }
}
__device__ void fold_store8(const float2* d, const float* __restrict__ phi, float* outp, int tid)
{
  const int k = tid >> 3, g = tid & 7;
  float acc = 0.f;
  for (int f = g; f < FOLD_F; f += 8) {
    float2 u = d[pad(f)];
    float w = phi[f] * ((f == 0) ? 1.f : 2.f);
    float sv, cv;
    __sincosf((TWO_PI/64.f) * (float)((f*k) & 63), &sv, &cv);
    acc += w * (u.x*cv - u.y*sv);
  }
  acc += __shfl_xor(acc, 1);
  acc += __shfl_xor(acc, 2);
  acc += __shfl_xor(acc, 4);
  if (g == 0) outp[k] = acc * INV_N;
}

// K1: xh = FFT(x) (natural order, to ws) + S0 fold. 16 blocks, 512 thr.
__global__ void __launch_bounds__(NT) k_fft_x(const float* __restrict__ x, const float* __restrict__ phi,
                                              float2* __restrict__ xh, float* __restrict__ out)
{
  extern __shared__ char smem[];
  float2* d = (float2*)smem;
  const int tid = threadIdx.x;
  const int b = blockIdx.x;
  const float* xr = x + b * T_N;
  for (int i = tid; i < T_N; i += NT) d[pad(i)] = make_float2(xr[i], 0.f);
  __syncthreads();
  dif_sweep(d, tid, -1.f, 12, 0);      // forward FFT, digit-reversed result
  for (int p = tid; p < T_N; p += NT) { // unscramble in place (involution)
    int r = rev4_14(p);
    if (p < r) { int ip = pad(p), ir = pad(r); float2 t = d[ip]; d[ip] = d[ir]; d[ir] = t; }
  }
  __syncthreads();
  float2* xrow = xh + (size_t)b * T_N;
  for (int i = tid; i < T_N; i += NT) xrow[i] = d[pad(i)];
  fold_store8(d, phi, out + b * 64, tid);   // S0
}

// K2: per (b,j1): Z = xh*psi1 -> IFFT -> |.| -> FFT -> store half-spectrum U1h + S1 fold.
__global__ void __launch_bounds__(NT2, 4) k_order1(const float2* __restrict__ xh, const float* __restrict__ psi1,
                                                   const float* __restrict__ phi, float2* __restrict__ u1h,
                                                   float* __restrict__ out)
{
  extern __shared__ char smem[];
  v2f* d = (v2f*)smem;
  const int tid = threadIdx.x;
  const int b = blockIdx.x >> 6, j1 = blockIdx.x & 63;
  const float2* xrow = xh + (size_t)b * T_N;
  const float* prow = psi1 + j1 * T_N;
#pragma unroll
  for (int s = 0; s < T_N/NT2; ++s) {
    int i = tid + s*NT2;
    float2 v = xrow[i];
    float p = prow[i];
    v2f z; z.x = v.x*p; z.y = v.y*p;
    d[pad(i)] = z;
  }
  __syncthreads();
  mod_pipeline(d, tid);                 // natural-order U1h in LDS
  float2* urow = u1h + (size_t)(b * N1 + j1) * USTRIDE;
  for (int i = tid; i <= T_N/2; i += NT2) {
    v2f u = d[pad(i)];
    urow[i] = make_float2(u.x, u.y);    // bins 0..8192
  }
  fold_store16(d, phi, out + 1024 + (size_t)(b * N1 + j1) * 64, tid);  // S1
}

// K3: per (b,pair): Z = U1h[j1]*psi2[j2] (Hermitian-extend) -> IFFT -> |.| -> FFT -> S2 fold.
__global__ void __launch_bounds__(NT2, 4) k_order2(const float2* __restrict__ u1h, const float* __restrict__ psi2,
                                                   const float* __restrict__ phi, const int* __restrict__ pj1,
                                                   const int* __restrict__ pj2, float* __restrict__ out)
{
  extern __shared__ char smem[];
  v2f* d = (v2f*)smem;
  const int tid = threadIdx.x;
  const int b = blockIdx.x / NPAIR, p = blockIdx.x % NPAIR;
  const int j1 = pj1[p], j2 = pj2[p];
  const float2* urow = u1h + (size_t)(b * N1 + j1) * USTRIDE;
  const float* prow = psi2 + j2 * T_N;
#pragma unroll
  for (int s = 0; s < T_N/NT2; ++s) {
    int i = tid + s*NT2;
    float2 u;
    if (i <= T_N/2) u = urow[i];
    else { float2 t = urow[T_N - i]; u = make_float2(t.x, -t.y); }  // conj mirror
    float ps = prow[i];
    v2f z; z.x = u.x*ps; z.y = u.y*ps;
    d[pad(i)] = z;
  }
  __syncthreads();
  mod_pipeline(d, tid);
  fold_store16(d, phi, out + 66560 + (size_t)(b * NPAIR + p) * 64, tid); // S2
}

extern "C" void kernel_launch(void* const* d_in, const int* in_sizes, int n_in,
                              void* d_out, int out_size, void* d_ws, size_t ws_size,
                              hipStream_t stream)
{
  const float* x    = (const float*)d_in[0];
  const float* psi1 = (const float*)d_in[1];
  const float* psi2 = (const float*)d_in[2];
  const float* phi  = (const float*)d_in[3];
  const int*   pj1  = (const int*)d_in[4];
  const int*   pj2  = (const int*)d_in[5];
  float* out = (float*)d_out;

  float2* xh  = (float2*)d_ws;                  // [16][16384] = 2 MB
  float2* u1h = xh + (size_t)B_SZ * T_N;        // [1024][USTRIDE] ~ 67 MB

  const size_t lds = (size_t)(T_N + (T_N >> 4)) * sizeof(float2);  // 139264 B

  (void)hipFuncSetAttribute((const void*)k_fft_x,  hipFuncAttributeMaxDynamicSharedMemorySize, (int)lds);
  (void)hipFuncSetAttribute((const void*)k_order1, hipFuncAttributeMaxDynamicSharedMemorySize, (int)lds);
  (void)hipFuncSetAttribute((const void*)k_order2, hipFuncAttributeMaxDynamicSharedMemorySize, (int)lds);

  hipLaunchKernelGGL(k_fft_x,  dim3(B_SZ),         dim3(NT),  lds, stream, x, phi, xh, out);
  hipLaunchKernelGGL(k_order1, dim3(B_SZ * N1),    dim3(NT2), lds, stream, xh, psi1, phi, u1h, out);
  hipLaunchKernelGGL(k_order2, dim3(B_SZ * NPAIR), dim3(NT2), lds, stream, u1h, psi2, phi, pj1, pj2, out);
}

// Round 6
// 444.959 us; speedup vs baseline: 1.9604x; 1.1288x over previous
//
#include <hip/hip_runtime.h>
#include <math.h>

// Wavelet scattering, T=16384. Register-blocked radix-16 in-LDS FFT with
// packed-fp32 complex math, 1024 threads/block.
// k_order2 forward transform is OUTPUT-PRUNED: only bins < 256 are needed by
// the phi-fold, so stage M=64 computes only r<4 outputs and stage M=1024 only
// y0 for groups j<256.  Fold uses exact i^k phase recurrence (1 sincos).

#define T_N   16384
#define NT    512          // threads for k_fft_x (radix-4 path)
#define NT2   1024         // threads for pipeline kernels; T_N/16 == NT2
#define B_SZ  16
#define N1    64
#define NPAIR 224
#define FOLD_F 256         // phi numerically zero past bin ~190 (sigma=22.4 bins)
#define USTRIDE 8208       // float2 row stride for half-spectrum (8193 used)
#define INV_N (1.0f/16384.0f)
#define TWO_PI 6.283185307179586f

typedef float v2f __attribute__((ext_vector_type(2)));

__device__ __forceinline__ int pad(int i) { return i + (i >> 4); }  // LDS pad

// full complex multiply a*w
__device__ __forceinline__ v2f cmulw(v2f a, v2f w){
  v2f n; n.x = -a.y; n.y = a.x;
  return w.x * a + w.y * n;
}
__device__ __forceinline__ constexpr int br4(int x){
  return ((x&1)<<3)|((x&2)<<1)|((x&4)>>1)|((x&8)>>3);
}
// reverse 7 base-4 digits of a 14-bit index (k_fft_x unscramble)
__device__ __forceinline__ int rev4_14(int p){
  unsigned r = __brev((unsigned)p) >> 18;
  return (int)(((r & 0x2AAAu) >> 1) | ((r & 0x1555u) << 1));
}

// Depth-4 product tree: tw[r] = w^r, r in [0,16). 14 cmuls, dep depth 4.
__device__ __forceinline__ void twiddle_tree(v2f w, v2f* tw){
  tw[0].x = 1.f; tw[0].y = 0.f;
  tw[1] = w;
  tw[2] = cmulw(w, w);
  tw[4] = cmulw(tw[2], tw[2]);
  tw[8] = cmulw(tw[4], tw[4]);
  tw[3] = cmulw(tw[2], w);
  tw[5] = cmulw(tw[4], w);
  tw[6] = cmulw(tw[4], tw[2]);
  tw[7] = cmulw(tw[4], tw[3]);
  tw[9]  = cmulw(tw[8], w);
  tw[10] = cmulw(tw[8], tw[2]);
  tw[11] = cmulw(tw[8], tw[3]);
  tw[12] = cmulw(tw[8], tw[4]);
  tw[13] = cmulw(tw[8], tw[5]);
  tw[14] = cmulw(tw[8], tw[6]);
  tw[15] = cmulw(tw[8], tw[7]);
}

// Fully-unrolled in-register DFT16, sign SGN; result y[r] lands at a[br4(r)].
template<int SGN>
__device__ __forceinline__ void dft16(v2f* a){
  static constexpr float C16[16] = {
    1.f, 0.98078528f, 0.92387953f, 0.83146961f, 0.70710678f, 0.55557023f,
    0.38268343f, 0.19509032f, 0.f, -0.19509032f, -0.38268343f, -0.55557023f,
    -0.70710678f, -0.83146961f, -0.92387953f, -0.98078528f };
  static constexpr float S16[16] = {
    0.f, 0.19509032f, 0.38268343f, 0.55557023f, 0.70710678f, 0.83146961f,
    0.92387953f, 0.98078528f, 1.f, 0.98078528f, 0.92387953f, 0.83146961f,
    0.70710678f, 0.55557023f, 0.38268343f, 0.19509032f };
#pragma unroll
  for (int m = 8; m >= 1; m >>= 1) {
#pragma unroll
    for (int base = 0; base < 16; base += 2*m) {
#pragma unroll
      for (int j = 0; j < m; ++j) {
        v2f u = a[base+j], v = a[base+j+m];
        a[base+j] = u + v;
        v2f w = u - v;
        const int ti = (j*16)/m;               // angle = pi*j/m = pi*ti/16
        v2f tw; tw.x = C16[ti]; tw.y = (float)SGN * S16[ti];
        a[base+j+m] = cmulw(w, tw);
      }
    }
  }
}

// DIF super-stage radix-16 at stride M (M in {1024,64,4}), one group/thread.
template<int SGN, int M, int LOGM>
__device__ __forceinline__ void super_dif16(v2f* d, int g)
{
  const int j = g & (M-1);
  const int base = ((g >> LOGM) << (LOGM+4)) | j;
  v2f* dp = d + pad(base);
  v2f a[16];
#pragma unroll
  for (int k = 0; k < 16; ++k) a[k] = dp[k*M + ((k*M)>>4)];
  dft16<SGN>(a);
  float sj, cj;
  __sincosf((float)SGN * (TWO_PI / (16.f*(float)M)) * (float)j, &sj, &cj);
  v2f w; w.x = cj; w.y = sj;
  v2f tw[16];
  twiddle_tree(w, tw);
  dp[0] = a[0];
#pragma unroll
  for (int r = 1; r < 16; ++r)
    dp[r*M + ((r*M)>>4)] = cmulw(a[br4(r)], tw[r]);
}

// DIT super-stage radix-16 at stride M (twiddle-before-combine).
template<int SGN, int M, int LOGM>
__device__ __forceinline__ void super_dit16(v2f* d, int g)
{
  const int j = g & (M-1);
  const int base = ((g >> LOGM) << (LOGM+4)) | j;
  v2f* dp = d + pad(base);
  float sj, cj;
  __sincosf((float)SGN * (TWO_PI / (16.f*(float)M)) * (float)j, &sj, &cj);
  v2f w; w.x = cj; w.y = sj;
  v2f tw[16];
  twiddle_tree(w, tw);
  v2f a[16];
  a[0] = dp[0];
#pragma unroll
  for (int k = 1; k < 16; ++k)
    a[k] = cmulw(dp[k*M + ((k*M)>>4)], tw[k]);
  dft16<SGN>(a);
#pragma unroll
  for (int r = 0; r < 16; ++r) dp[r*M + ((r*M)>>4)] = a[br4(r)];
}

// PRUNED DIT16 at M=64: only outputs r<4 needed (bins 64r+j' < 256 within each
// 1024-segment).  y_r = sum_c W16^{SGN rc} B_c[r], B_c[r] = DFT4_t(a[c+4t]).
template<int SGN>
__device__ __forceinline__ void super_dit16_m64_prune(v2f* d, int g)
{
  constexpr int M = 64;
  constexpr int PSTR = M + (M>>4);           // 68
  const int j = g & 63;
  const int base = ((g >> 6) << 10) | j;
  v2f* dp = d + pad(base);
  float sj, cj;
  __sincosf((float)SGN * (TWO_PI / 1024.f) * (float)j, &sj, &cj);
  v2f w; w.x = cj; w.y = sj;
  v2f tw[16];
  twiddle_tree(w, tw);
  v2f a[16];
  a[0] = dp[0];
#pragma unroll
  for (int k = 1; k < 16; ++k)
    a[k] = cmulw(dp[k*M + ((k*M)>>4)], tw[k]);
  // 4 DFT4s over t for each c
  v2f Y[4][4];
#pragma unroll
  for (int c = 0; c < 4; ++c) {
    v2f s0=a[c], s1=a[c+4], s2=a[c+8], s3=a[c+12];
    v2f e0 = s0+s2, e1 = s0-s2, o0 = s1+s3, o1 = s1-s3;
    v2f io1; io1.x = -(float)SGN * o1.y; io1.y = (float)SGN * o1.x;  // SGN*i*o1
    Y[c][0] = e0 + o0;
    Y[c][1] = e1 + io1;
    Y[c][2] = e0 - o0;
    Y[c][3] = e1 - io1;
  }
  // combine with W16^{SGN rc} (m = r*c in [0,10))
  static constexpr float WC[10] = {1.f,0.92387953f,0.70710678f,0.38268343f,0.f,
                                   -0.38268343f,-0.70710678f,-0.92387953f,-1.f,-0.92387953f};
  static constexpr float WS[10] = {0.f,0.38268343f,0.70710678f,0.92387953f,1.f,
                                   0.92387953f,0.70710678f,0.38268343f,0.f,-0.38268343f};
#pragma unroll
  for (int r = 0; r < 4; ++r) {
    v2f acc = Y[0][r];
#pragma unroll
    for (int c = 1; c < 4; ++c) {
      v2f wc; wc.x = WC[r*c]; wc.y = (float)SGN * WS[r*c];
      acc += cmulw(Y[c][r], wc);
    }
    dp[r*PSTR] = acc;
  }
}

// PRUNED final DIT16 at M=1024: only bins k=j<256, i.e. y0 of groups j<256:
// X[j] = sum_k dp[k*1088] * w^k.  dp[0] is read only by this thread's group.
template<int SGN>
__device__ __forceinline__ void super_dit16_m1024_bin256(v2f* d, int tid)
{
  if (tid < 256) {
    const int j = tid;
    v2f* dp = d + pad(j);
    float sj, cj;
    __sincosf((float)SGN * (TWO_PI / 16384.f) * (float)j, &sj, &cj);
    v2f w; w.x = cj; w.y = sj;
    v2f tw[16];
    twiddle_tree(w, tw);
    v2f acc = dp[0];
#pragma unroll
    for (int k = 1; k < 16; ++k)
      acc += cmulw(dp[k*1024 + ((k*1024)>>4)], tw[k]);
    dp[0] = acc;
  }
}

// Fused middle: per contiguous-4 group (unit twiddles at stride 1):
// inverse DFT4 -> modulus*1/N -> forward DFT4.  pad(16t+i) = 17t+i.
__device__ __forceinline__ void fused_mid4(v2f* d, int t)
{
  v2f* dp = d + 17*t;
#pragma unroll
  for (int q = 0; q < 4; ++q) {
    v2f a0=dp[4*q], a1=dp[4*q+1], a2=dp[4*q+2], a3=dp[4*q+3];
    v2f t0=a0+a2, t1=a0-a2, t2=a1+a3, t3=a1-a3;
    v2f it3; it3.x = -t3.y; it3.y = t3.x;           // i*t3
    v2f y0=t0+t2, y2=t0-t2, y1=t1+it3, y3=t1-it3;   // inverse (sgn=+1)
    float m0 = INV_N * sqrtf(y0.x*y0.x + y0.y*y0.y);
    float m1 = INV_N * sqrtf(y1.x*y1.x + y1.y*y1.y);
    float m2 = INV_N * sqrtf(y2.x*y2.x + y2.y*y2.y);
    float m3 = INV_N * sqrtf(y3.x*y3.x + y3.y*y3.y);
    float p0=m0+m2, p1=m0-m2, p2=m1+m3, p3=m1-m3;   // forward DFT4 on reals
    v2f o0; o0.x = p0+p2; o0.y = 0.f;
    v2f o1; o1.x = p1;    o1.y = -p3;
    v2f o2; o2.x = p0-p2; o2.y = 0.f;
    v2f o3; o3.x = p1;    o3.y = p3;
    dp[4*q]=o0; dp[4*q+1]=o1; dp[4*q+2]=o2; dp[4*q+3]=o3;
  }
}

// Full pipeline (k_order1 needs the whole half-spectrum).
__device__ __forceinline__ void mod_pipeline(v2f* d, int tid)
{
  super_dif16<+1, 1024, 10>(d, tid); __syncthreads();
  super_dif16<+1,   64,  6>(d, tid); __syncthreads();
  super_dif16<+1,    4,  2>(d, tid); __syncthreads();
  fused_mid4(d, tid);                __syncthreads();
  super_dit16<-1,    4,  2>(d, tid); __syncthreads();
  super_dit16<-1,   64,  6>(d, tid); __syncthreads();
  super_dit16<-1, 1024, 10>(d, tid); __syncthreads();
}

// Pruned pipeline (k_order2: only bins <256 of the forward transform survive).
__device__ __forceinline__ void mod_pipeline_pruned(v2f* d, int tid)
{
  super_dif16<+1, 1024, 10>(d, tid);  __syncthreads();
  super_dif16<+1,   64,  6>(d, tid);  __syncthreads();
  super_dif16<+1,    4,  2>(d, tid);  __syncthreads();
  fused_mid4(d, tid);                 __syncthreads();
  super_dit16<-1,    4,  2>(d, tid);  __syncthreads();
  super_dit16_m64_prune<-1>(d, tid);  __syncthreads();
  super_dit16_m1024_bin256<-1>(d, tid); __syncthreads();
}

// S[k] = (1/N) * Re sum_f spec[f]*phi[f]*e^{+2pi i f k/64}, Hermitian-doubled,
// phi support truncated to f < FOLD_F. 16 threads per output k.
// Phase step per f+=16 is e^{2pi i 16k/64} = i^k  (exact {0,+-1} rotation).
__device__ void fold_store16(const v2f* d, const float* __restrict__ phi, float* outp, int tid)
{
  const int k = tid >> 4, g = tid & 15;
  float sv, cv;
  __sincosf((TWO_PI/64.f) * (float)((g*k) & 63), &sv, &cv);
  const int km = k & 3;
  const float strRe = (km==0) ? 1.f : (km==2 ? -1.f : 0.f);
  const float strIm = (km==1) ? 1.f : (km==3 ? -1.f : 0.f);
  float acc = 0.f;
#pragma unroll
  for (int m = 0; m < 16; ++m) {
    const int f = g + 16*m;
    v2f u = d[pad(f)];
    float wgt = phi[f] * ((f == 0) ? 1.f : 2.f);
    acc += wgt * (u.x*cv - u.y*sv);
    float nc = cv*strRe - sv*strIm;
    float ns = cv*strIm + sv*strRe;
    cv = nc; sv = ns;
  }
  acc += __shfl_xor(acc, 1);
  acc += __shfl_xor(acc, 2);
  acc += __shfl_xor(acc, 4);
  acc += __shfl_xor(acc, 8);
  if (g == 0) outp[k] = acc * INV_N;
}

// ---- radix-4 float2 path kept only for k_fft_x (16 blocks, proven) ----
__device__ __forceinline__ float2 f2add(float2 a, float2 b){ return make_float2(a.x+b.x, a.y+b.y); }
__device__ __forceinline__ float2 f2sub(float2 a, float2 b){ return make_float2(a.x-b.x, a.y-b.y); }
__device__ __forceinline__ float2 cmul_cs(float2 a, float c, float s){
  return make_float2(a.x*c - a.y*s, a.x*s + a.y*c);
}
__device__ void dif_sweep(float2* d, int tid, float sgn, int mb_hi, int mb_lo)
{
  const float ang = sgn * (TWO_PI / (float)T_N);
  for (int mbits = mb_hi; mbits >= mb_lo; mbits -= 2) {
    const int M = 1 << mbits;
#pragma unroll 8
    for (int v = tid; v < T_N/4; v += NT) {
      const int j = v & (M-1);
      const int base = ((v >> mbits) << (mbits+2)) | j;
      const int i0 = pad(base), i1 = pad(base+M), i2 = pad(base+2*M), i3 = pad(base+3*M);
      float2 a0=d[i0], a1=d[i1], a2=d[i2], a3=d[i3];
      float2 t0=f2add(a0,a2), t1=f2sub(a0,a2), t2=f2add(a1,a3), t3=f2sub(a1,a3);
      float2 y0=f2add(t0,t2), y2=f2sub(t0,t2);
      float2 y1=make_float2(t1.x - sgn*t3.y, t1.y + sgn*t3.x);
      float2 y3=make_float2(t1.x + sgn*t3.y, t1.y - sgn*t3.x);
      float s1,c1;
      __sincosf(ang * (float)(j << (12-mbits)), &s1, &c1);
      float c2=c1*c1-s1*s1, s2=2.f*c1*s1;
      float c3=c1*c2-s1*s2, s3=c1*s2+s1*c2;
      d[i0]=y0;
      d[i1]=cmul_cs(y1,c1,s1);
      d[i2]=cmul_cs(y2,c2,s2);
      d[i3]=cmul_cs(y3,c3,s3);
    }
    __syncthreads();
  }
}
__device__ void fold_store8(const float2* d, const float* __restrict__ phi, float* outp, int tid)
{
  const int k = tid >> 3, g = tid & 7;
  float acc = 0.f;
  for (int f = g; f < FOLD_F; f += 8) {
    float2 u = d[pad(f)];
    float w = phi[f] * ((f == 0) ? 1.f : 2.f);
    float sv, cv;
    __sincosf((TWO_PI/64.f) * (float)((f*k) & 63), &sv, &cv);
    acc += w * (u.x*cv - u.y*sv);
  }
  acc += __shfl_xor(acc, 1);
  acc += __shfl_xor(acc, 2);
  acc += __shfl_xor(acc, 4);
  if (g == 0) outp[k] = acc * INV_N;
}

// K1: xh = FFT(x) (natural order, to ws) + S0 fold. 16 blocks, 512 thr.
__global__ void __launch_bounds__(NT) k_fft_x(const float* __restrict__ x, const float* __restrict__ phi,
                                              float2* __restrict__ xh, float* __restrict__ out)
{
  extern __shared__ char smem[];
  float2* d = (float2*)smem;
  const int tid = threadIdx.x;
  const int b = blockIdx.x;
  const float* xr = x + b * T_N;
  for (int i = tid; i < T_N; i += NT) d[pad(i)] = make_float2(xr[i], 0.f);
  __syncthreads();
  dif_sweep(d, tid, -1.f, 12, 0);      // forward FFT, digit-reversed result
  for (int p = tid; p < T_N; p += NT) { // unscramble in place (involution)
    int r = rev4_14(p);
    if (p < r) { int ip = pad(p), ir = pad(r); float2 t = d[ip]; d[ip] = d[ir]; d[ir] = t; }
  }
  __syncthreads();
  float2* xrow = xh + (size_t)b * T_N;
  for (int i = tid; i < T_N; i += NT) xrow[i] = d[pad(i)];
  fold_store8(d, phi, out + b * 64, tid);   // S0
}

// K2: per (b,j1): Z = xh*psi1 -> IFFT -> |.| -> FFT -> store half-spectrum U1h + S1 fold.
__global__ void __launch_bounds__(NT2, 4) k_order1(const float2* __restrict__ xh, const float* __restrict__ psi1,
                                                   const float* __restrict__ phi, float2* __restrict__ u1h,
                                                   float* __restrict__ out)
{
  extern __shared__ char smem[];
  v2f* d = (v2f*)smem;
  const int tid = threadIdx.x;
  const int b = blockIdx.x >> 6, j1 = blockIdx.x & 63;
  const float2* xrow = xh + (size_t)b * T_N;
  const float* prow = psi1 + j1 * T_N;
#pragma unroll
  for (int s = 0; s < T_N/NT2; ++s) {
    int i = tid + s*NT2;
    float2 v = xrow[i];
    float p = prow[i];
    v2f z; z.x = v.x*p; z.y = v.y*p;
    d[pad(i)] = z;
  }
  __syncthreads();
  mod_pipeline(d, tid);                 // natural-order U1h in LDS
  float2* urow = u1h + (size_t)(b * N1 + j1) * USTRIDE;
  for (int i = tid; i <= T_N/2; i += NT2) {
    v2f u = d[pad(i)];
    urow[i] = make_float2(u.x, u.y);    // bins 0..8192
  }
  fold_store16(d, phi, out + 1024 + (size_t)(b * N1 + j1) * 64, tid);  // S1
}

// K3: per (b,pair): Z = U1h[j1]*psi2[j2] (Hermitian-extend) -> IFFT -> |.| ->
// pruned FFT (bins<256) -> S2 fold.
__global__ void __launch_bounds__(NT2, 4) k_order2(const float2* __restrict__ u1h, const float* __restrict__ psi2,
                                                   const float* __restrict__ phi, const int* __restrict__ pj1,
                                                   const int* __restrict__ pj2, float* __restrict__ out)
{
  extern __shared__ char smem[];
  v2f* d = (v2f*)smem;
  const int tid = threadIdx.x;
  const int b = blockIdx.x / NPAIR, p = blockIdx.x % NPAIR;
  const int j1 = pj1[p], j2 = pj2[p];
  const float2* urow = u1h + (size_t)(b * N1 + j1) * USTRIDE;
  const float* prow = psi2 + j2 * T_N;
#pragma unroll
  for (int s = 0; s < T_N/NT2; ++s) {
    int i = tid + s*NT2;
    float2 u;
    if (i <= T_N/2) u = urow[i];
    else { float2 t = urow[T_N - i]; u = make_float2(t.x, -t.y); }  // conj mirror
    float ps = prow[i];
    v2f z; z.x = u.x*ps; z.y = u.y*ps;
    d[pad(i)] = z;
  }
  __syncthreads();
  mod_pipeline_pruned(d, tid);
  fold_store16(d, phi, out + 66560 + (size_t)(b * NPAIR + p) * 64, tid); // S2
}

extern "C" void kernel_launch(void* const* d_in, const int* in_sizes, int n_in,
                              void* d_out, int out_size, void* d_ws, size_t ws_size,
                              hipStream_t stream)
{
  const float* x    = (const float*)d_in[0];
  const float* psi1 = (const float*)d_in[1];
  const float* psi2 = (const float*)d_in[2];
  const float* phi  = (const float*)d_in[3];
  const int*   pj1  = (const int*)d_in[4];
  const int*   pj2  = (const int*)d_in[5];
  float* out = (float*)d_out;

  float2* xh  = (float2*)d_ws;                  // [16][16384] = 2 MB
  float2* u1h = xh + (size_t)B_SZ * T_N;        // [1024][USTRIDE] ~ 67 MB

  const size_t lds = (size_t)(T_N + (T_N >> 4)) * sizeof(float2);  // 139264 B

  (void)hipFuncSetAttribute((const void*)k_fft_x,  hipFuncAttributeMaxDynamicSharedMemorySize, (int)lds);
  (void)hipFuncSetAttribute((const void*)k_order1, hipFuncAttributeMaxDynamicSharedMemorySize, (int)lds);
  (void)hipFuncSetAttribute((const void*)k_order2, hipFuncAttributeMaxDynamicSharedMemorySize, (int)lds);

  hipLaunchKernelGGL(k_fft_x,  dim3(B_SZ),         dim3(NT),  lds, stream, x, phi, xh, out);
  hipLaunchKernelGGL(k_order1, dim3(B_SZ * N1),    dim3(NT2), lds, stream, xh, psi1, phi, u1h, out);
  hipLaunchKernelGGL(k_order2, dim3(B_SZ * NPAIR), dim3(NT2), lds, stream, u1h, psi2, phi, pj1, pj2, out);
}

// Round 7
// 403.133 us; speedup vs baseline: 2.1638x; 1.1038x over previous
//
#include <hip/hip_runtime.h>
#include <math.h>

// Wavelet scattering, T=16384. Register-blocked radix-16 in-LDS FFT, packed
// fp32 complex math, 1024 threads/block.
// NEW: input-pruned inverse stages (Gaussian filters are ~zero outside +-7
// sigma, so stage-1/stage-2 DIF16 use K-tap sparse DFTs over the band), plus
// store-pruned U1h (k_order2 only reads bins < W(j2min)).  Forward transform
// in k_order2 remains output-pruned to bins < 256 (phi-fold support).

#define T_N   16384
#define NT    512          // threads for k_fft_x (radix-4 path)
#define NT2   1024         // threads for pipeline kernels
#define B_SZ  16
#define N1    64
#define NPAIR 224
#define FOLD_F 256
#define USTRIDE 8208       // float2 row stride for half-spectrum
#define INV_N (1.0f/16384.0f)
#define TWO_PI 6.283185307179586f

typedef float v2f __attribute__((ext_vector_type(2)));

__device__ __forceinline__ int pad(int i) { return i + (i >> 4); }  // LDS pad

__device__ __forceinline__ v2f cmulw(v2f a, v2f w){
  v2f n; n.x = -a.y; n.y = a.x;
  return w.x * a + w.y * n;
}
__device__ __forceinline__ constexpr int br4(int x){
  return ((x&1)<<3)|((x&2)<<1)|((x&4)>>1)|((x&8)>>3);
}
__device__ __forceinline__ int rev4_14(int p){
  unsigned r = __brev((unsigned)p) >> 18;
  return (int)(((r & 0x2AAAu) >> 1) | ((r & 0x1555u) << 1));
}
__device__ __forceinline__ int pow2ceil16(int k){
  return (k<=1)?1:(k<=2)?2:(k<=4)?4:(k<=8)?8:16;
}

// Depth-4 product tree: tw[r] = w^r.
__device__ __forceinline__ void twiddle_tree(v2f w, v2f* tw){
  tw[0].x = 1.f; tw[0].y = 0.f;
  tw[1] = w;
  tw[2] = cmulw(w, w);
  tw[4] = cmulw(tw[2], tw[2]);
  tw[8] = cmulw(tw[4], tw[4]);
  tw[3] = cmulw(tw[2], w);
  tw[5] = cmulw(tw[4], w);
  tw[6] = cmulw(tw[4], tw[2]);
  tw[7] = cmulw(tw[4], tw[3]);
  tw[9]  = cmulw(tw[8], w);
  tw[10] = cmulw(tw[8], tw[2]);
  tw[11] = cmulw(tw[8], tw[3]);
  tw[12] = cmulw(tw[8], tw[4]);
  tw[13] = cmulw(tw[8], tw[5]);
  tw[14] = cmulw(tw[8], tw[6]);
  tw[15] = cmulw(tw[8], tw[7]);
}

// Fully-unrolled DFT16; result y[r] lands at a[br4(r)].
template<int SGN>
__device__ __forceinline__ void dft16(v2f* a){
  static constexpr float C16[16] = {
    1.f, 0.98078528f, 0.92387953f, 0.83146961f, 0.70710678f, 0.55557023f,
    0.38268343f, 0.19509032f, 0.f, -0.19509032f, -0.38268343f, -0.55557023f,
    -0.70710678f, -0.83146961f, -0.92387953f, -0.98078528f };
  static constexpr float S16[16] = {
    0.f, 0.19509032f, 0.38268343f, 0.55557023f, 0.70710678f, 0.83146961f,
    0.92387953f, 0.98078528f, 1.f, 0.98078528f, 0.92387953f, 0.83146961f,
    0.70710678f, 0.55557023f, 0.38268343f, 0.19509032f };
#pragma unroll
  for (int m = 8; m >= 1; m >>= 1) {
#pragma unroll
    for (int base = 0; base < 16; base += 2*m) {
#pragma unroll
      for (int j = 0; j < m; ++j) {
        v2f u = a[base+j], v = a[base+j+m];
        a[base+j] = u + v;
        v2f w = u - v;
        const int ti = (j*16)/m;
        v2f tw; tw.x = C16[ti]; tw.y = (float)SGN * S16[ti];
        a[base+j+m] = cmulw(w, tw);
      }
    }
  }
}

// Full DIF super-stage radix-16 at stride M.
template<int SGN, int M, int LOGM>
__device__ __forceinline__ void super_dif16(v2f* d, int g)
{
  const int j = g & (M-1);
  const int base = ((g >> LOGM) << (LOGM+4)) | j;
  v2f* dp = d + pad(base);
  v2f a[16];
#pragma unroll
  for (int k = 0; k < 16; ++k) a[k] = dp[k*M + ((k*M)>>4)];
  dft16<SGN>(a);
  float sj, cj;
  __sincosf((float)SGN * (TWO_PI / (16.f*(float)M)) * (float)j, &sj, &cj);
  v2f w; w.x = cj; w.y = sj;
  v2f tw[16];
  twiddle_tree(w, tw);
  dp[0] = a[0];
#pragma unroll
  for (int r = 1; r < 16; ++r)
    dp[r*M + ((r*M)>>4)] = cmulw(a[br4(r)], tw[r]);
}

// SPARSE DIF super-stage: only taps k in [k0, k0+K) are (possibly) nonzero;
// positions outside the window MUST hold zeros.  All 16 outputs written.
// y[r0+(16/K)r1] = DFT_K(a_m * W16^{SGN r0 m}); window phase folded into the
// output twiddle via jeff = j + k0*M.
template<int SGN, int M, int LOGM, int K>
__device__ __forceinline__ void super_dif16_sparse(v2f* d, int g, int k0)
{
  static constexpr float CW[16] = { 1.f, 0.92387953f, 0.70710678f, 0.38268343f,
    0.f, -0.38268343f, -0.70710678f, -0.92387953f, -1.f, -0.92387953f,
    -0.70710678f, -0.38268343f, 0.f, 0.38268343f, 0.70710678f, 0.92387953f };
  static constexpr float SW[16] = { 0.f, 0.38268343f, 0.70710678f, 0.92387953f,
    1.f, 0.92387953f, 0.70710678f, 0.38268343f, 0.f, -0.38268343f,
    -0.70710678f, -0.92387953f, -1.f, -0.92387953f, -0.70710678f, -0.38268343f };
  const int j = g & (M-1);
  const int base = ((g >> LOGM) << (LOGM+4)) | j;
  v2f* dp = d + pad(base);
  v2f a[K];
#pragma unroll
  for (int m = 0; m < K; ++m) {
    const int k = k0 + m;
    a[m] = dp[k*M + ((k*M)>>4)];
  }
  v2f y[16];
  if constexpr (K == 1) {
#pragma unroll
    for (int r = 0; r < 16; ++r) y[r] = a[0];
  } else if constexpr (K == 2) {
#pragma unroll
    for (int r0 = 0; r0 < 8; ++r0) {
      v2f w; w.x = CW[r0]; w.y = (float)SGN * SW[r0];
      v2f b1 = cmulw(a[1], w);
      y[r0]   = a[0] + b1;
      y[r0+8] = a[0] - b1;
    }
  } else if constexpr (K == 4) {
#pragma unroll
    for (int r0 = 0; r0 < 4; ++r0) {
      v2f z1, z2, z3;
      { v2f w; w.x = CW[r0];        w.y = (float)SGN*SW[r0];        z1 = cmulw(a[1], w); }
      { v2f w; w.x = CW[(2*r0)&15]; w.y = (float)SGN*SW[(2*r0)&15]; z2 = cmulw(a[2], w); }
      { v2f w; w.x = CW[(3*r0)&15]; w.y = (float)SGN*SW[(3*r0)&15]; z3 = cmulw(a[3], w); }
      v2f e0 = a[0]+z2, e1 = a[0]-z2, o0 = z1+z3, o1 = z1-z3;
      v2f io; io.x = -(float)SGN*o1.y; io.y = (float)SGN*o1.x;
      y[r0]    = e0 + o0;
      y[r0+4]  = e1 + io;
      y[r0+8]  = e0 - o0;
      y[r0+12] = e1 - io;
    }
  } else { // K == 8
#pragma unroll
    for (int r0 = 0; r0 < 2; ++r0) {
      v2f z[8];
      z[0] = a[0];
#pragma unroll
      for (int m = 1; m < 8; ++m) {
        v2f w; w.x = CW[(m*r0)&15]; w.y = (float)SGN*SW[(m*r0)&15];
        z[m] = cmulw(a[m], w);
      }
      v2f E[4], O[4];
      {
        v2f e0=z[0]+z[4], e1=z[0]-z[4], o0=z[2]+z[6], o1=z[2]-z[6];
        v2f io; io.x=-(float)SGN*o1.y; io.y=(float)SGN*o1.x;
        E[0]=e0+o0; E[1]=e1+io; E[2]=e0-o0; E[3]=e1-io;
      }
      {
        v2f e0=z[1]+z[5], e1=z[1]-z[5], o0=z[3]+z[7], o1=z[3]-z[7];
        v2f io; io.x=-(float)SGN*o1.y; io.y=(float)SGN*o1.x;
        O[0]=e0+o0; O[1]=e1+io; O[2]=e0-o0; O[3]=e1-io;
      }
      constexpr float RT = 0.70710678f;
#pragma unroll
      for (int r1 = 0; r1 < 4; ++r1) {
        v2f w8;
        if (r1 == 0)      { w8.x = 1.f;  w8.y = 0.f; }
        else if (r1 == 1) { w8.x = RT;   w8.y = (float)SGN*RT; }
        else if (r1 == 2) { w8.x = 0.f;  w8.y = (float)SGN; }
        else              { w8.x = -RT;  w8.y = (float)SGN*RT; }
        v2f t = cmulw(O[r1], w8);
        y[2*r1 + r0]     = E[r1] + t;
        y[2*r1 + r0 + 8] = E[r1] - t;
      }
    }
  }
  float sj, cj;
  __sincosf((float)SGN * (TWO_PI / (16.f*(float)M)) * (float)(j + k0*M), &sj, &cj);
  v2f w; w.x = cj; w.y = sj;
  v2f tw[16];
  twiddle_tree(w, tw);
  dp[0] = y[0];
#pragma unroll
  for (int r = 1; r < 16; ++r)
    dp[r*M + ((r*M)>>4)] = cmulw(y[r], tw[r]);
}

// Block-uniform dispatch helpers (include trailing barrier).
__device__ __forceinline__ void stage1_dispatch(v2f* d, int tid, int k0, int K1, int jlo, int jhi)
{
  if (K1 == 16)     super_dif16<+1, 1024, 10>(d, tid);
  else if (K1 == 8) super_dif16_sparse<+1,1024,10,8>(d, tid, k0);
  else if (K1 == 4) super_dif16_sparse<+1,1024,10,4>(d, tid, k0);
  else if (K1 == 2) super_dif16_sparse<+1,1024,10,2>(d, tid, k0);
  else { if (tid >= jlo && tid < jhi) super_dif16_sparse<+1,1024,10,1>(d, tid, k0); }
  __syncthreads();
}
__device__ __forceinline__ void stage2_dispatch(v2f* d, int tid, int k0, int K2)
{
  if (K2 == 16)     super_dif16<+1, 64, 6>(d, tid);
  else if (K2 == 8) super_dif16_sparse<+1,64,6,8>(d, tid, k0);
  else if (K2 == 4) super_dif16_sparse<+1,64,6,4>(d, tid, k0);
  else if (K2 == 2) super_dif16_sparse<+1,64,6,2>(d, tid, k0);
  else              super_dif16_sparse<+1,64,6,1>(d, tid, k0);
  __syncthreads();
}

// Full DIT super-stage radix-16 at stride M (twiddle-before-combine).
template<int SGN, int M, int LOGM>
__device__ __forceinline__ void super_dit16(v2f* d, int g)
{
  const int j = g & (M-1);
  const int base = ((g >> LOGM) << (LOGM+4)) | j;
  v2f* dp = d + pad(base);
  float sj, cj;
  __sincosf((float)SGN * (TWO_PI / (16.f*(float)M)) * (float)j, &sj, &cj);
  v2f w; w.x = cj; w.y = sj;
  v2f tw[16];
  twiddle_tree(w, tw);
  v2f a[16];
  a[0] = dp[0];
#pragma unroll
  for (int k = 1; k < 16; ++k)
    a[k] = cmulw(dp[k*M + ((k*M)>>4)], tw[k]);
  dft16<SGN>(a);
#pragma unroll
  for (int r = 0; r < 16; ++r) dp[r*M + ((r*M)>>4)] = a[br4(r)];
}

// PRUNED DIT16 at M=64: only outputs r<4 needed.
template<int SGN>
__device__ __forceinline__ void super_dit16_m64_prune(v2f* d, int g)
{
  constexpr int M = 64;
  constexpr int PSTR = M + (M>>4);
  const int j = g & 63;
  const int base = ((g >> 6) << 10) | j;
  v2f* dp = d + pad(base);
  float sj, cj;
  __sincosf((float)SGN * (TWO_PI / 1024.f) * (float)j, &sj, &cj);
  v2f w; w.x = cj; w.y = sj;
  v2f tw[16];
  twiddle_tree(w, tw);
  v2f a[16];
  a[0] = dp[0];
#pragma unroll
  for (int k = 1; k < 16; ++k)
    a[k] = cmulw(dp[k*M + ((k*M)>>4)], tw[k]);
  v2f Y[4][4];
#pragma unroll
  for (int c = 0; c < 4; ++c) {
    v2f s0=a[c], s1=a[c+4], s2=a[c+8], s3=a[c+12];
    v2f e0 = s0+s2, e1 = s0-s2, o0 = s1+s3, o1 = s1-s3;
    v2f io1; io1.x = -(float)SGN * o1.y; io1.y = (float)SGN * o1.x;
    Y[c][0] = e0 + o0;
    Y[c][1] = e1 + io1;
    Y[c][2] = e0 - o0;
    Y[c][3] = e1 - io1;
  }
  static constexpr float WC[10] = {1.f,0.92387953f,0.70710678f,0.38268343f,0.f,
                                   -0.38268343f,-0.70710678f,-0.92387953f,-1.f,-0.92387953f};
  static constexpr float WS[10] = {0.f,0.38268343f,0.70710678f,0.92387953f,1.f,
                                   0.92387953f,0.70710678f,0.38268343f,0.f,-0.38268343f};
#pragma unroll
  for (int r = 0; r < 4; ++r) {
    v2f acc = Y[0][r];
#pragma unroll
    for (int c = 1; c < 4; ++c) {
      v2f wc; wc.x = WC[r*c]; wc.y = (float)SGN * WS[r*c];
      acc += cmulw(Y[c][r], wc);
    }
    dp[r*PSTR] = acc;
  }
}

// PRUNED final DIT16 at M=1024: only bins j<256.
template<int SGN>
__device__ __forceinline__ void super_dit16_m1024_bin256(v2f* d, int tid)
{
  if (tid < 256) {
    const int j = tid;
    v2f* dp = d + pad(j);
    float sj, cj;
    __sincosf((float)SGN * (TWO_PI / 16384.f) * (float)j, &sj, &cj);
    v2f w; w.x = cj; w.y = sj;
    v2f tw[16];
    twiddle_tree(w, tw);
    v2f acc = dp[0];
#pragma unroll
    for (int k = 1; k < 16; ++k)
      acc += cmulw(dp[k*1024 + ((k*1024)>>4)], tw[k]);
    dp[0] = acc;
  }
}

// Fused middle: inverse DFT4 -> |.|/N -> forward DFT4 on contiguous 16.
__device__ __forceinline__ void fused_mid4(v2f* d, int t)
{
  v2f* dp = d + 17*t;
#pragma unroll
  for (int q = 0; q < 4; ++q) {
    v2f a0=dp[4*q], a1=dp[4*q+1], a2=dp[4*q+2], a3=dp[4*q+3];
    v2f t0=a0+a2, t1=a0-a2, t2=a1+a3, t3=a1-a3;
    v2f it3; it3.x = -t3.y; it3.y = t3.x;
    v2f y0=t0+t2, y2=t0-t2, y1=t1+it3, y3=t1-it3;
    float m0 = INV_N * sqrtf(y0.x*y0.x + y0.y*y0.y);
    float m1 = INV_N * sqrtf(y1.x*y1.x + y1.y*y1.y);
    float m2 = INV_N * sqrtf(y2.x*y2.x + y2.y*y2.y);
    float m3 = INV_N * sqrtf(y3.x*y3.x + y3.y*y3.y);
    float p0=m0+m2, p1=m0-m2, p2=m1+m3, p3=m1-m3;
    v2f o0; o0.x = p0+p2; o0.y = 0.f;
    v2f o1; o1.x = p1;    o1.y = -p3;
    v2f o2; o2.x = p0-p2; o2.y = 0.f;
    v2f o3; o3.x = p1;    o3.y = p3;
    dp[4*q]=o0; dp[4*q+1]=o1; dp[4*q+2]=o2; dp[4*q+3]=o3;
  }
}

// phi-fold: S[k] = (1/N) Re sum_{f<256} spec[f]*phi[f]*e^{+2pi i f k/64}*herm.
__device__ void fold_store16(const v2f* d, const float* __restrict__ phi, float* outp, int tid)
{
  const int k = tid >> 4, g = tid & 15;
  float sv, cv;
  __sincosf((TWO_PI/64.f) * (float)((g*k) & 63), &sv, &cv);
  const int km = k & 3;
  const float strRe = (km==0) ? 1.f : (km==2 ? -1.f : 0.f);
  const float strIm = (km==1) ? 1.f : (km==3 ? -1.f : 0.f);
  float acc = 0.f;
#pragma unroll
  for (int m = 0; m < 16; ++m) {
    const int f = g + 16*m;
    v2f u = d[pad(f)];
    float wgt = phi[f] * ((f == 0) ? 1.f : 2.f);
    acc += wgt * (u.x*cv - u.y*sv);
    float nc = cv*strRe - sv*strIm;
    float ns = cv*strIm + sv*strRe;
    cv = nc; sv = ns;
  }
  acc += __shfl_xor(acc, 1);
  acc += __shfl_xor(acc, 2);
  acc += __shfl_xor(acc, 4);
  acc += __shfl_xor(acc, 8);
  if (g == 0) outp[k] = acc * INV_N;
}

// ---- radix-4 float2 path for k_fft_x ----
__device__ __forceinline__ float2 f2add(float2 a, float2 b){ return make_float2(a.x+b.x, a.y+b.y); }
__device__ __forceinline__ float2 f2sub(float2 a, float2 b){ return make_float2(a.x-b.x, a.y-b.y); }
__device__ __forceinline__ float2 cmul_cs(float2 a, float c, float s){
  return make_float2(a.x*c - a.y*s, a.x*s + a.y*c);
}
__device__ void dif_sweep(float2* d, int tid, float sgn, int mb_hi, int mb_lo)
{
  const float ang = sgn * (TWO_PI / (float)T_N);
  for (int mbits = mb_hi; mbits >= mb_lo; mbits -= 2) {
    const int M = 1 << mbits;
#pragma unroll 8
    for (int v = tid; v < T_N/4; v += NT) {
      const int j = v & (M-1);
      const int base = ((v >> mbits) << (mbits+2)) | j;
      const int i0 = pad(base), i1 = pad(base+M), i2 = pad(base+2*M), i3 = pad(base+3*M);
      float2 a0=d[i0], a1=d[i1], a2=d[i2], a3=d[i3];
      float2 t0=f2add(a0,a2), t1=f2sub(a0,a2), t2=f2add(a1,a3), t3=f2sub(a1,a3);
      float2 y0=f2add(t0,t2), y2=f2sub(t0,t2);
      float2 y1=make_float2(t1.x - sgn*t3.y, t1.y + sgn*t3.x);
      float2 y3=make_float2(t1.x + sgn*t3.y, t1.y - sgn*t3.x);
      float s1,c1;
      __sincosf(ang * (float)(j << (12-mbits)), &s1, &c1);
      float c2=c1*c1-s1*s1, s2=2.f*c1*s1;
      float c3=c1*c2-s1*s2, s3=c1*s2+s1*c2;
      d[i0]=y0;
      d[i1]=cmul_cs(y1,c1,s1);
      d[i2]=cmul_cs(y2,c2,s2);
      d[i3]=cmul_cs(y3,c3,s3);
    }
    __syncthreads();
  }
}
__device__ void fold_store8(const float2* d, const float* __restrict__ phi, float* outp, int tid)
{
  const int k = tid >> 3, g = tid & 7;
  float acc = 0.f;
  for (int f = g; f < FOLD_F; f += 8) {
    float2 u = d[pad(f)];
    float w = phi[f] * ((f == 0) ? 1.f : 2.f);
    float sv, cv;
    __sincosf((TWO_PI/64.f) * (float)((f*k) & 63), &sv, &cv);
    acc += w * (u.x*cv - u.y*sv);
  }
  acc += __shfl_xor(acc, 1);
  acc += __shfl_xor(acc, 2);
  acc += __shfl_xor(acc, 4);
  if (g == 0) outp[k] = acc * INV_N;
}

// K1: xh = FFT(x) + S0 fold. 16 blocks, 512 thr.
__global__ void __launch_bounds__(NT) k_fft_x(const float* __restrict__ x, const float* __restrict__ phi,
                                              float2* __restrict__ xh, float* __restrict__ out)
{
  extern __shared__ char smem[];
  float2* d = (float2*)smem;
  const int tid = threadIdx.x;
  const int b = blockIdx.x;
  const float* xr = x + b * T_N;
  for (int i = tid; i < T_N; i += NT) d[pad(i)] = make_float2(xr[i], 0.f);
  __syncthreads();
  dif_sweep(d, tid, -1.f, 12, 0);
  for (int p = tid; p < T_N; p += NT) {
    int r = rev4_14(p);
    if (p < r) { int ip = pad(p), ir = pad(r); float2 t = d[ip]; d[ip] = d[ir]; d[ir] = t; }
  }
  __syncthreads();
  float2* xrow = xh + (size_t)b * T_N;
  for (int i = tid; i < T_N; i += NT) xrow[i] = d[pad(i)];
  fold_store8(d, phi, out + b * 64, tid);   // S0
}

// Store bound for U1h per j1-octave: widest psi2 among valid pairs (j2>q).
__device__ __constant__ int SBTAB[8] = {8193, 6452, 3226, 1613, 807, 404, 202, 0};
// psi2 band [0, W), W = ceil(4.5 * 5734.4 * 2^-j2)
__device__ __constant__ int WTAB[8]  = {16384, 12903, 6452, 3226, 1613, 807, 404, 202};

// K2: per (b,j1): Z = xh*psi1 (band [lo,hi)) -> sparse IFFT -> |.| -> FFT
//     -> store pruned half-spectrum + S1 fold.
__global__ void __launch_bounds__(NT2, 4) k_order1(const float2* __restrict__ xh, const float* __restrict__ psi1,
                                                   const float* __restrict__ phi, float2* __restrict__ u1h,
                                                   float* __restrict__ out)
{
  extern __shared__ char smem[];
  v2f* d = (v2f*)smem;
  const int tid = threadIdx.x;
  const int b = blockIdx.x >> 6, j1 = blockIdx.x & 63;
  const float2* xrow = xh + (size_t)b * T_N;
  const float* prow = psi1 + j1 * T_N;
  // psi1 band: center c, sigma = 0.0905c, +-7 sigma ~ [0.366c, 1.634c]
  const float c = 5734.4f * exp2f(-0.125f * (float)j1);
  const int lo = max(0, (int)(0.36f * c));
  const int hi = min(T_N, (int)(1.64f * c) + 2);
#pragma unroll
  for (int s = 0; s < T_N/NT2; ++s) {
    int i = tid + s*NT2;
    v2f z; z.x = 0.f; z.y = 0.f;
    if (i >= lo && i < hi) {
      float2 v = xrow[i];
      float p = prow[i];
      z.x = v.x*p; z.y = v.y*p;
    }
    d[pad(i)] = z;
  }
  __syncthreads();
  // sparse stage dispatch
  const int k_lo = lo >> 10, k_hi = (hi + 1023) >> 10;
  const int K1 = pow2ceil16(k_hi - k_lo);
  const int k0 = min(k_lo, 16 - K1);
  int jlo = 0, jhi = NT2, k0_2 = 0, K2 = 16;
  if (K1 == 1) {
    jlo = lo - (k_lo << 10); jhi = hi - (k_lo << 10);
    const int k2_lo = jlo >> 6, k2_hi = (jhi + 63) >> 6;
    K2 = pow2ceil16(k2_hi - k2_lo);
    k0_2 = min(k2_lo, 16 - K2);
  }
  stage1_dispatch(d, tid, k0, K1, jlo, jhi);
  stage2_dispatch(d, tid, k0_2, K2);
  super_dif16<+1, 4, 2>(d, tid);     __syncthreads();
  fused_mid4(d, tid);                __syncthreads();
  super_dit16<-1, 4, 2>(d, tid);     __syncthreads();
  super_dit16<-1, 64, 6>(d, tid);    __syncthreads();
  super_dit16<-1, 1024, 10>(d, tid); __syncthreads();
  // pruned half-spectrum store (k_order2 only reads bins < SBTAB[j1>>3])
  const int sb = SBTAB[j1 >> 3];
  float2* urow = u1h + (size_t)(b * N1 + j1) * USTRIDE;
  for (int i = tid; i < sb; i += NT2) {
    v2f u = d[pad(i)];
    urow[i] = make_float2(u.x, u.y);
  }
  fold_store16(d, phi, out + 1024 + (size_t)(b * N1 + j1) * 64, tid);  // S1
}

// K3: per (b,pair): Z = U1h[j1]*psi2[j2] (band [0,W)) -> sparse IFFT -> |.|
//     -> output-pruned FFT (bins<256) -> S2 fold.
__global__ void __launch_bounds__(NT2, 4) k_order2(const float2* __restrict__ u1h, const float* __restrict__ psi2,
                                                   const float* __restrict__ phi, const int* __restrict__ pj1,
                                                   const int* __restrict__ pj2, float* __restrict__ out)
{
  extern __shared__ char smem[];
  v2f* d = (v2f*)smem;
  const int tid = threadIdx.x;
  const int b = blockIdx.x / NPAIR, p = blockIdx.x % NPAIR;
  const int j1 = pj1[p], j2 = pj2[p];
  const float2* urow = u1h + (size_t)(b * N1 + j1) * USTRIDE;
  const float* prow = psi2 + j2 * T_N;
  const int W = WTAB[j2 & 7];
#pragma unroll
  for (int s = 0; s < T_N/NT2; ++s) {
    int i = tid + s*NT2;
    v2f z; z.x = 0.f; z.y = 0.f;
    if (i < W) {
      float2 u;
      if (i <= T_N/2) u = urow[i];
      else { float2 t = urow[T_N - i]; u = make_float2(t.x, -t.y); }
      float ps = prow[i];
      z.x = u.x*ps; z.y = u.y*ps;
    }
    d[pad(i)] = z;
  }
  __syncthreads();
  const int K1 = pow2ceil16((W + 1023) >> 10);
  int k0_2 = 0, K2 = 16;
  if (K1 == 1) {
    K2 = pow2ceil16((W + 63) >> 6);
  }
  stage1_dispatch(d, tid, 0, K1, 0, W);
  stage2_dispatch(d, tid, k0_2, K2);
  super_dif16<+1, 4, 2>(d, tid);      __syncthreads();
  fused_mid4(d, tid);                 __syncthreads();
  super_dit16<-1, 4, 2>(d, tid);      __syncthreads();
  super_dit16_m64_prune<-1>(d, tid);  __syncthreads();
  super_dit16_m1024_bin256<-1>(d, tid); __syncthreads();
  fold_store16(d, phi, out + 66560 + (size_t)(b * NPAIR + p) * 64, tid); // S2
}

extern "C" void kernel_launch(void* const* d_in, const int* in_sizes, int n_in,
                              void* d_out, int out_size, void* d_ws, size_t ws_size,
                              hipStream_t stream)
{
  const float* x    = (const float*)d_in[0];
  const float* psi1 = (const float*)d_in[1];
  const float* psi2 = (const float*)d_in[2];
  const float* phi  = (const float*)d_in[3];
  const int*   pj1  = (const int*)d_in[4];
  const int*   pj2  = (const int*)d_in[5];
  float* out = (float*)d_out;

  float2* xh  = (float2*)d_ws;                  // [16][16384] = 2 MB
  float2* u1h = xh + (size_t)B_SZ * T_N;        // [1024][USTRIDE] ~ 67 MB

  const size_t lds = (size_t)(T_N + (T_N >> 4)) * sizeof(float2);  // 139264 B

  (void)hipFuncSetAttribute((const void*)k_fft_x,  hipFuncAttributeMaxDynamicSharedMemorySize, (int)lds);
  (void)hipFuncSetAttribute((const void*)k_order1, hipFuncAttributeMaxDynamicSharedMemorySize, (int)lds);
  (void)hipFuncSetAttribute((const void*)k_order2, hipFuncAttributeMaxDynamicSharedMemorySize, (int)lds);

  hipLaunchKernelGGL(k_fft_x,  dim3(B_SZ),         dim3(NT),  lds, stream, x, phi, xh, out);
  hipLaunchKernelGGL(k_order1, dim3(B_SZ * N1),    dim3(NT2), lds, stream, xh, psi1, phi, u1h, out);
  hipLaunchKernelGGL(k_order2, dim3(B_SZ * NPAIR), dim3(NT2), lds, stream, u1h, psi2, phi, pj1, pj2, out);
}

// Round 8
// 313.764 us; speedup vs baseline: 2.7801x; 1.2848x over previous
//
#include <hip/hip_runtime.h>
#include <math.h>

// Wavelet scattering, T=16384.  Radix-16 register-blocked in-LDS FFTs.
// k_order2 now runs per-j2 DECIMATED pipelines: Z2 has support [0,W), so a
// length-N' (N' ~ 2.5W, pow2) inverse DFT gives exact decimated time samples;
// modulus + forward N'-DFT bins<256 approximate the full-grid result with
// only sqrt-envelope aliasing (phi kills f>~190).  Pairs packed PPB=16384/N'
// per 1024-thread block; fold scale 1/N', mid scale stays 1/T.

#define T_N   16384
#define NT    512
#define NT2   1024
#define B_SZ  16
#define N1    64
#define NPAIR 224
#define FOLD_F 256
#define USTRIDE 8208
#define INV_N (1.0f/16384.0f)
#define TWO_PI 6.283185307179586f

typedef float v2f __attribute__((ext_vector_type(2)));

__device__ __forceinline__ int pad(int i) { return i + (i >> 4); }

__device__ __forceinline__ v2f cmulw(v2f a, v2f w){
  v2f n; n.x = -a.y; n.y = a.x;
  return w.x * a + w.y * n;
}
__device__ __forceinline__ constexpr int br4(int x){
  return ((x&1)<<3)|((x&2)<<1)|((x&4)>>1)|((x&8)>>3);
}
template<int LB>
__device__ __forceinline__ constexpr int brN(int x){
  int r=0;
  for(int i=0;i<LB;++i){ r=(r<<1)|((x>>i)&1); }
  return r;
}
__device__ __forceinline__ int rev4_14(int p){
  unsigned r = __brev((unsigned)p) >> 18;
  return (int)(((r & 0x2AAAu) >> 1) | ((r & 0x1555u) << 1));
}
__device__ __forceinline__ int pow2ceil16(int k){
  return (k<=1)?1:(k<=2)?2:(k<=4)?4:(k<=8)?8:16;
}

// tw[r] = w^r via depth-4 product tree.
__device__ __forceinline__ void twiddle_tree(v2f w, v2f* tw){
  tw[0].x = 1.f; tw[0].y = 0.f;
  tw[1] = w;
  tw[2] = cmulw(w, w);
  tw[4] = cmulw(tw[2], tw[2]);
  tw[8] = cmulw(tw[4], tw[4]);
  tw[3] = cmulw(tw[2], w);
  tw[5] = cmulw(tw[4], w);
  tw[6] = cmulw(tw[4], tw[2]);
  tw[7] = cmulw(tw[4], tw[3]);
  tw[9]  = cmulw(tw[8], w);
  tw[10] = cmulw(tw[8], tw[2]);
  tw[11] = cmulw(tw[8], tw[3]);
  tw[12] = cmulw(tw[8], tw[4]);
  tw[13] = cmulw(tw[8], tw[5]);
  tw[14] = cmulw(tw[8], tw[6]);
  tw[15] = cmulw(tw[8], tw[7]);
}

// Generic fully-unrolled DFT of size 2^LOGNN (<=16); y[r] lands at a[brN(r)].
template<int SGN, int LOGNN>
__device__ __forceinline__ void dft_reg(v2f* a){
  constexpr int NN = 1<<LOGNN;
  static constexpr float C16[16] = {
    1.f, 0.98078528f, 0.92387953f, 0.83146961f, 0.70710678f, 0.55557023f,
    0.38268343f, 0.19509032f, 0.f, -0.19509032f, -0.38268343f, -0.55557023f,
    -0.70710678f, -0.83146961f, -0.92387953f, -0.98078528f };
  static constexpr float S16[16] = {
    0.f, 0.19509032f, 0.38268343f, 0.55557023f, 0.70710678f, 0.83146961f,
    0.92387953f, 0.98078528f, 1.f, 0.98078528f, 0.92387953f, 0.83146961f,
    0.70710678f, 0.55557023f, 0.38268343f, 0.19509032f };
#pragma unroll
  for (int m = NN/2; m >= 1; m >>= 1) {
#pragma unroll
    for (int base = 0; base < NN; base += 2*m) {
#pragma unroll
      for (int j = 0; j < m; ++j) {
        v2f u = a[base+j], v = a[base+j+m];
        a[base+j] = u + v;
        v2f w = u - v;
        const int ti = (j*16)/m;
        v2f tw; tw.x = C16[ti]; tw.y = (float)SGN * S16[ti];
        a[base+j+m] = cmulw(w, tw);
      }
    }
  }
}
template<int SGN>
__device__ __forceinline__ void dft16(v2f* a){ dft_reg<SGN,4>(a); }

// Full DIF super-stage radix-16 at stride M.
template<int SGN, int M, int LOGM>
__device__ __forceinline__ void super_dif16(v2f* d, int g)
{
  const int j = g & (M-1);
  const int base = ((g >> LOGM) << (LOGM+4)) | j;
  v2f* dp = d + pad(base);
  v2f a[16];
#pragma unroll
  for (int k = 0; k < 16; ++k) a[k] = dp[k*M + ((k*M)>>4)];
  dft16<SGN>(a);
  float sj, cj;
  __sincosf((float)SGN * (TWO_PI / (16.f*(float)M)) * (float)j, &sj, &cj);
  v2f w; w.x = cj; w.y = sj;
  v2f tw[16];
  twiddle_tree(w, tw);
  dp[0] = a[0];
#pragma unroll
  for (int r = 1; r < 16; ++r)
    dp[r*M + ((r*M)>>4)] = cmulw(a[br4(r)], tw[r]);
}

// SPARSE DIF super-stage: only taps [k0,k0+K) possibly nonzero (rest zeros).
template<int SGN, int M, int LOGM, int K>
__device__ __forceinline__ void super_dif16_sparse(v2f* d, int g, int k0)
{
  static constexpr float CW[16] = { 1.f, 0.92387953f, 0.70710678f, 0.38268343f,
    0.f, -0.38268343f, -0.70710678f, -0.92387953f, -1.f, -0.92387953f,
    -0.70710678f, -0.38268343f, 0.f, 0.38268343f, 0.70710678f, 0.92387953f };
  static constexpr float SW[16] = { 0.f, 0.38268343f, 0.70710678f, 0.92387953f,
    1.f, 0.92387953f, 0.70710678f, 0.38268343f, 0.f, -0.38268343f,
    -0.70710678f, -0.92387953f, -1.f, -0.92387953f, -0.70710678f, -0.38268343f };
  const int j = g & (M-1);
  const int base = ((g >> LOGM) << (LOGM+4)) | j;
  v2f* dp = d + pad(base);
  v2f a[K];
#pragma unroll
  for (int m = 0; m < K; ++m) {
    const int k = k0 + m;
    a[m] = dp[k*M + ((k*M)>>4)];
  }
  v2f y[16];
  if constexpr (K == 1) {
#pragma unroll
    for (int r = 0; r < 16; ++r) y[r] = a[0];
  } else if constexpr (K == 2) {
#pragma unroll
    for (int r0 = 0; r0 < 8; ++r0) {
      v2f w; w.x = CW[r0]; w.y = (float)SGN * SW[r0];
      v2f b1 = cmulw(a[1], w);
      y[r0]   = a[0] + b1;
      y[r0+8] = a[0] - b1;
    }
  } else if constexpr (K == 4) {
#pragma unroll
    for (int r0 = 0; r0 < 4; ++r0) {
      v2f z1, z2, z3;
      { v2f w; w.x = CW[r0];        w.y = (float)SGN*SW[r0];        z1 = cmulw(a[1], w); }
      { v2f w; w.x = CW[(2*r0)&15]; w.y = (float)SGN*SW[(2*r0)&15]; z2 = cmulw(a[2], w); }
      { v2f w; w.x = CW[(3*r0)&15]; w.y = (float)SGN*SW[(3*r0)&15]; z3 = cmulw(a[3], w); }
      v2f e0 = a[0]+z2, e1 = a[0]-z2, o0 = z1+z3, o1 = z1-z3;
      v2f io; io.x = -(float)SGN*o1.y; io.y = (float)SGN*o1.x;
      y[r0]    = e0 + o0;
      y[r0+4]  = e1 + io;
      y[r0+8]  = e0 - o0;
      y[r0+12] = e1 - io;
    }
  } else { // K == 8
#pragma unroll
    for (int r0 = 0; r0 < 2; ++r0) {
      v2f z[8];
      z[0] = a[0];
#pragma unroll
      for (int m = 1; m < 8; ++m) {
        v2f w; w.x = CW[(m*r0)&15]; w.y = (float)SGN*SW[(m*r0)&15];
        z[m] = cmulw(a[m], w);
      }
      v2f E[4], O[4];
      {
        v2f e0=z[0]+z[4], e1=z[0]-z[4], o0=z[2]+z[6], o1=z[2]-z[6];
        v2f io; io.x=-(float)SGN*o1.y; io.y=(float)SGN*o1.x;
        E[0]=e0+o0; E[1]=e1+io; E[2]=e0-o0; E[3]=e1-io;
      }
      {
        v2f e0=z[1]+z[5], e1=z[1]-z[5], o0=z[3]+z[7], o1=z[3]-z[7];
        v2f io; io.x=-(float)SGN*o1.y; io.y=(float)SGN*o1.x;
        O[0]=e0+o0; O[1]=e1+io; O[2]=e0-o0; O[3]=e1-io;
      }
      constexpr float RT = 0.70710678f;
#pragma unroll
      for (int r1 = 0; r1 < 4; ++r1) {
        v2f w8;
        if (r1 == 0)      { w8.x = 1.f;  w8.y = 0.f; }
        else if (r1 == 1) { w8.x = RT;   w8.y = (float)SGN*RT; }
        else if (r1 == 2) { w8.x = 0.f;  w8.y = (float)SGN; }
        else              { w8.x = -RT;  w8.y = (float)SGN*RT; }
        v2f t = cmulw(O[r1], w8);
        y[2*r1 + r0]     = E[r1] + t;
        y[2*r1 + r0 + 8] = E[r1] - t;
      }
    }
  }
  float sj, cj;
  __sincosf((float)SGN * (TWO_PI / (16.f*(float)M)) * (float)(j + k0*M), &sj, &cj);
  v2f w; w.x = cj; w.y = sj;
  v2f tw[16];
  twiddle_tree(w, tw);
  dp[0] = y[0];
#pragma unroll
  for (int r = 1; r < 16; ++r)
    dp[r*M + ((r*M)>>4)] = cmulw(y[r], tw[r]);
}

// Runtime dispatch (16k class), barriers included.
__device__ __forceinline__ void stage1_dispatch(v2f* d, int tid, int k0, int K1, int jlo, int jhi)
{
  if (K1 == 16)     super_dif16<+1, 1024, 10>(d, tid);
  else if (K1 == 8) super_dif16_sparse<+1,1024,10,8>(d, tid, k0);
  else if (K1 == 4) super_dif16_sparse<+1,1024,10,4>(d, tid, k0);
  else if (K1 == 2) super_dif16_sparse<+1,1024,10,2>(d, tid, k0);
  else { if (tid >= jlo && tid < jhi) super_dif16_sparse<+1,1024,10,1>(d, tid, k0); }
  __syncthreads();
}
__device__ __forceinline__ void stage2_dispatch(v2f* d, int tid, int k0, int K2)
{
  if (K2 == 16)     super_dif16<+1, 64, 6>(d, tid);
  else if (K2 == 8) super_dif16_sparse<+1,64,6,8>(d, tid, k0);
  else if (K2 == 4) super_dif16_sparse<+1,64,6,4>(d, tid, k0);
  else if (K2 == 2) super_dif16_sparse<+1,64,6,2>(d, tid, k0);
  else              super_dif16_sparse<+1,64,6,1>(d, tid, k0);
  __syncthreads();
}

// Full DIT super-stage radix-16 at stride M.
template<int SGN, int M, int LOGM>
__device__ __forceinline__ void super_dit16(v2f* d, int g)
{
  const int j = g & (M-1);
  const int base = ((g >> LOGM) << (LOGM+4)) | j;
  v2f* dp = d + pad(base);
  float sj, cj;
  __sincosf((float)SGN * (TWO_PI / (16.f*(float)M)) * (float)j, &sj, &cj);
  v2f w; w.x = cj; w.y = sj;
  v2f tw[16];
  twiddle_tree(w, tw);
  v2f a[16];
  a[0] = dp[0];
#pragma unroll
  for (int k = 1; k < 16; ++k)
    a[k] = cmulw(dp[k*M + ((k*M)>>4)], tw[k]);
  dft16<SGN>(a);
#pragma unroll
  for (int r = 0; r < 16; ++r) dp[r*M + ((r*M)>>4)] = a[br4(r)];
}

// PRUNED DIT16 at M=64 (r<4) — 16k pipeline.
template<int SGN>
__device__ __forceinline__ void super_dit16_m64_prune(v2f* d, int g)
{
  constexpr int M = 64;
  constexpr int PSTR = M + (M>>4);
  const int j = g & 63;
  const int base = ((g >> 6) << 10) | j;
  v2f* dp = d + pad(base);
  float sj, cj;
  __sincosf((float)SGN * (TWO_PI / 1024.f) * (float)j, &sj, &cj);
  v2f w; w.x = cj; w.y = sj;
  v2f tw[16];
  twiddle_tree(w, tw);
  v2f a[16];
  a[0] = dp[0];
#pragma unroll
  for (int k = 1; k < 16; ++k)
    a[k] = cmulw(dp[k*M + ((k*M)>>4)], tw[k]);
  v2f Y[4][4];
#pragma unroll
  for (int c = 0; c < 4; ++c) {
    v2f s0=a[c], s1=a[c+4], s2=a[c+8], s3=a[c+12];
    v2f e0 = s0+s2, e1 = s0-s2, o0 = s1+s3, o1 = s1-s3;
    v2f io1; io1.x = -(float)SGN * o1.y; io1.y = (float)SGN * o1.x;
    Y[c][0] = e0 + o0;
    Y[c][1] = e1 + io1;
    Y[c][2] = e0 - o0;
    Y[c][3] = e1 - io1;
  }
  static constexpr float WC[10] = {1.f,0.92387953f,0.70710678f,0.38268343f,0.f,
                                   -0.38268343f,-0.70710678f,-0.92387953f,-1.f,-0.92387953f};
  static constexpr float WS[10] = {0.f,0.38268343f,0.70710678f,0.92387953f,1.f,
                                   0.92387953f,0.70710678f,0.38268343f,0.f,-0.38268343f};
#pragma unroll
  for (int r = 0; r < 4; ++r) {
    v2f acc = Y[0][r];
#pragma unroll
    for (int c = 1; c < 4; ++c) {
      v2f wc; wc.x = WC[r*c]; wc.y = (float)SGN * WS[r*c];
      acc += cmulw(Y[c][r], wc);
    }
    dp[r*PSTR] = acc;
  }
}

// PRUNED final DIT16 at M=1024: bins j<256 — 16k pipeline.
template<int SGN>
__device__ __forceinline__ void super_dit16_m1024_bin256(v2f* d, int tid)
{
  if (tid < 256) {
    const int j = tid;
    v2f* dp = d + pad(j);
    float sj, cj;
    __sincosf((float)SGN * (TWO_PI / 16384.f) * (float)j, &sj, &cj);
    v2f w; w.x = cj; w.y = sj;
    v2f tw[16];
    twiddle_tree(w, tw);
    v2f acc = dp[0];
#pragma unroll
    for (int k = 1; k < 16; ++k)
      acc += cmulw(dp[k*1024 + ((k*1024)>>4)], tw[k]);
    dp[0] = acc;
  }
}

// Generic output-pruned final DIT16 at M1 = 2^LOGM1: outputs r < RMAX.
template<int SGN, int LOGM1, int RMAX, bool JLIM>
__device__ __forceinline__ void final_prune(v2f* ds, int t)
{
  static constexpr float CW[16] = { 1.f, 0.92387953f, 0.70710678f, 0.38268343f,
    0.f, -0.38268343f, -0.70710678f, -0.92387953f, -1.f, -0.92387953f,
    -0.70710678f, -0.38268343f, 0.f, 0.38268343f, 0.70710678f, 0.92387953f };
  static constexpr float SW[16] = { 0.f, 0.38268343f, 0.70710678f, 0.92387953f,
    1.f, 0.92387953f, 0.70710678f, 0.38268343f, 0.f, -0.38268343f,
    -0.70710678f, -0.92387953f, -1.f, -0.92387953f, -0.70710678f, -0.38268343f };
  constexpr int M1 = 1<<LOGM1;
  const int j = t;
  if (JLIM && j >= 256) return;
  v2f* dp = ds + j + (j>>4);
  float sj, cj;
  __sincosf((float)SGN * (TWO_PI / (16.f*(float)M1)) * (float)j, &sj, &cj);
  v2f w; w.x = cj; w.y = sj;
  v2f tw[16];
  twiddle_tree(w, tw);
  v2f b[16];
  b[0] = dp[0];
#pragma unroll
  for (int k = 1; k < 16; ++k)
    b[k] = cmulw(dp[k*M1 + ((k*M1)>>4)], tw[k]);
  v2f y[RMAX];
#pragma unroll
  for (int r = 0; r < RMAX; ++r) {
    v2f acc = b[0];
#pragma unroll
    for (int k = 1; k < 16; ++k) {
      v2f wc; wc.x = CW[(r*k)&15]; wc.y = (float)SGN*SW[(r*k)&15];
      acc += cmulw(b[k], wc);
    }
    y[r] = acc;
  }
#pragma unroll
  for (int r = 0; r < RMAX; ++r) dp[r*M1 + ((r*M1)>>4)] = y[r];
}

// DIF chain descending (barrier after each stage).
template<int SGN, int LOGM>
__device__ __forceinline__ void dif_chain(v2f* ds, int t){
  super_dif16<SGN, (1<<LOGM), LOGM>(ds, t);
  __syncthreads();
  if constexpr (LOGM > 4) dif_chain<SGN, LOGM-4>(ds, t);
}
// DIT chain ascending up to (excluding) LOGTOP.
template<int SGN, int LOGM, int LOGTOP>
__device__ __forceinline__ void dit_chain(v2f* ds, int t){
  super_dit16<SGN, (1<<LOGM), LOGM>(ds, t);
  __syncthreads();
  if constexpr (LOGM + 4 < LOGTOP) dit_chain<SGN, LOGM+4, LOGTOP>(ds, t);
}

// Generic mid: per contiguous-16 (thread t): inverse DFT_MM -> |.|/T -> fwd DFT_MM.
template<int LOGMM>
__device__ __forceinline__ void mid_generic(v2f* ds, int t)
{
  constexpr int MM = 1<<LOGMM;
  v2f* dp = ds + 17*t;
#pragma unroll
  for (int q = 0; q < 16/MM; ++q) {
    v2f a[MM];
#pragma unroll
    for (int i = 0; i < MM; ++i) a[i] = dp[q*MM+i];
    dft_reg<+1,LOGMM>(a);
    v2f m[MM];
#pragma unroll
    for (int r = 0; r < MM; ++r) {
      v2f y = a[brN<LOGMM>(r)];
      m[r].x = INV_N * sqrtf(y.x*y.x + y.y*y.y);
      m[r].y = 0.f;
    }
    dft_reg<-1,LOGMM>(m);
#pragma unroll
    for (int k = 0; k < MM; ++k) dp[q*MM+k] = m[brN<LOGMM>(k)];
  }
}

// mid4 specialization used by 16k pipelines (proven path).
__device__ __forceinline__ void fused_mid4(v2f* d, int t)
{
  v2f* dp = d + 17*t;
#pragma unroll
  for (int q = 0; q < 4; ++q) {
    v2f a0=dp[4*q], a1=dp[4*q+1], a2=dp[4*q+2], a3=dp[4*q+3];
    v2f t0=a0+a2, t1=a0-a2, t2=a1+a3, t3=a1-a3;
    v2f it3; it3.x = -t3.y; it3.y = t3.x;
    v2f y0=t0+t2, y2=t0-t2, y1=t1+it3, y3=t1-it3;
    float m0 = INV_N * sqrtf(y0.x*y0.x + y0.y*y0.y);
    float m1 = INV_N * sqrtf(y1.x*y1.x + y1.y*y1.y);
    float m2 = INV_N * sqrtf(y2.x*y2.x + y2.y*y2.y);
    float m3 = INV_N * sqrtf(y3.x*y3.x + y3.y*y3.y);
    float p0=m0+m2, p1=m0-m2, p2=m1+m3, p3=m1-m3;
    v2f o0; o0.x = p0+p2; o0.y = 0.f;
    v2f o1; o1.x = p1;    o1.y = -p3;
    v2f o2; o2.x = p0-p2; o2.y = 0.f;
    v2f o3; o3.x = p1;    o3.y = p3;
    dp[4*q]=o0; dp[4*q+1]=o1; dp[4*q+2]=o2; dp[4*q+3]=o3;
  }
}

// Generic decimated pipeline body for LOGN in {10,11,12,13}.
template<int LOGN>
__device__ __forceinline__ void o2_body(v2f* ds, int t)
{
  constexpr int LOGM1 = LOGN-4;
  super_dif16_sparse<+1, (1<<LOGM1), LOGM1, 8>(ds, t, 0);
  __syncthreads();
  dif_chain<+1, LOGM1-4>(ds, t);
  constexpr int LOGMM = ((LOGM1-5)%4)+1;
  mid_generic<LOGMM>(ds, t);
  __syncthreads();
  dit_chain<-1, LOGMM, LOGM1>(ds, t);
  constexpr int RM = ((1<<LOGM1) >= 256) ? 1 : (256>>LOGM1);
  constexpr bool JL = ((1<<LOGM1) > 256);
  final_prune<-1, LOGM1, RM, JL>(ds, t);
  __syncthreads();
}

// Generic fold: SEGT = 64*PERK threads, scale applied at write.
template<int PERK>
__device__ __forceinline__ void fold_generic(const v2f* ds, const float* __restrict__ phi,
                                             float* outp, int t, float scale)
{
  const int k = t / PERK, g = t % PERK;
  float sv, cv, ss, cs;
  __sincosf((TWO_PI/64.f) * (float)((g*k) & 63), &sv, &cv);
  __sincosf((TWO_PI/64.f) * (float)((PERK*k) & 63), &ss, &cs);
  float acc = 0.f;
#pragma unroll
  for (int m = 0; m < 256/PERK; ++m) {
    const int f = g + PERK*m;
    v2f u = ds[f + (f>>4)];
    float wgt = phi[f] * ((f == 0) ? 1.f : 2.f);
    acc += wgt * (u.x*cv - u.y*sv);
    float nc = cv*cs - sv*ss, ns = cv*ss + sv*cs;
    cv = nc; sv = ns;
  }
#pragma unroll
  for (int o = 1; o < PERK; o <<= 1) acc += __shfl_xor(acc, o);
  if (g == 0) outp[k] = acc * scale;
}

// phi-fold for full-size (SEGT=1024) pipelines.
__device__ void fold_store16(const v2f* d, const float* __restrict__ phi, float* outp, int tid)
{
  const int k = tid >> 4, g = tid & 15;
  float sv, cv;
  __sincosf((TWO_PI/64.f) * (float)((g*k) & 63), &sv, &cv);
  const int km = k & 3;
  const float strRe = (km==0) ? 1.f : (km==2 ? -1.f : 0.f);
  const float strIm = (km==1) ? 1.f : (km==3 ? -1.f : 0.f);
  float acc = 0.f;
#pragma unroll
  for (int m = 0; m < 16; ++m) {
    const int f = g + 16*m;
    v2f u = d[pad(f)];
    float wgt = phi[f] * ((f == 0) ? 1.f : 2.f);
    acc += wgt * (u.x*cv - u.y*sv);
    float nc = cv*strRe - sv*strIm;
    float ns = cv*strIm + sv*strRe;
    cv = nc; sv = ns;
  }
  acc += __shfl_xor(acc, 1);
  acc += __shfl_xor(acc, 2);
  acc += __shfl_xor(acc, 4);
  acc += __shfl_xor(acc, 8);
  if (g == 0) outp[k] = acc * INV_N;
}

// Reference pair index (j1-major, valid j2 > j1/8).
__device__ __forceinline__ int pair_index(int j1, int j2)
{
  const int q = j1 >> 3;
  return 8*(7*q - (q*(q-1))/2) + (j1 & 7)*(7 - q) + (j2 - q - 1);
}

// psi2 band widths W(j2) = ceil(4.5 * 5734.4 * 2^-j2)
__device__ __constant__ int WTAB[8]  = {16384, 12903, 6452, 3226, 1613, 807, 404, 202};
// U1h store bound per j1-octave q: W(q+1) capped at 8193
__device__ __constant__ int SBTAB[8] = {8193, 6452, 3226, 1613, 807, 404, 202, 0};

// ---- radix-4 float2 path for k_fft_x ----
__device__ __forceinline__ float2 f2add(float2 a, float2 b){ return make_float2(a.x+b.x, a.y+b.y); }
__device__ __forceinline__ float2 f2sub(float2 a, float2 b){ return make_float2(a.x-b.x, a.y-b.y); }
__device__ __forceinline__ float2 cmul_cs(float2 a, float c, float s){
  return make_float2(a.x*c - a.y*s, a.x*s + a.y*c);
}
__device__ void dif_sweep(float2* d, int tid, float sgn, int mb_hi, int mb_lo)
{
  const float ang = sgn * (TWO_PI / (float)T_N);
  for (int mbits = mb_hi; mbits >= mb_lo; mbits -= 2) {
    const int M = 1 << mbits;
#pragma unroll 8
    for (int v = tid; v < T_N/4; v += NT) {
      const int j = v & (M-1);
      const int base = ((v >> mbits) << (mbits+2)) | j;
      const int i0 = pad(base), i1 = pad(base+M), i2 = pad(base+2*M), i3 = pad(base+3*M);
      float2 a0=d[i0], a1=d[i1], a2=d[i2], a3=d[i3];
      float2 t0=f2add(a0,a2), t1=f2sub(a0,a2), t2=f2add(a1,a3), t3=f2sub(a1,a3);
      float2 y0=f2add(t0,t2), y2=f2sub(t0,t2);
      float2 y1=make_float2(t1.x - sgn*t3.y, t1.y + sgn*t3.x);
      float2 y3=make_float2(t1.x + sgn*t3.y, t1.y - sgn*t3.x);
      float s1,c1;
      __sincosf(ang * (float)(j << (12-mbits)), &s1, &c1);
      float c2=c1*c1-s1*s1, s2=2.f*c1*s1;
      float c3=c1*c2-s1*s2, s3=c1*s2+s1*c2;
      d[i0]=y0;
      d[i1]=cmul_cs(y1,c1,s1);
      d[i2]=cmul_cs(y2,c2,s2);
      d[i3]=cmul_cs(y3,c3,s3);
    }
    __syncthreads();
  }
}
__device__ void fold_store8(const float2* d, const float* __restrict__ phi, float* outp, int tid)
{
  const int k = tid >> 3, g = tid & 7;
  float acc = 0.f;
  for (int f = g; f < FOLD_F; f += 8) {
    float2 u = d[pad(f)];
    float w = phi[f] * ((f == 0) ? 1.f : 2.f);
    float sv, cv;
    __sincosf((TWO_PI/64.f) * (float)((f*k) & 63), &sv, &cv);
    acc += w * (u.x*cv - u.y*sv);
  }
  acc += __shfl_xor(acc, 1);
  acc += __shfl_xor(acc, 2);
  acc += __shfl_xor(acc, 4);
  if (g == 0) outp[k] = acc * INV_N;
}

// K1: xh = FFT(x) + S0 fold.
__global__ void __launch_bounds__(NT) k_fft_x(const float* __restrict__ x, const float* __restrict__ phi,
                                              float2* __restrict__ xh, float* __restrict__ out)
{
  extern __shared__ char smem[];
  float2* d = (float2*)smem;
  const int tid = threadIdx.x;
  const int b = blockIdx.x;
  const float* xr = x + b * T_N;
  for (int i = tid; i < T_N; i += NT) d[pad(i)] = make_float2(xr[i], 0.f);
  __syncthreads();
  dif_sweep(d, tid, -1.f, 12, 0);
  for (int p = tid; p < T_N; p += NT) {
    int r = rev4_14(p);
    if (p < r) { int ip = pad(p), ir = pad(r); float2 t = d[ip]; d[ip] = d[ir]; d[ir] = t; }
  }
  __syncthreads();
  float2* xrow = xh + (size_t)b * T_N;
  for (int i = tid; i < T_N; i += NT) xrow[i] = d[pad(i)];
  fold_store8(d, phi, out + b * 64, tid);
}

// K2: per (b,j1): Z = xh*psi1 (band) -> sparse IFFT -> |.| -> FFT -> U1h + S1.
__global__ void __launch_bounds__(NT2, 4) k_order1(const float2* __restrict__ xh, const float* __restrict__ psi1,
                                                   const float* __restrict__ phi, float2* __restrict__ u1h,
                                                   float* __restrict__ out)
{
  extern __shared__ char smem[];
  v2f* d = (v2f*)smem;
  const int tid = threadIdx.x;
  const int b = blockIdx.x >> 6, j1 = blockIdx.x & 63;
  const float2* xrow = xh + (size_t)b * T_N;
  const float* prow = psi1 + j1 * T_N;
  const float c = 5734.4f * exp2f(-0.125f * (float)j1);
  const int lo = max(0, (int)(0.36f * c));
  const int hi = min(T_N, (int)(1.64f * c) + 2);
#pragma unroll
  for (int s = 0; s < T_N/NT2; ++s) {
    int i = tid + s*NT2;
    v2f z; z.x = 0.f; z.y = 0.f;
    if (i >= lo && i < hi) {
      float2 v = xrow[i];
      float p = prow[i];
      z.x = v.x*p; z.y = v.y*p;
    }
    d[pad(i)] = z;
  }
  __syncthreads();
  const int k_lo = lo >> 10, k_hi = (hi + 1023) >> 10;
  const int K1 = pow2ceil16(k_hi - k_lo);
  const int k0 = min(k_lo, 16 - K1);
  int jlo = 0, jhi = NT2, k0_2 = 0, K2 = 16;
  if (K1 == 1) {
    jlo = lo - (k_lo << 10); jhi = hi - (k_lo << 10);
    const int k2_lo = jlo >> 6, k2_hi = (jhi + 63) >> 6;
    K2 = pow2ceil16(k2_hi - k2_lo);
    k0_2 = min(k2_lo, 16 - K2);
  }
  stage1_dispatch(d, tid, k0, K1, jlo, jhi);
  stage2_dispatch(d, tid, k0_2, K2);
  super_dif16<+1, 4, 2>(d, tid);     __syncthreads();
  fused_mid4(d, tid);                __syncthreads();
  super_dit16<-1, 4, 2>(d, tid);     __syncthreads();
  super_dit16<-1, 64, 6>(d, tid);    __syncthreads();
  super_dit16<-1, 1024, 10>(d, tid); __syncthreads();
  const int sb = SBTAB[j1 >> 3];
  float2* urow = u1h + (size_t)(b * N1 + j1) * USTRIDE;
  for (int i = tid; i < sb; i += NT2) {
    v2f u = d[pad(i)];
    urow[i] = make_float2(u.x, u.y);
  }
  fold_store16(d, phi, out + 1024 + (size_t)(b * N1 + j1) * 64, tid);
}

// K3a: j2 in {1,2}, full 16384 pipeline (mirror needed for j2=1). 24 pairs.
__global__ void __launch_bounds__(NT2, 4) k_o2_16k(const float2* __restrict__ u1h, const float* __restrict__ psi2,
                                                   const float* __restrict__ phi, float* __restrict__ out)
{
  extern __shared__ char smem[];
  v2f* d = (v2f*)smem;
  const int tid = threadIdx.x;
  const int b = blockIdx.x / 24, cls_p = blockIdx.x % 24;
  const int j2 = (cls_p < 8) ? 1 : 2;
  const int j1 = cls_p - ((cls_p < 8) ? 0 : 8);
  const int W = WTAB[j2];
  const float2* urow = u1h + (size_t)(b * N1 + j1) * USTRIDE;
  const float* prow = psi2 + j2 * T_N;
#pragma unroll
  for (int s = 0; s < T_N/NT2; ++s) {
    int i = tid + s*NT2;
    v2f z; z.x = 0.f; z.y = 0.f;
    if (i < W) {
      float2 u;
      if (i <= T_N/2) u = urow[i];
      else { float2 t = urow[T_N - i]; u = make_float2(t.x, -t.y); }
      float ps = prow[i];
      z.x = u.x*ps; z.y = u.y*ps;
    }
    d[pad(i)] = z;
  }
  __syncthreads();
  const int K1 = pow2ceil16((W + 1023) >> 10);
  stage1_dispatch(d, tid, 0, K1, 0, W);
  stage2_dispatch(d, tid, 0, 16);
  super_dif16<+1, 4, 2>(d, tid);      __syncthreads();
  fused_mid4(d, tid);                 __syncthreads();
  super_dit16<-1, 4, 2>(d, tid);      __syncthreads();
  super_dit16_m64_prune<-1>(d, tid);  __syncthreads();
  super_dit16_m1024_bin256<-1>(d, tid); __syncthreads();
  const int p = pair_index(j1, j2);
  fold_store16(d, phi, out + 66560 + (size_t)(b * NPAIR + p) * 64, tid);
}

// K3b: single-j2 decimated classes. N=2^LOGN, PPB pairs per block.
template<int LOGN, int J2, int NPAIRS_CLS>
__global__ void __launch_bounds__(NT2, 4) k_o2_cls(const float2* __restrict__ u1h, const float* __restrict__ psi2,
                                                   const float* __restrict__ phi, float* __restrict__ out)
{
  constexpr int N = 1<<LOGN, SEGT = N/16, PPB = T_N/N, NGRP = NPAIRS_CLS/PPB;
  extern __shared__ char smem[];
  const int grp = blockIdx.x % NGRP, b = blockIdx.x / NGRP;
  const int sub = threadIdx.x >> (LOGN-4), t = threadIdx.x & (SEGT-1);
  const int j1 = grp*PPB + sub;
  const int soff = sub*N + ((sub*N)>>4);
  v2f* ds = (v2f*)smem + soff;
  const int W = WTAB[J2];
  const float2* urow = u1h + (size_t)(b * N1 + j1) * USTRIDE;
  const float* prow = psi2 + J2 * T_N;
#pragma unroll
  for (int s = 0; s < 16; ++s) {
    int f = t + s*SEGT;
    v2f z; z.x = 0.f; z.y = 0.f;
    if (f < W) { float2 u = urow[f]; float ps = prow[f]; z.x = u.x*ps; z.y = u.y*ps; }
    ds[f + (f>>4)] = z;
  }
  __syncthreads();
  o2_body<LOGN>(ds, t);
  const int p = pair_index(j1, J2);
  fold_generic<SEGT/64>(ds, phi, out + 66560 + (size_t)(b * NPAIR + p) * 64, t, 1.f/(float)N);
}

// K3c: N=1024 mixed class (j2 in {6,7}): 104 pairs, 16/block, 7 groups.
__global__ void __launch_bounds__(NT2, 4) k_o2_1k(const float2* __restrict__ u1h, const float* __restrict__ psi2,
                                                  const float* __restrict__ phi, float* __restrict__ out)
{
  constexpr int N = 1024, SEGT = 64;
  extern __shared__ char smem[];
  const int grp = blockIdx.x % 7, b = blockIdx.x / 7;
  const int sub = threadIdx.x >> 6, t = threadIdx.x & 63;
  const int cls_p = grp*16 + sub;
  const int valid = (cls_p < 104);
  const int j2 = (cls_p < 48) ? 6 : 7;
  const int j1 = cls_p - ((cls_p < 48) ? 0 : 48);
  const int soff = sub*N + ((sub*N)>>4);
  v2f* ds = (v2f*)smem + soff;
  const int W = WTAB[j2];
  const float2* urow = u1h + (size_t)(b * N1 + j1) * USTRIDE;
  const float* prow = psi2 + j2 * T_N;
#pragma unroll
  for (int s = 0; s < 16; ++s) {
    int f = t + s*SEGT;
    v2f z; z.x = 0.f; z.y = 0.f;
    if (valid && f < W) { float2 u = urow[f]; float ps = prow[f]; z.x = u.x*ps; z.y = u.y*ps; }
    ds[f + (f>>4)] = z;
  }
  __syncthreads();
  o2_body<10>(ds, t);
  if (valid) {
    const int p = pair_index(j1, j2);
    fold_generic<1>(ds, phi, out + 66560 + (size_t)(b * NPAIR + p) * 64, t, 1.f/(float)N);
  }
}

extern "C" void kernel_launch(void* const* d_in, const int* in_sizes, int n_in,
                              void* d_out, int out_size, void* d_ws, size_t ws_size,
                              hipStream_t stream)
{
  const float* x    = (const float*)d_in[0];
  const float* psi1 = (const float*)d_in[1];
  const float* psi2 = (const float*)d_in[2];
  const float* phi  = (const float*)d_in[3];
  float* out = (float*)d_out;

  float2* xh  = (float2*)d_ws;
  float2* u1h = xh + (size_t)B_SZ * T_N;

  const size_t lds = (size_t)(T_N + (T_N >> 4)) * sizeof(float2);  // 139264 B

  auto* f8k = k_o2_cls<13,3,24>;
  auto* f4k = k_o2_cls<12,4,32>;
  auto* f2k = k_o2_cls<11,5,40>;
  (void)hipFuncSetAttribute((const void*)k_fft_x,  hipFuncAttributeMaxDynamicSharedMemorySize, (int)lds);
  (void)hipFuncSetAttribute((const void*)k_order1, hipFuncAttributeMaxDynamicSharedMemorySize, (int)lds);
  (void)hipFuncSetAttribute((const void*)k_o2_16k, hipFuncAttributeMaxDynamicSharedMemorySize, (int)lds);
  (void)hipFuncSetAttribute((const void*)f8k,      hipFuncAttributeMaxDynamicSharedMemorySize, (int)lds);
  (void)hipFuncSetAttribute((const void*)f4k,      hipFuncAttributeMaxDynamicSharedMemorySize, (int)lds);
  (void)hipFuncSetAttribute((const void*)f2k,      hipFuncAttributeMaxDynamicSharedMemorySize, (int)lds);
  (void)hipFuncSetAttribute((const void*)k_o2_1k,  hipFuncAttributeMaxDynamicSharedMemorySize, (int)lds);

  hipLaunchKernelGGL(k_fft_x,  dim3(B_SZ),      dim3(NT),  lds, stream, x, phi, xh, out);
  hipLaunchKernelGGL(k_order1, dim3(B_SZ * N1), dim3(NT2), lds, stream, xh, psi1, phi, u1h, out);
  hipLaunchKernelGGL(k_o2_16k, dim3(B_SZ * 24), dim3(NT2), lds, stream, u1h, psi2, phi, out);
  hipLaunchKernelGGL(f8k,      dim3(B_SZ * 12), dim3(NT2), lds, stream, u1h, psi2, phi, out);
  hipLaunchKernelGGL(f4k,      dim3(B_SZ * 8),  dim3(NT2), lds, stream, u1h, psi2, phi, out);
  hipLaunchKernelGGL(f2k,      dim3(B_SZ * 5),  dim3(NT2), lds, stream, u1h, psi2, phi, out);
  hipLaunchKernelGGL(k_o2_1k,  dim3(B_SZ * 7),  dim3(NT2), lds, stream, u1h, psi2, phi, out);
}

// Round 9
// 259.670 us; speedup vs baseline: 3.3593x; 1.2083x over previous
//
#include <hip/hip_runtime.h>
#include <math.h>

// Wavelet scattering, T=16384.  Radix-16 register-blocked in-LDS FFTs.
// Order-1 AND order-2 use per-octave DECIMATED pipelines: the filter band is
// demodulated to baseband (|.| is shift-invariant), folded into N' = pow2
// slots (exact: band width <= N'), inverse N'-DFT -> |.|/T -> forward N'-DFT
// whose bins approximate full-grid bins via U_full[f] ~= R*DFT_N'[f], R=T/N'.
// Aliasing margin N'-sb >= 2.5x envelope BW for every class.

#define T_N   16384
#define NT    512
#define NT2   1024
#define B_SZ  16
#define N1    64
#define NPAIR 224
#define FOLD_F 256
#define USTRIDE 8208
#define INV_N (1.0f/16384.0f)
#define TWO_PI 6.283185307179586f

typedef float v2f __attribute__((ext_vector_type(2)));

__device__ __forceinline__ int pad(int i) { return i + (i >> 4); }

__device__ __forceinline__ v2f cmulw(v2f a, v2f w){
  v2f n; n.x = -a.y; n.y = a.x;
  return w.x * a + w.y * n;
}
__device__ __forceinline__ constexpr int br4(int x){
  return ((x&1)<<3)|((x&2)<<1)|((x&4)>>1)|((x&8)>>3);
}
template<int LB>
__device__ __forceinline__ constexpr int brN(int x){
  int r=0;
  for(int i=0;i<LB;++i){ r=(r<<1)|((x>>i)&1); }
  return r;
}
__device__ __forceinline__ int rev4_14(int p){
  unsigned r = __brev((unsigned)p) >> 18;
  return (int)(((r & 0x2AAAu) >> 1) | ((r & 0x1555u) << 1));
}
__device__ __forceinline__ int pow2ceil16(int k){
  return (k<=1)?1:(k<=2)?2:(k<=4)?4:(k<=8)?8:16;
}

// tw[r] = w^r via depth-4 product tree.
__device__ __forceinline__ void twiddle_tree(v2f w, v2f* tw){
  tw[0].x = 1.f; tw[0].y = 0.f;
  tw[1] = w;
  tw[2] = cmulw(w, w);
  tw[4] = cmulw(tw[2], tw[2]);
  tw[8] = cmulw(tw[4], tw[4]);
  tw[3] = cmulw(tw[2], w);
  tw[5] = cmulw(tw[4], w);
  tw[6] = cmulw(tw[4], tw[2]);
  tw[7] = cmulw(tw[4], tw[3]);
  tw[9]  = cmulw(tw[8], w);
  tw[10] = cmulw(tw[8], tw[2]);
  tw[11] = cmulw(tw[8], tw[3]);
  tw[12] = cmulw(tw[8], tw[4]);
  tw[13] = cmulw(tw[8], tw[5]);
  tw[14] = cmulw(tw[8], tw[6]);
  tw[15] = cmulw(tw[8], tw[7]);
}

// Generic fully-unrolled DFT of size 2^LOGNN (<=16); y[r] lands at a[brN(r)].
template<int SGN, int LOGNN>
__device__ __forceinline__ void dft_reg(v2f* a){
  constexpr int NN = 1<<LOGNN;
  static constexpr float C16[16] = {
    1.f, 0.98078528f, 0.92387953f, 0.83146961f, 0.70710678f, 0.55557023f,
    0.38268343f, 0.19509032f, 0.f, -0.19509032f, -0.38268343f, -0.55557023f,
    -0.70710678f, -0.83146961f, -0.92387953f, -0.98078528f };
  static constexpr float S16[16] = {
    0.f, 0.19509032f, 0.38268343f, 0.55557023f, 0.70710678f, 0.83146961f,
    0.92387953f, 0.98078528f, 1.f, 0.98078528f, 0.92387953f, 0.83146961f,
    0.70710678f, 0.55557023f, 0.38268343f, 0.19509032f };
#pragma unroll
  for (int m = NN/2; m >= 1; m >>= 1) {
#pragma unroll
    for (int base = 0; base < NN; base += 2*m) {
#pragma unroll
      for (int j = 0; j < m; ++j) {
        v2f u = a[base+j], v = a[base+j+m];
        a[base+j] = u + v;
        v2f w = u - v;
        const int ti = (j*16)/m;
        v2f tw; tw.x = C16[ti]; tw.y = (float)SGN * S16[ti];
        a[base+j+m] = cmulw(w, tw);
      }
    }
  }
}
template<int SGN>
__device__ __forceinline__ void dft16(v2f* a){ dft_reg<SGN,4>(a); }

// Full DIF super-stage radix-16 at stride M.
template<int SGN, int M, int LOGM>
__device__ __forceinline__ void super_dif16(v2f* d, int g)
{
  const int j = g & (M-1);
  const int base = ((g >> LOGM) << (LOGM+4)) | j;
  v2f* dp = d + pad(base);
  v2f a[16];
#pragma unroll
  for (int k = 0; k < 16; ++k) a[k] = dp[k*M + ((k*M)>>4)];
  dft16<SGN>(a);
  float sj, cj;
  __sincosf((float)SGN * (TWO_PI / (16.f*(float)M)) * (float)j, &sj, &cj);
  v2f w; w.x = cj; w.y = sj;
  v2f tw[16];
  twiddle_tree(w, tw);
  dp[0] = a[0];
#pragma unroll
  for (int r = 1; r < 16; ++r)
    dp[r*M + ((r*M)>>4)] = cmulw(a[br4(r)], tw[r]);
}

// SPARSE DIF super-stage: only taps [k0,k0+K) possibly nonzero (rest zeros).
template<int SGN, int M, int LOGM, int K>
__device__ __forceinline__ void super_dif16_sparse(v2f* d, int g, int k0)
{
  static constexpr float CW[16] = { 1.f, 0.92387953f, 0.70710678f, 0.38268343f,
    0.f, -0.38268343f, -0.70710678f, -0.92387953f, -1.f, -0.92387953f,
    -0.70710678f, -0.38268343f, 0.f, 0.38268343f, 0.70710678f, 0.92387953f };
  static constexpr float SW[16] = { 0.f, 0.38268343f, 0.70710678f, 0.92387953f,
    1.f, 0.92387953f, 0.70710678f, 0.38268343f, 0.f, -0.38268343f,
    -0.70710678f, -0.92387953f, -1.f, -0.92387953f, -0.70710678f, -0.38268343f };
  const int j = g & (M-1);
  const int base = ((g >> LOGM) << (LOGM+4)) | j;
  v2f* dp = d + pad(base);
  v2f a[K];
#pragma unroll
  for (int m = 0; m < K; ++m) {
    const int k = k0 + m;
    a[m] = dp[k*M + ((k*M)>>4)];
  }
  v2f y[16];
  if constexpr (K == 1) {
#pragma unroll
    for (int r = 0; r < 16; ++r) y[r] = a[0];
  } else if constexpr (K == 2) {
#pragma unroll
    for (int r0 = 0; r0 < 8; ++r0) {
      v2f w; w.x = CW[r0]; w.y = (float)SGN * SW[r0];
      v2f b1 = cmulw(a[1], w);
      y[r0]   = a[0] + b1;
      y[r0+8] = a[0] - b1;
    }
  } else if constexpr (K == 4) {
#pragma unroll
    for (int r0 = 0; r0 < 4; ++r0) {
      v2f z1, z2, z3;
      { v2f w; w.x = CW[r0];        w.y = (float)SGN*SW[r0];        z1 = cmulw(a[1], w); }
      { v2f w; w.x = CW[(2*r0)&15]; w.y = (float)SGN*SW[(2*r0)&15]; z2 = cmulw(a[2], w); }
      { v2f w; w.x = CW[(3*r0)&15]; w.y = (float)SGN*SW[(3*r0)&15]; z3 = cmulw(a[3], w); }
      v2f e0 = a[0]+z2, e1 = a[0]-z2, o0 = z1+z3, o1 = z1-z3;
      v2f io; io.x = -(float)SGN*o1.y; io.y = (float)SGN*o1.x;
      y[r0]    = e0 + o0;
      y[r0+4]  = e1 + io;
      y[r0+8]  = e0 - o0;
      y[r0+12] = e1 - io;
    }
  } else { // K == 8
#pragma unroll
    for (int r0 = 0; r0 < 2; ++r0) {
      v2f z[8];
      z[0] = a[0];
#pragma unroll
      for (int m = 1; m < 8; ++m) {
        v2f w; w.x = CW[(m*r0)&15]; w.y = (float)SGN*SW[(m*r0)&15];
        z[m] = cmulw(a[m], w);
      }
      v2f E[4], O[4];
      {
        v2f e0=z[0]+z[4], e1=z[0]-z[4], o0=z[2]+z[6], o1=z[2]-z[6];
        v2f io; io.x=-(float)SGN*o1.y; io.y=(float)SGN*o1.x;
        E[0]=e0+o0; E[1]=e1+io; E[2]=e0-o0; E[3]=e1-io;
      }
      {
        v2f e0=z[1]+z[5], e1=z[1]-z[5], o0=z[3]+z[7], o1=z[3]-z[7];
        v2f io; io.x=-(float)SGN*o1.y; io.y=(float)SGN*o1.x;
        O[0]=e0+o0; O[1]=e1+io; O[2]=e0-o0; O[3]=e1-io;
      }
      constexpr float RT = 0.70710678f;
#pragma unroll
      for (int r1 = 0; r1 < 4; ++r1) {
        v2f w8;
        if (r1 == 0)      { w8.x = 1.f;  w8.y = 0.f; }
        else if (r1 == 1) { w8.x = RT;   w8.y = (float)SGN*RT; }
        else if (r1 == 2) { w8.x = 0.f;  w8.y = (float)SGN; }
        else              { w8.x = -RT;  w8.y = (float)SGN*RT; }
        v2f t = cmulw(O[r1], w8);
        y[2*r1 + r0]     = E[r1] + t;
        y[2*r1 + r0 + 8] = E[r1] - t;
      }
    }
  }
  float sj, cj;
  __sincosf((float)SGN * (TWO_PI / (16.f*(float)M)) * (float)(j + k0*M), &sj, &cj);
  v2f w; w.x = cj; w.y = sj;
  v2f tw[16];
  twiddle_tree(w, tw);
  dp[0] = y[0];
#pragma unroll
  for (int r = 1; r < 16; ++r)
    dp[r*M + ((r*M)>>4)] = cmulw(y[r], tw[r]);
}

// Runtime dispatch (16k pipelines), barriers included.
__device__ __forceinline__ void stage1_dispatch(v2f* d, int tid, int k0, int K1, int jlo, int jhi)
{
  if (K1 == 16)     super_dif16<+1, 1024, 10>(d, tid);
  else if (K1 == 8) super_dif16_sparse<+1,1024,10,8>(d, tid, k0);
  else if (K1 == 4) super_dif16_sparse<+1,1024,10,4>(d, tid, k0);
  else if (K1 == 2) super_dif16_sparse<+1,1024,10,2>(d, tid, k0);
  else { if (tid >= jlo && tid < jhi) super_dif16_sparse<+1,1024,10,1>(d, tid, k0); }
  __syncthreads();
}
__device__ __forceinline__ void stage2_dispatch(v2f* d, int tid, int k0, int K2)
{
  if (K2 == 16)     super_dif16<+1, 64, 6>(d, tid);
  else if (K2 == 8) super_dif16_sparse<+1,64,6,8>(d, tid, k0);
  else if (K2 == 4) super_dif16_sparse<+1,64,6,4>(d, tid, k0);
  else if (K2 == 2) super_dif16_sparse<+1,64,6,2>(d, tid, k0);
  else              super_dif16_sparse<+1,64,6,1>(d, tid, k0);
  __syncthreads();
}

// Full DIT super-stage radix-16 at stride M.
template<int SGN, int M, int LOGM>
__device__ __forceinline__ void super_dit16(v2f* d, int g)
{
  const int j = g & (M-1);
  const int base = ((g >> LOGM) << (LOGM+4)) | j;
  v2f* dp = d + pad(base);
  float sj, cj;
  __sincosf((float)SGN * (TWO_PI / (16.f*(float)M)) * (float)j, &sj, &cj);
  v2f w; w.x = cj; w.y = sj;
  v2f tw[16];
  twiddle_tree(w, tw);
  v2f a[16];
  a[0] = dp[0];
#pragma unroll
  for (int k = 1; k < 16; ++k)
    a[k] = cmulw(dp[k*M + ((k*M)>>4)], tw[k]);
  dft16<SGN>(a);
#pragma unroll
  for (int r = 0; r < 16; ++r) dp[r*M + ((r*M)>>4)] = a[br4(r)];
}

// PRUNED DIT16 at M=64 (r<4) — 16k pipeline.
template<int SGN>
__device__ __forceinline__ void super_dit16_m64_prune(v2f* d, int g)
{
  constexpr int M = 64;
  constexpr int PSTR = M + (M>>4);
  const int j = g & 63;
  const int base = ((g >> 6) << 10) | j;
  v2f* dp = d + pad(base);
  float sj, cj;
  __sincosf((float)SGN * (TWO_PI / 1024.f) * (float)j, &sj, &cj);
  v2f w; w.x = cj; w.y = sj;
  v2f tw[16];
  twiddle_tree(w, tw);
  v2f a[16];
  a[0] = dp[0];
#pragma unroll
  for (int k = 1; k < 16; ++k)
    a[k] = cmulw(dp[k*M + ((k*M)>>4)], tw[k]);
  v2f Y[4][4];
#pragma unroll
  for (int c = 0; c < 4; ++c) {
    v2f s0=a[c], s1=a[c+4], s2=a[c+8], s3=a[c+12];
    v2f e0 = s0+s2, e1 = s0-s2, o0 = s1+s3, o1 = s1-s3;
    v2f io1; io1.x = -(float)SGN * o1.y; io1.y = (float)SGN * o1.x;
    Y[c][0] = e0 + o0;
    Y[c][1] = e1 + io1;
    Y[c][2] = e0 - o0;
    Y[c][3] = e1 - io1;
  }
  static constexpr float WC[10] = {1.f,0.92387953f,0.70710678f,0.38268343f,0.f,
                                   -0.38268343f,-0.70710678f,-0.92387953f,-1.f,-0.92387953f};
  static constexpr float WS[10] = {0.f,0.38268343f,0.70710678f,0.92387953f,1.f,
                                   0.92387953f,0.70710678f,0.38268343f,0.f,-0.38268343f};
#pragma unroll
  for (int r = 0; r < 4; ++r) {
    v2f acc = Y[0][r];
#pragma unroll
    for (int c = 1; c < 4; ++c) {
      v2f wc; wc.x = WC[r*c]; wc.y = (float)SGN * WS[r*c];
      acc += cmulw(Y[c][r], wc);
    }
    dp[r*PSTR] = acc;
  }
}

// PRUNED final DIT16 at M=1024: bins j<256 — 16k pipeline.
template<int SGN>
__device__ __forceinline__ void super_dit16_m1024_bin256(v2f* d, int tid)
{
  if (tid < 256) {
    const int j = tid;
    v2f* dp = d + pad(j);
    float sj, cj;
    __sincosf((float)SGN * (TWO_PI / 16384.f) * (float)j, &sj, &cj);
    v2f w; w.x = cj; w.y = sj;
    v2f tw[16];
    twiddle_tree(w, tw);
    v2f acc = dp[0];
#pragma unroll
    for (int k = 1; k < 16; ++k)
      acc += cmulw(dp[k*1024 + ((k*1024)>>4)], tw[k]);
    dp[0] = acc;
  }
}

// Generic output-pruned final DIT16 at M1 = 2^LOGM1: outputs r < RMAX.
template<int SGN, int LOGM1, int RMAX, bool JLIM>
__device__ __forceinline__ void final_prune(v2f* ds, int t)
{
  static constexpr float CW[16] = { 1.f, 0.92387953f, 0.70710678f, 0.38268343f,
    0.f, -0.38268343f, -0.70710678f, -0.92387953f, -1.f, -0.92387953f,
    -0.70710678f, -0.38268343f, 0.f, 0.38268343f, 0.70710678f, 0.92387953f };
  static constexpr float SW[16] = { 0.f, 0.38268343f, 0.70710678f, 0.92387953f,
    1.f, 0.92387953f, 0.70710678f, 0.38268343f, 0.f, -0.38268343f,
    -0.70710678f, -0.92387953f, -1.f, -0.92387953f, -0.70710678f, -0.38268343f };
  constexpr int M1 = 1<<LOGM1;
  const int j = t;
  if (JLIM && j >= 256) return;
  v2f* dp = ds + j + (j>>4);
  float sj, cj;
  __sincosf((float)SGN * (TWO_PI / (16.f*(float)M1)) * (float)j, &sj, &cj);
  v2f w; w.x = cj; w.y = sj;
  v2f tw[16];
  twiddle_tree(w, tw);
  v2f b[16];
  b[0] = dp[0];
#pragma unroll
  for (int k = 1; k < 16; ++k)
    b[k] = cmulw(dp[k*M1 + ((k*M1)>>4)], tw[k]);
  v2f y[RMAX];
#pragma unroll
  for (int r = 0; r < RMAX; ++r) {
    v2f acc = b[0];
#pragma unroll
    for (int k = 1; k < 16; ++k) {
      v2f wc; wc.x = CW[(r*k)&15]; wc.y = (float)SGN*SW[(r*k)&15];
      acc += cmulw(b[k], wc);
    }
    y[r] = acc;
  }
#pragma unroll
  for (int r = 0; r < RMAX; ++r) dp[r*M1 + ((r*M1)>>4)] = y[r];
}

// DIF chain descending (barrier after each stage).
template<int SGN, int LOGM>
__device__ __forceinline__ void dif_chain(v2f* ds, int t){
  super_dif16<SGN, (1<<LOGM), LOGM>(ds, t);
  __syncthreads();
  if constexpr (LOGM > 4) dif_chain<SGN, LOGM-4>(ds, t);
}
// DIT chain ascending up to (excluding) LOGTOP.
template<int SGN, int LOGM, int LOGTOP>
__device__ __forceinline__ void dit_chain(v2f* ds, int t){
  super_dit16<SGN, (1<<LOGM), LOGM>(ds, t);
  __syncthreads();
  if constexpr (LOGM + 4 < LOGTOP) dit_chain<SGN, LOGM+4, LOGTOP>(ds, t);
}

// Generic mid: per contiguous-16 (thread t): inverse DFT_MM -> |.|/T -> fwd DFT_MM.
template<int LOGMM>
__device__ __forceinline__ void mid_generic(v2f* ds, int t)
{
  constexpr int MM = 1<<LOGMM;
  v2f* dp = ds + 17*t;
#pragma unroll
  for (int q = 0; q < 16/MM; ++q) {
    v2f a[MM];
#pragma unroll
    for (int i = 0; i < MM; ++i) a[i] = dp[q*MM+i];
    dft_reg<+1,LOGMM>(a);
    v2f m[MM];
#pragma unroll
    for (int r = 0; r < MM; ++r) {
      v2f y = a[brN<LOGMM>(r)];
      m[r].x = INV_N * sqrtf(y.x*y.x + y.y*y.y);
      m[r].y = 0.f;
    }
    dft_reg<-1,LOGMM>(m);
#pragma unroll
    for (int k = 0; k < MM; ++k) dp[q*MM+k] = m[brN<LOGMM>(k)];
  }
}

// mid4 specialization used by 16k pipelines (proven path).
__device__ __forceinline__ void fused_mid4(v2f* d, int t)
{
  v2f* dp = d + 17*t;
#pragma unroll
  for (int q = 0; q < 4; ++q) {
    v2f a0=dp[4*q], a1=dp[4*q+1], a2=dp[4*q+2], a3=dp[4*q+3];
    v2f t0=a0+a2, t1=a0-a2, t2=a1+a3, t3=a1-a3;
    v2f it3; it3.x = -t3.y; it3.y = t3.x;
    v2f y0=t0+t2, y2=t0-t2, y1=t1+it3, y3=t1-it3;
    float m0 = INV_N * sqrtf(y0.x*y0.x + y0.y*y0.y);
    float m1 = INV_N * sqrtf(y1.x*y1.x + y1.y*y1.y);
    float m2 = INV_N * sqrtf(y2.x*y2.x + y2.y*y2.y);
    float m3 = INV_N * sqrtf(y3.x*y3.x + y3.y*y3.y);
    float p0=m0+m2, p1=m0-m2, p2=m1+m3, p3=m1-m3;
    v2f o0; o0.x = p0+p2; o0.y = 0.f;
    v2f o1; o1.x = p1;    o1.y = -p3;
    v2f o2; o2.x = p0-p2; o2.y = 0.f;
    v2f o3; o3.x = p1;    o3.y = p3;
    dp[4*q]=o0; dp[4*q+1]=o1; dp[4*q+2]=o2; dp[4*q+3]=o3;
  }
}

// Generic decimated pipeline body for LOGN in {10,11,12,13}.
// RMAX/JL parametrize the output pruning of the final stage.
template<int LOGN, int RMAX, bool JL>
__device__ __forceinline__ void o2_body(v2f* ds, int t)
{
  constexpr int LOGM1 = LOGN-4;
  super_dif16_sparse<+1, (1<<LOGM1), LOGM1, 8>(ds, t, 0);
  __syncthreads();
  dif_chain<+1, LOGM1-4>(ds, t);
  constexpr int LOGMM = ((LOGM1-5)%4)+1;
  mid_generic<LOGMM>(ds, t);
  __syncthreads();
  dit_chain<-1, LOGMM, LOGM1>(ds, t);
  final_prune<-1, LOGM1, RMAX, JL>(ds, t);
  __syncthreads();
}

// Generic fold: SEGT = 64*PERK threads, scale applied at write.
template<int PERK>
__device__ __forceinline__ void fold_generic(const v2f* ds, const float* __restrict__ phi,
                                             float* outp, int t, float scale)
{
  const int k = t / PERK, g = t % PERK;
  float sv, cv, ss, cs;
  __sincosf((TWO_PI/64.f) * (float)((g*k) & 63), &sv, &cv);
  __sincosf((TWO_PI/64.f) * (float)((PERK*k) & 63), &ss, &cs);
  float acc = 0.f;
#pragma unroll
  for (int m = 0; m < 256/PERK; ++m) {
    const int f = g + PERK*m;
    v2f u = ds[f + (f>>4)];
    float wgt = phi[f] * ((f == 0) ? 1.f : 2.f);
    acc += wgt * (u.x*cv - u.y*sv);
    float nc = cv*cs - sv*ss, ns = cv*ss + sv*cs;
    cv = nc; sv = ns;
  }
#pragma unroll
  for (int o = 1; o < PERK; o <<= 1) acc += __shfl_xor(acc, o);
  if (g == 0) outp[k] = acc * scale;
}

// phi-fold for full-size (SEGT=1024) pipelines.
__device__ void fold_store16(const v2f* d, const float* __restrict__ phi, float* outp, int tid)
{
  const int k = tid >> 4, g = tid & 15;
  float sv, cv;
  __sincosf((TWO_PI/64.f) * (float)((g*k) & 63), &sv, &cv);
  const int km = k & 3;
  const float strRe = (km==0) ? 1.f : (km==2 ? -1.f : 0.f);
  const float strIm = (km==1) ? 1.f : (km==3 ? -1.f : 0.f);
  float acc = 0.f;
#pragma unroll
  for (int m = 0; m < 16; ++m) {
    const int f = g + 16*m;
    v2f u = d[pad(f)];
    float wgt = phi[f] * ((f == 0) ? 1.f : 2.f);
    acc += wgt * (u.x*cv - u.y*sv);
    float nc = cv*strRe - sv*strIm;
    float ns = cv*strIm + sv*strRe;
    cv = nc; sv = ns;
  }
  acc += __shfl_xor(acc, 1);
  acc += __shfl_xor(acc, 2);
  acc += __shfl_xor(acc, 4);
  acc += __shfl_xor(acc, 8);
  if (g == 0) outp[k] = acc * INV_N;
}

// Reference pair index (j1-major, valid j2 > j1/8).
__device__ __forceinline__ int pair_index(int j1, int j2)
{
  const int q = j1 >> 3;
  return 8*(7*q - (q*(q-1))/2) + (j1 & 7)*(7 - q) + (j2 - q - 1);
}

// psi2 band widths W(j2) = ceil(4.5 * 5734.4 * 2^-j2)
__device__ __constant__ int WTAB[8]  = {16384, 12903, 6452, 3226, 1613, 807, 404, 202};
// U1h store bound per j1-octave q: W(q+1) capped at 8193
__device__ __constant__ int SBTAB[8] = {8193, 6452, 3226, 1613, 807, 404, 202, 0};

// ---- radix-4 float2 path for k_fft_x ----
__device__ __forceinline__ float2 f2add(float2 a, float2 b){ return make_float2(a.x+b.x, a.y+b.y); }
__device__ __forceinline__ float2 f2sub(float2 a, float2 b){ return make_float2(a.x-b.x, a.y-b.y); }
__device__ __forceinline__ float2 cmul_cs(float2 a, float c, float s){
  return make_float2(a.x*c - a.y*s, a.x*s + a.y*c);
}
__device__ void dif_sweep(float2* d, int tid, float sgn, int mb_hi, int mb_lo)
{
  const float ang = sgn * (TWO_PI / (float)T_N);
  for (int mbits = mb_hi; mbits >= mb_lo; mbits -= 2) {
    const int M = 1 << mbits;
#pragma unroll 8
    for (int v = tid; v < T_N/4; v += NT) {
      const int j = v & (M-1);
      const int base = ((v >> mbits) << (mbits+2)) | j;
      const int i0 = pad(base), i1 = pad(base+M), i2 = pad(base+2*M), i3 = pad(base+3*M);
      float2 a0=d[i0], a1=d[i1], a2=d[i2], a3=d[i3];
      float2 t0=f2add(a0,a2), t1=f2sub(a0,a2), t2=f2add(a1,a3), t3=f2sub(a1,a3);
      float2 y0=f2add(t0,t2), y2=f2sub(t0,t2);
      float2 y1=make_float2(t1.x - sgn*t3.y, t1.y + sgn*t3.x);
      float2 y3=make_float2(t1.x + sgn*t3.y, t1.y - sgn*t3.x);
      float s1,c1;
      __sincosf(ang * (float)(j << (12-mbits)), &s1, &c1);
      float c2=c1*c1-s1*s1, s2=2.f*c1*s1;
      float c3=c1*c2-s1*s2, s3=c1*s2+s1*c2;
      d[i0]=y0;
      d[i1]=cmul_cs(y1,c1,s1);
      d[i2]=cmul_cs(y2,c2,s2);
      d[i3]=cmul_cs(y3,c3,s3);
    }
    __syncthreads();
  }
}
__device__ void fold_store8(const float2* d, const float* __restrict__ phi, float* outp, int tid)
{
  const int k = tid >> 3, g = tid & 7;
  float acc = 0.f;
  for (int f = g; f < FOLD_F; f += 8) {
    float2 u = d[pad(f)];
    float w = phi[f] * ((f == 0) ? 1.f : 2.f);
    float sv, cv;
    __sincosf((TWO_PI/64.f) * (float)((f*k) & 63), &sv, &cv);
    acc += w * (u.x*cv - u.y*sv);
  }
  acc += __shfl_xor(acc, 1);
  acc += __shfl_xor(acc, 2);
  acc += __shfl_xor(acc, 4);
  if (g == 0) outp[k] = acc * INV_N;
}

// K1: xh = FFT(x) + S0 fold.
__global__ void __launch_bounds__(NT) k_fft_x(const float* __restrict__ x, const float* __restrict__ phi,
                                              float2* __restrict__ xh, float* __restrict__ out)
{
  extern __shared__ char smem[];
  float2* d = (float2*)smem;
  const int tid = threadIdx.x;
  const int b = blockIdx.x;
  const float* xr = x + b * T_N;
  for (int i = tid; i < T_N; i += NT) d[pad(i)] = make_float2(xr[i], 0.f);
  __syncthreads();
  dif_sweep(d, tid, -1.f, 12, 0);
  for (int p = tid; p < T_N; p += NT) {
    int r = rev4_14(p);
    if (p < r) { int ip = pad(p), ir = pad(r); float2 t = d[ip]; d[ip] = d[ir]; d[ir] = t; }
  }
  __syncthreads();
  float2* xrow = xh + (size_t)b * T_N;
  for (int i = tid; i < T_N; i += NT) xrow[i] = d[pad(i)];
  fold_store8(d, phi, out + b * 64, tid);
}

// K2: j1 < 16 (octaves 0,1): full 16k pipeline (sb too wide to decimate).
__global__ void __launch_bounds__(NT2, 4) k_o1_full(const float2* __restrict__ xh, const float* __restrict__ psi1,
                                                    const float* __restrict__ phi, float2* __restrict__ u1h,
                                                    float* __restrict__ out)
{
  extern __shared__ char smem[];
  v2f* d = (v2f*)smem;
  const int tid = threadIdx.x;
  const int b = blockIdx.x >> 4, j1 = blockIdx.x & 15;
  const float2* xrow = xh + (size_t)b * T_N;
  const float* prow = psi1 + j1 * T_N;
  const float c = 5734.4f * exp2f(-0.125f * (float)j1);
  const int lo = max(0, (int)(0.36f * c));
  const int hi = min(T_N, (int)(1.64f * c) + 2);
#pragma unroll
  for (int s = 0; s < T_N/NT2; ++s) {
    int i = tid + s*NT2;
    v2f z; z.x = 0.f; z.y = 0.f;
    if (i >= lo && i < hi) {
      float2 v = xrow[i];
      float p = prow[i];
      z.x = v.x*p; z.y = v.y*p;
    }
    d[pad(i)] = z;
  }
  __syncthreads();
  const int k_lo = lo >> 10, k_hi = (hi + 1023) >> 10;
  const int K1 = pow2ceil16(k_hi - k_lo);
  const int k0 = min(k_lo, 16 - K1);
  stage1_dispatch(d, tid, k0, K1, 0, NT2);
  stage2_dispatch(d, tid, 0, 16);
  super_dif16<+1, 4, 2>(d, tid);     __syncthreads();
  fused_mid4(d, tid);                __syncthreads();
  super_dit16<-1, 4, 2>(d, tid);     __syncthreads();
  super_dit16<-1, 64, 6>(d, tid);    __syncthreads();
  super_dit16<-1, 1024, 10>(d, tid); __syncthreads();
  const int sb = SBTAB[j1 >> 3];
  float2* urow = u1h + (size_t)(b * N1 + j1) * USTRIDE;
  for (int i = tid; i < sb; i += NT2) {
    v2f u = d[pad(i)];
    urow[i] = make_float2(u.x, u.y);
  }
  fold_store16(d, phi, out + 1024 + (size_t)(b * N1 + j1) * 64, tid);
}

// Decimated order-1 body: demodulated band [lo,hi) at slots [0,W), N'-point
// pipeline; store R*bins[0,sb) to u1h; S1 fold at scale 1/N'.
template<int LOGN>
__device__ __forceinline__ void o1_dec_body(v2f* sm, int sub, int t, int j1, int b,
    const float2* __restrict__ xh, const float* __restrict__ psi1,
    const float* __restrict__ phi, float2* __restrict__ u1h, float* __restrict__ out)
{
  constexpr int N = 1<<LOGN, SEGT = N/16;
  const bool valid = (j1 < 64);
  const int jc = valid ? j1 : 63;
  v2f* ds = sm + sub*N + ((sub*N)>>4);
  int lo = 0, W = 0;
  if (valid) {
    const float c = 5734.4f * exp2f(-0.125f*(float)j1);
    lo = max(0, (int)(0.36f*c));
    const int hi = min(T_N, (int)(1.64f*c)+2);
    W = hi - lo;
  }
  const float2* xrow = xh + (size_t)b * T_N;
  const float* prow = psi1 + jc * T_N;
#pragma unroll
  for (int s = 0; s < 16; ++s) {
    int f = t + s*SEGT;
    v2f z; z.x = 0.f; z.y = 0.f;
    if (f < W) { float2 xv = xrow[lo+f]; float p = prow[lo+f]; z.x = xv.x*p; z.y = xv.y*p; }
    ds[f + (f>>4)] = z;
  }
  __syncthreads();
  o2_body<LOGN, 7, false>(ds, t);       // bins [0, 7*N/16) >= sb
  if (valid) {
    const int sb = SBTAB[j1>>3];
    const float R = (float)(T_N >> LOGN);
    float2* urow = u1h + (size_t)(b*N1 + j1) * USTRIDE;
    for (int i = t; i < sb; i += SEGT) {
      v2f u = ds[i + (i>>4)];
      urow[i] = make_float2(R*u.x, R*u.y);
    }
    fold_generic<SEGT/64>(ds, phi, out + 1024 + (size_t)(b*N1 + j1)*64, t, 1.f/(float)N);
  }
}

// K3: decimated order-1, j1 >= 16.  9 groups per batch:
// grp 0-3: q=2 N'=8192 PPB=2 | 4-5: q=3 4096x4 | 6: q=4 2048x8 | 7-8: q>=5 1024x16.
__global__ void __launch_bounds__(NT2, 4) k_o1_dec(const float2* __restrict__ xh, const float* __restrict__ psi1,
                                                   const float* __restrict__ phi, float2* __restrict__ u1h,
                                                   float* __restrict__ out)
{
  extern __shared__ char smem[];
  v2f* sm = (v2f*)smem;
  const int grp = blockIdx.x % 9, b = blockIdx.x / 9;
  if (grp < 4) {
    o1_dec_body<13>(sm, threadIdx.x >> 9, threadIdx.x & 511, 16 + grp*2 + (threadIdx.x >> 9),
                    b, xh, psi1, phi, u1h, out);
  } else if (grp < 6) {
    o1_dec_body<12>(sm, threadIdx.x >> 8, threadIdx.x & 255, 24 + (grp-4)*4 + (threadIdx.x >> 8),
                    b, xh, psi1, phi, u1h, out);
  } else if (grp == 6) {
    o1_dec_body<11>(sm, threadIdx.x >> 7, threadIdx.x & 127, 32 + (threadIdx.x >> 7),
                    b, xh, psi1, phi, u1h, out);
  } else {
    o1_dec_body<10>(sm, threadIdx.x >> 6, threadIdx.x & 63, 40 + (grp-7)*16 + (threadIdx.x >> 6),
                    b, xh, psi1, phi, u1h, out);
  }
}

// K4: order-2, j2 in {1,2}: full 16384 pipeline (W too wide to decimate).
__global__ void __launch_bounds__(NT2, 4) k_o2_16k(const float2* __restrict__ u1h, const float* __restrict__ psi2,
                                                   const float* __restrict__ phi, float* __restrict__ out)
{
  extern __shared__ char smem[];
  v2f* d = (v2f*)smem;
  const int tid = threadIdx.x;
  const int b = blockIdx.x / 24, cls_p = blockIdx.x % 24;
  const int j2 = (cls_p < 8) ? 1 : 2;
  const int j1 = cls_p - ((cls_p < 8) ? 0 : 8);
  const int W = WTAB[j2];
  const float2* urow = u1h + (size_t)(b * N1 + j1) * USTRIDE;
  const float* prow = psi2 + j2 * T_N;
#pragma unroll
  for (int s = 0; s < T_N/NT2; ++s) {
    int i = tid + s*NT2;
    v2f z; z.x = 0.f; z.y = 0.f;
    if (i < W) {
      float2 u;
      if (i <= T_N/2) u = urow[i];
      else { float2 t = urow[T_N - i]; u = make_float2(t.x, -t.y); }
      float ps = prow[i];
      z.x = u.x*ps; z.y = u.y*ps;
    }
    d[pad(i)] = z;
  }
  __syncthreads();
  const int K1 = pow2ceil16((W + 1023) >> 10);
  stage1_dispatch(d, tid, 0, K1, 0, W);
  stage2_dispatch(d, tid, 0, 16);
  super_dif16<+1, 4, 2>(d, tid);      __syncthreads();
  fused_mid4(d, tid);                 __syncthreads();
  super_dit16<-1, 4, 2>(d, tid);      __syncthreads();
  super_dit16_m64_prune<-1>(d, tid);  __syncthreads();
  super_dit16_m1024_bin256<-1>(d, tid); __syncthreads();
  const int p = pair_index(j1, j2);
  fold_store16(d, phi, out + 66560 + (size_t)(b * NPAIR + p) * 64, tid);
}

// Decimated order-2 body (S2 fold only).
template<int LOGN>
__device__ __forceinline__ void o2_cls_body(v2f* sm, int sub, int t, int b, int j1, int j2, bool valid,
    const float2* __restrict__ u1h, const float* __restrict__ psi2,
    const float* __restrict__ phi, float* __restrict__ out)
{
  constexpr int N = 1<<LOGN, SEGT = N/16;
  v2f* ds = sm + sub*N + ((sub*N)>>4);
  const int W = valid ? WTAB[j2 & 7] : 0;
  const float2* urow = u1h + (size_t)(b * N1 + j1) * USTRIDE;
  const float* prow = psi2 + j2 * T_N;
#pragma unroll
  for (int s = 0; s < 16; ++s) {
    int f = t + s*SEGT;
    v2f z; z.x = 0.f; z.y = 0.f;
    if (f < W) { float2 u = urow[f]; float ps = prow[f]; z.x = u.x*ps; z.y = u.y*ps; }
    ds[f + (f>>4)] = z;
  }
  __syncthreads();
  constexpr int RM = ((1<<(LOGN-4)) >= 256) ? 1 : (256 >> (LOGN-4));
  constexpr bool JL = ((1<<(LOGN-4)) > 256);
  o2_body<LOGN, RM, JL>(ds, t);
  if (valid) {
    const int p = pair_index(j1, j2);
    fold_generic<SEGT/64>(ds, phi, out + 66560 + (size_t)(b * NPAIR + p) * 64, t, 1.f/(float)N);
  }
}

// K5: merged decimated order-2 classes.  32 groups per batch:
// 0-11: j2=3 N'=8192 PPB=2 | 12-19: j2=4 4096x4 | 20-24: j2=5 2048x8 | 25-31: j2 in {6,7} 1024x16.
__global__ void __launch_bounds__(NT2, 4) k_o2_dec(const float2* __restrict__ u1h, const float* __restrict__ psi2,
                                                   const float* __restrict__ phi, float* __restrict__ out)
{
  extern __shared__ char smem[];
  v2f* sm = (v2f*)smem;
  const int grp = blockIdx.x & 31, b = blockIdx.x >> 5;
  if (grp < 12) {
    const int sub = threadIdx.x >> 9, t = threadIdx.x & 511;
    o2_cls_body<13>(sm, sub, t, b, grp*2 + sub, 3, true, u1h, psi2, phi, out);
  } else if (grp < 20) {
    const int sub = threadIdx.x >> 8, t = threadIdx.x & 255;
    o2_cls_body<12>(sm, sub, t, b, (grp-12)*4 + sub, 4, true, u1h, psi2, phi, out);
  } else if (grp < 25) {
    const int sub = threadIdx.x >> 7, t = threadIdx.x & 127;
    o2_cls_body<11>(sm, sub, t, b, (grp-20)*8 + sub, 5, true, u1h, psi2, phi, out);
  } else {
    const int sub = threadIdx.x >> 6, t = threadIdx.x & 63;
    const int cls_p = (grp-25)*16 + sub;
    const bool valid = (cls_p < 104);
    const int j2 = (cls_p < 48) ? 6 : 7;
    const int j1 = cls_p - ((cls_p < 48) ? 0 : 48);
    o2_cls_body<10>(sm, sub, t, b, j1, j2, valid, u1h, psi2, phi, out);
  }
}

extern "C" void kernel_launch(void* const* d_in, const int* in_sizes, int n_in,
                              void* d_out, int out_size, void* d_ws, size_t ws_size,
                              hipStream_t stream)
{
  const float* x    = (const float*)d_in[0];
  const float* psi1 = (const float*)d_in[1];
  const float* psi2 = (const float*)d_in[2];
  const float* phi  = (const float*)d_in[3];
  float* out = (float*)d_out;

  float2* xh  = (float2*)d_ws;
  float2* u1h = xh + (size_t)B_SZ * T_N;

  const size_t lds = (size_t)(T_N + (T_N >> 4)) * sizeof(float2);  // 139264 B

  (void)hipFuncSetAttribute((const void*)k_fft_x,   hipFuncAttributeMaxDynamicSharedMemorySize, (int)lds);
  (void)hipFuncSetAttribute((const void*)k_o1_full, hipFuncAttributeMaxDynamicSharedMemorySize, (int)lds);
  (void)hipFuncSetAttribute((const void*)k_o1_dec,  hipFuncAttributeMaxDynamicSharedMemorySize, (int)lds);
  (void)hipFuncSetAttribute((const void*)k_o2_16k,  hipFuncAttributeMaxDynamicSharedMemorySize, (int)lds);
  (void)hipFuncSetAttribute((const void*)k_o2_dec,  hipFuncAttributeMaxDynamicSharedMemorySize, (int)lds);

  hipLaunchKernelGGL(k_fft_x,   dim3(B_SZ),      dim3(NT),  lds, stream, x, phi, xh, out);
  hipLaunchKernelGGL(k_o1_full, dim3(B_SZ * 16), dim3(NT2), lds, stream, xh, psi1, phi, u1h, out);
  hipLaunchKernelGGL(k_o1_dec,  dim3(B_SZ * 9),  dim3(NT2), lds, stream, xh, psi1, phi, u1h, out);
  hipLaunchKernelGGL(k_o2_16k,  dim3(B_SZ * 24), dim3(NT2), lds, stream, u1h, psi2, phi, out);
  hipLaunchKernelGGL(k_o2_dec,  dim3(B_SZ * 32), dim3(NT2), lds, stream, u1h, psi2, phi, out);
}

// Round 10
// 253.749 us; speedup vs baseline: 3.4376x; 1.0233x over previous
//
#include <hip/hip_runtime.h>
#include <math.h>

// Wavelet scattering, T=16384.  Radix-16 register-blocked in-LDS FFTs with
// per-octave decimated pipelines (demodulate band to baseband, N'-point
// IFFT -> |.|/T -> N'-point forward DFT, U_full[f] ~= (T/N')*DFT_N'[f]).
// R10: launch-graph compaction — 3 launches (k_fft_x -> k_o1 -> k_o2);
// heavy 16k-pipeline blocks at low block indices, decimated classes backfill.

#define T_N   16384
#define NT    512
#define NT2   1024
#define B_SZ  16
#define N1    64
#define NPAIR 224
#define FOLD_F 256
#define USTRIDE 8208
#define INV_N (1.0f/16384.0f)
#define TWO_PI 6.283185307179586f

typedef float v2f __attribute__((ext_vector_type(2)));

__device__ __forceinline__ int pad(int i) { return i + (i >> 4); }

__device__ __forceinline__ v2f cmulw(v2f a, v2f w){
  v2f n; n.x = -a.y; n.y = a.x;
  return w.x * a + w.y * n;
}
__device__ __forceinline__ constexpr int br4(int x){
  return ((x&1)<<3)|((x&2)<<1)|((x&4)>>1)|((x&8)>>3);
}
template<int LB>
__device__ __forceinline__ constexpr int brN(int x){
  int r=0;
  for(int i=0;i<LB;++i){ r=(r<<1)|((x>>i)&1); }
  return r;
}
__device__ __forceinline__ int rev4_14(int p){
  unsigned r = __brev((unsigned)p) >> 18;
  return (int)(((r & 0x2AAAu) >> 1) | ((r & 0x1555u) << 1));
}
__device__ __forceinline__ int pow2ceil16(int k){
  return (k<=1)?1:(k<=2)?2:(k<=4)?4:(k<=8)?8:16;
}

// tw[r] = w^r via depth-4 product tree.
__device__ __forceinline__ void twiddle_tree(v2f w, v2f* tw){
  tw[0].x = 1.f; tw[0].y = 0.f;
  tw[1] = w;
  tw[2] = cmulw(w, w);
  tw[4] = cmulw(tw[2], tw[2]);
  tw[8] = cmulw(tw[4], tw[4]);
  tw[3] = cmulw(tw[2], w);
  tw[5] = cmulw(tw[4], w);
  tw[6] = cmulw(tw[4], tw[2]);
  tw[7] = cmulw(tw[4], tw[3]);
  tw[9]  = cmulw(tw[8], w);
  tw[10] = cmulw(tw[8], tw[2]);
  tw[11] = cmulw(tw[8], tw[3]);
  tw[12] = cmulw(tw[8], tw[4]);
  tw[13] = cmulw(tw[8], tw[5]);
  tw[14] = cmulw(tw[8], tw[6]);
  tw[15] = cmulw(tw[8], tw[7]);
}

// Generic fully-unrolled DFT of size 2^LOGNN (<=16); y[r] lands at a[brN(r)].
template<int SGN, int LOGNN>
__device__ __forceinline__ void dft_reg(v2f* a){
  constexpr int NN = 1<<LOGNN;
  static constexpr float C16[16] = {
    1.f, 0.98078528f, 0.92387953f, 0.83146961f, 0.70710678f, 0.55557023f,
    0.38268343f, 0.19509032f, 0.f, -0.19509032f, -0.38268343f, -0.55557023f,
    -0.70710678f, -0.83146961f, -0.92387953f, -0.98078528f };
  static constexpr float S16[16] = {
    0.f, 0.19509032f, 0.38268343f, 0.55557023f, 0.70710678f, 0.83146961f,
    0.92387953f, 0.98078528f, 1.f, 0.98078528f, 0.92387953f, 0.83146961f,
    0.70710678f, 0.55557023f, 0.38268343f, 0.19509032f };
#pragma unroll
  for (int m = NN/2; m >= 1; m >>= 1) {
#pragma unroll
    for (int base = 0; base < NN; base += 2*m) {
#pragma unroll
      for (int j = 0; j < m; ++j) {
        v2f u = a[base+j], v = a[base+j+m];
        a[base+j] = u + v;
        v2f w = u - v;
        const int ti = (j*16)/m;
        v2f tw; tw.x = C16[ti]; tw.y = (float)SGN * S16[ti];
        a[base+j+m] = cmulw(w, tw);
      }
    }
  }
}
template<int SGN>
__device__ __forceinline__ void dft16(v2f* a){ dft_reg<SGN,4>(a); }

// Full DIF super-stage radix-16 at stride M.
template<int SGN, int M, int LOGM>
__device__ __forceinline__ void super_dif16(v2f* d, int g)
{
  const int j = g & (M-1);
  const int base = ((g >> LOGM) << (LOGM+4)) | j;
  v2f* dp = d + pad(base);
  v2f a[16];
#pragma unroll
  for (int k = 0; k < 16; ++k) a[k] = dp[k*M + ((k*M)>>4)];
  dft16<SGN>(a);
  float sj, cj;
  __sincosf((float)SGN * (TWO_PI / (16.f*(float)M)) * (float)j, &sj, &cj);
  v2f w; w.x = cj; w.y = sj;
  v2f tw[16];
  twiddle_tree(w, tw);
  dp[0] = a[0];
#pragma unroll
  for (int r = 1; r < 16; ++r)
    dp[r*M + ((r*M)>>4)] = cmulw(a[br4(r)], tw[r]);
}

// SPARSE DIF super-stage: only taps [k0,k0+K) possibly nonzero (rest zeros).
template<int SGN, int M, int LOGM, int K>
__device__ __forceinline__ void super_dif16_sparse(v2f* d, int g, int k0)
{
  static constexpr float CW[16] = { 1.f, 0.92387953f, 0.70710678f, 0.38268343f,
    0.f, -0.38268343f, -0.70710678f, -0.92387953f, -1.f, -0.92387953f,
    -0.70710678f, -0.38268343f, 0.f, 0.38268343f, 0.70710678f, 0.92387953f };
  static constexpr float SW[16] = { 0.f, 0.38268343f, 0.70710678f, 0.92387953f,
    1.f, 0.92387953f, 0.70710678f, 0.38268343f, 0.f, -0.38268343f,
    -0.70710678f, -0.92387953f, -1.f, -0.92387953f, -0.70710678f, -0.38268343f };
  const int j = g & (M-1);
  const int base = ((g >> LOGM) << (LOGM+4)) | j;
  v2f* dp = d + pad(base);
  v2f a[K];
#pragma unroll
  for (int m = 0; m < K; ++m) {
    const int k = k0 + m;
    a[m] = dp[k*M + ((k*M)>>4)];
  }
  v2f y[16];
  if constexpr (K == 1) {
#pragma unroll
    for (int r = 0; r < 16; ++r) y[r] = a[0];
  } else if constexpr (K == 2) {
#pragma unroll
    for (int r0 = 0; r0 < 8; ++r0) {
      v2f w; w.x = CW[r0]; w.y = (float)SGN * SW[r0];
      v2f b1 = cmulw(a[1], w);
      y[r0]   = a[0] + b1;
      y[r0+8] = a[0] - b1;
    }
  } else if constexpr (K == 4) {
#pragma unroll
    for (int r0 = 0; r0 < 4; ++r0) {
      v2f z1, z2, z3;
      { v2f w; w.x = CW[r0];        w.y = (float)SGN*SW[r0];        z1 = cmulw(a[1], w); }
      { v2f w; w.x = CW[(2*r0)&15]; w.y = (float)SGN*SW[(2*r0)&15]; z2 = cmulw(a[2], w); }
      { v2f w; w.x = CW[(3*r0)&15]; w.y = (float)SGN*SW[(3*r0)&15]; z3 = cmulw(a[3], w); }
      v2f e0 = a[0]+z2, e1 = a[0]-z2, o0 = z1+z3, o1 = z1-z3;
      v2f io; io.x = -(float)SGN*o1.y; io.y = (float)SGN*o1.x;
      y[r0]    = e0 + o0;
      y[r0+4]  = e1 + io;
      y[r0+8]  = e0 - o0;
      y[r0+12] = e1 - io;
    }
  } else { // K == 8
#pragma unroll
    for (int r0 = 0; r0 < 2; ++r0) {
      v2f z[8];
      z[0] = a[0];
#pragma unroll
      for (int m = 1; m < 8; ++m) {
        v2f w; w.x = CW[(m*r0)&15]; w.y = (float)SGN*SW[(m*r0)&15];
        z[m] = cmulw(a[m], w);
      }
      v2f E[4], O[4];
      {
        v2f e0=z[0]+z[4], e1=z[0]-z[4], o0=z[2]+z[6], o1=z[2]-z[6];
        v2f io; io.x=-(float)SGN*o1.y; io.y=(float)SGN*o1.x;
        E[0]=e0+o0; E[1]=e1+io; E[2]=e0-o0; E[3]=e1-io;
      }
      {
        v2f e0=z[1]+z[5], e1=z[1]-z[5], o0=z[3]+z[7], o1=z[3]-z[7];
        v2f io; io.x=-(float)SGN*o1.y; io.y=(float)SGN*o1.x;
        O[0]=e0+o0; O[1]=e1+io; O[2]=e0-o0; O[3]=e1-io;
      }
      constexpr float RT = 0.70710678f;
#pragma unroll
      for (int r1 = 0; r1 < 4; ++r1) {
        v2f w8;
        if (r1 == 0)      { w8.x = 1.f;  w8.y = 0.f; }
        else if (r1 == 1) { w8.x = RT;   w8.y = (float)SGN*RT; }
        else if (r1 == 2) { w8.x = 0.f;  w8.y = (float)SGN; }
        else              { w8.x = -RT;  w8.y = (float)SGN*RT; }
        v2f t = cmulw(O[r1], w8);
        y[2*r1 + r0]     = E[r1] + t;
        y[2*r1 + r0 + 8] = E[r1] - t;
      }
    }
  }
  float sj, cj;
  __sincosf((float)SGN * (TWO_PI / (16.f*(float)M)) * (float)(j + k0*M), &sj, &cj);
  v2f w; w.x = cj; w.y = sj;
  v2f tw[16];
  twiddle_tree(w, tw);
  dp[0] = y[0];
#pragma unroll
  for (int r = 1; r < 16; ++r)
    dp[r*M + ((r*M)>>4)] = cmulw(y[r], tw[r]);
}

// Runtime dispatch (16k pipelines), barriers included.
__device__ __forceinline__ void stage1_dispatch(v2f* d, int tid, int k0, int K1, int jlo, int jhi)
{
  if (K1 == 16)     super_dif16<+1, 1024, 10>(d, tid);
  else if (K1 == 8) super_dif16_sparse<+1,1024,10,8>(d, tid, k0);
  else if (K1 == 4) super_dif16_sparse<+1,1024,10,4>(d, tid, k0);
  else if (K1 == 2) super_dif16_sparse<+1,1024,10,2>(d, tid, k0);
  else { if (tid >= jlo && tid < jhi) super_dif16_sparse<+1,1024,10,1>(d, tid, k0); }
  __syncthreads();
}
__device__ __forceinline__ void stage2_dispatch(v2f* d, int tid, int k0, int K2)
{
  if (K2 == 16)     super_dif16<+1, 64, 6>(d, tid);
  else if (K2 == 8) super_dif16_sparse<+1,64,6,8>(d, tid, k0);
  else if (K2 == 4) super_dif16_sparse<+1,64,6,4>(d, tid, k0);
  else if (K2 == 2) super_dif16_sparse<+1,64,6,2>(d, tid, k0);
  else              super_dif16_sparse<+1,64,6,1>(d, tid, k0);
  __syncthreads();
}

// Full DIT super-stage radix-16 at stride M.
template<int SGN, int M, int LOGM>
__device__ __forceinline__ void super_dit16(v2f* d, int g)
{
  const int j = g & (M-1);
  const int base = ((g >> LOGM) << (LOGM+4)) | j;
  v2f* dp = d + pad(base);
  float sj, cj;
  __sincosf((float)SGN * (TWO_PI / (16.f*(float)M)) * (float)j, &sj, &cj);
  v2f w; w.x = cj; w.y = sj;
  v2f tw[16];
  twiddle_tree(w, tw);
  v2f a[16];
  a[0] = dp[0];
#pragma unroll
  for (int k = 1; k < 16; ++k)
    a[k] = cmulw(dp[k*M + ((k*M)>>4)], tw[k]);
  dft16<SGN>(a);
#pragma unroll
  for (int r = 0; r < 16; ++r) dp[r*M + ((r*M)>>4)] = a[br4(r)];
}

// PRUNED DIT16 at M=64 (r<4) — 16k pipeline.
template<int SGN>
__device__ __forceinline__ void super_dit16_m64_prune(v2f* d, int g)
{
  constexpr int M = 64;
  constexpr int PSTR = M + (M>>4);
  const int j = g & 63;
  const int base = ((g >> 6) << 10) | j;
  v2f* dp = d + pad(base);
  float sj, cj;
  __sincosf((float)SGN * (TWO_PI / 1024.f) * (float)j, &sj, &cj);
  v2f w; w.x = cj; w.y = sj;
  v2f tw[16];
  twiddle_tree(w, tw);
  v2f a[16];
  a[0] = dp[0];
#pragma unroll
  for (int k = 1; k < 16; ++k)
    a[k] = cmulw(dp[k*M + ((k*M)>>4)], tw[k]);
  v2f Y[4][4];
#pragma unroll
  for (int c = 0; c < 4; ++c) {
    v2f s0=a[c], s1=a[c+4], s2=a[c+8], s3=a[c+12];
    v2f e0 = s0+s2, e1 = s0-s2, o0 = s1+s3, o1 = s1-s3;
    v2f io1; io1.x = -(float)SGN * o1.y; io1.y = (float)SGN * o1.x;
    Y[c][0] = e0 + o0;
    Y[c][1] = e1 + io1;
    Y[c][2] = e0 - o0;
    Y[c][3] = e1 - io1;
  }
  static constexpr float WC[10] = {1.f,0.92387953f,0.70710678f,0.38268343f,0.f,
                                   -0.38268343f,-0.70710678f,-0.92387953f,-1.f,-0.92387953f};
  static constexpr float WS[10] = {0.f,0.38268343f,0.70710678f,0.92387953f,1.f,
                                   0.92387953f,0.70710678f,0.38268343f,0.f,-0.38268343f};
#pragma unroll
  for (int r = 0; r < 4; ++r) {
    v2f acc = Y[0][r];
#pragma unroll
    for (int c = 1; c < 4; ++c) {
      v2f wc; wc.x = WC[r*c]; wc.y = (float)SGN * WS[r*c];
      acc += cmulw(Y[c][r], wc);
    }
    dp[r*PSTR] = acc;
  }
}

// PRUNED final DIT16 at M=1024: bins j<256 — 16k pipeline.
template<int SGN>
__device__ __forceinline__ void super_dit16_m1024_bin256(v2f* d, int tid)
{
  if (tid < 256) {
    const int j = tid;
    v2f* dp = d + pad(j);
    float sj, cj;
    __sincosf((float)SGN * (TWO_PI / 16384.f) * (float)j, &sj, &cj);
    v2f w; w.x = cj; w.y = sj;
    v2f tw[16];
    twiddle_tree(w, tw);
    v2f acc = dp[0];
#pragma unroll
    for (int k = 1; k < 16; ++k)
      acc += cmulw(dp[k*1024 + ((k*1024)>>4)], tw[k]);
    dp[0] = acc;
  }
}

// Generic output-pruned final DIT16 at M1 = 2^LOGM1: outputs r < RMAX.
template<int SGN, int LOGM1, int RMAX, bool JLIM>
__device__ __forceinline__ void final_prune(v2f* ds, int t)
{
  static constexpr float CW[16] = { 1.f, 0.92387953f, 0.70710678f, 0.38268343f,
    0.f, -0.38268343f, -0.70710678f, -0.92387953f, -1.f, -0.92387953f,
    -0.70710678f, -0.38268343f, 0.f, 0.38268343f, 0.70710678f, 0.92387953f };
  static constexpr float SW[16] = { 0.f, 0.38268343f, 0.70710678f, 0.92387953f,
    1.f, 0.92387953f, 0.70710678f, 0.38268343f, 0.f, -0.38268343f,
    -0.70710678f, -0.92387953f, -1.f, -0.92387953f, -0.70710678f, -0.38268343f };
  constexpr int M1 = 1<<LOGM1;
  const int j = t;
  if (JLIM && j >= 256) return;
  v2f* dp = ds + j + (j>>4);
  float sj, cj;
  __sincosf((float)SGN * (TWO_PI / (16.f*(float)M1)) * (float)j, &sj, &cj);
  v2f w; w.x = cj; w.y = sj;
  v2f tw[16];
  twiddle_tree(w, tw);
  v2f b[16];
  b[0] = dp[0];
#pragma unroll
  for (int k = 1; k < 16; ++k)
    b[k] = cmulw(dp[k*M1 + ((k*M1)>>4)], tw[k]);
  v2f y[RMAX];
#pragma unroll
  for (int r = 0; r < RMAX; ++r) {
    v2f acc = b[0];
#pragma unroll
    for (int k = 1; k < 16; ++k) {
      v2f wc; wc.x = CW[(r*k)&15]; wc.y = (float)SGN*SW[(r*k)&15];
      acc += cmulw(b[k], wc);
    }
    y[r] = acc;
  }
#pragma unroll
  for (int r = 0; r < RMAX; ++r) dp[r*M1 + ((r*M1)>>4)] = y[r];
}

// DIF chain descending (barrier after each stage).
template<int SGN, int LOGM>
__device__ __forceinline__ void dif_chain(v2f* ds, int t){
  super_dif16<SGN, (1<<LOGM), LOGM>(ds, t);
  __syncthreads();
  if constexpr (LOGM > 4) dif_chain<SGN, LOGM-4>(ds, t);
}
// DIT chain ascending up to (excluding) LOGTOP.
template<int SGN, int LOGM, int LOGTOP>
__device__ __forceinline__ void dit_chain(v2f* ds, int t){
  super_dit16<SGN, (1<<LOGM), LOGM>(ds, t);
  __syncthreads();
  if constexpr (LOGM + 4 < LOGTOP) dit_chain<SGN, LOGM+4, LOGTOP>(ds, t);
}

// Generic mid: per contiguous-16 (thread t): inverse DFT_MM -> |.|/T -> fwd DFT_MM.
template<int LOGMM>
__device__ __forceinline__ void mid_generic(v2f* ds, int t)
{
  constexpr int MM = 1<<LOGMM;
  v2f* dp = ds + 17*t;
#pragma unroll
  for (int q = 0; q < 16/MM; ++q) {
    v2f a[MM];
#pragma unroll
    for (int i = 0; i < MM; ++i) a[i] = dp[q*MM+i];
    dft_reg<+1,LOGMM>(a);
    v2f m[MM];
#pragma unroll
    for (int r = 0; r < MM; ++r) {
      v2f y = a[brN<LOGMM>(r)];
      m[r].x = INV_N * sqrtf(y.x*y.x + y.y*y.y);
      m[r].y = 0.f;
    }
    dft_reg<-1,LOGMM>(m);
#pragma unroll
    for (int k = 0; k < MM; ++k) dp[q*MM+k] = m[brN<LOGMM>(k)];
  }
}

// mid4 specialization used by 16k pipelines.
__device__ __forceinline__ void fused_mid4(v2f* d, int t)
{
  v2f* dp = d + 17*t;
#pragma unroll
  for (int q = 0; q < 4; ++q) {
    v2f a0=dp[4*q], a1=dp[4*q+1], a2=dp[4*q+2], a3=dp[4*q+3];
    v2f t0=a0+a2, t1=a0-a2, t2=a1+a3, t3=a1-a3;
    v2f it3; it3.x = -t3.y; it3.y = t3.x;
    v2f y0=t0+t2, y2=t0-t2, y1=t1+it3, y3=t1-it3;
    float m0 = INV_N * sqrtf(y0.x*y0.x + y0.y*y0.y);
    float m1 = INV_N * sqrtf(y1.x*y1.x + y1.y*y1.y);
    float m2 = INV_N * sqrtf(y2.x*y2.x + y2.y*y2.y);
    float m3 = INV_N * sqrtf(y3.x*y3.x + y3.y*y3.y);
    float p0=m0+m2, p1=m0-m2, p2=m1+m3, p3=m1-m3;
    v2f o0; o0.x = p0+p2; o0.y = 0.f;
    v2f o1; o1.x = p1;    o1.y = -p3;
    v2f o2; o2.x = p0-p2; o2.y = 0.f;
    v2f o3; o3.x = p1;    o3.y = p3;
    dp[4*q]=o0; dp[4*q+1]=o1; dp[4*q+2]=o2; dp[4*q+3]=o3;
  }
}

// Generic decimated pipeline body for LOGN in {10,11,12,13}.
template<int LOGN, int RMAX, bool JL>
__device__ __forceinline__ void o2_body(v2f* ds, int t)
{
  constexpr int LOGM1 = LOGN-4;
  super_dif16_sparse<+1, (1<<LOGM1), LOGM1, 8>(ds, t, 0);
  __syncthreads();
  dif_chain<+1, LOGM1-4>(ds, t);
  constexpr int LOGMM = ((LOGM1-5)%4)+1;
  mid_generic<LOGMM>(ds, t);
  __syncthreads();
  dit_chain<-1, LOGMM, LOGM1>(ds, t);
  final_prune<-1, LOGM1, RMAX, JL>(ds, t);
  __syncthreads();
}

// Generic fold: SEGT = 64*PERK threads, scale applied at write.
template<int PERK>
__device__ __forceinline__ void fold_generic(const v2f* ds, const float* __restrict__ phi,
                                             float* outp, int t, float scale)
{
  const int k = t / PERK, g = t % PERK;
  float sv, cv, ss, cs;
  __sincosf((TWO_PI/64.f) * (float)((g*k) & 63), &sv, &cv);
  __sincosf((TWO_PI/64.f) * (float)((PERK*k) & 63), &ss, &cs);
  float acc = 0.f;
#pragma unroll
  for (int m = 0; m < 256/PERK; ++m) {
    const int f = g + PERK*m;
    v2f u = ds[f + (f>>4)];
    float wgt = phi[f] * ((f == 0) ? 1.f : 2.f);
    acc += wgt * (u.x*cv - u.y*sv);
    float nc = cv*cs - sv*ss, ns = cv*ss + sv*cs;
    cv = nc; sv = ns;
  }
#pragma unroll
  for (int o = 1; o < PERK; o <<= 1) acc += __shfl_xor(acc, o);
  if (g == 0) outp[k] = acc * scale;
}

// phi-fold for full-size (1024-thread) pipelines.
__device__ void fold_store16(const v2f* d, const float* __restrict__ phi, float* outp, int tid)
{
  const int k = tid >> 4, g = tid & 15;
  float sv, cv;
  __sincosf((TWO_PI/64.f) * (float)((g*k) & 63), &sv, &cv);
  const int km = k & 3;
  const float strRe = (km==0) ? 1.f : (km==2 ? -1.f : 0.f);
  const float strIm = (km==1) ? 1.f : (km==3 ? -1.f : 0.f);
  float acc = 0.f;
#pragma unroll
  for (int m = 0; m < 16; ++m) {
    const int f = g + 16*m;
    v2f u = d[pad(f)];
    float wgt = phi[f] * ((f == 0) ? 1.f : 2.f);
    acc += wgt * (u.x*cv - u.y*sv);
    float nc = cv*strRe - sv*strIm;
    float ns = cv*strIm + sv*strRe;
    cv = nc; sv = ns;
  }
  acc += __shfl_xor(acc, 1);
  acc += __shfl_xor(acc, 2);
  acc += __shfl_xor(acc, 4);
  acc += __shfl_xor(acc, 8);
  if (g == 0) outp[k] = acc * INV_N;
}

// Reference pair index (j1-major, valid j2 > j1/8).
__device__ __forceinline__ int pair_index(int j1, int j2)
{
  const int q = j1 >> 3;
  return 8*(7*q - (q*(q-1))/2) + (j1 & 7)*(7 - q) + (j2 - q - 1);
}

// psi2 band widths W(j2) = ceil(4.5 * 5734.4 * 2^-j2)
__device__ __constant__ int WTAB[8]  = {16384, 12903, 6452, 3226, 1613, 807, 404, 202};
// U1h store bound per j1-octave q: W(q+1) capped at 8193
__device__ __constant__ int SBTAB[8] = {8193, 6452, 3226, 1613, 807, 404, 202, 0};

// ---- radix-4 float2 path for k_fft_x ----
__device__ __forceinline__ float2 f2add(float2 a, float2 b){ return make_float2(a.x+b.x, a.y+b.y); }
__device__ __forceinline__ float2 f2sub(float2 a, float2 b){ return make_float2(a.x-b.x, a.y-b.y); }
__device__ __forceinline__ float2 cmul_cs(float2 a, float c, float s){
  return make_float2(a.x*c - a.y*s, a.x*s + a.y*c);
}
__device__ void dif_sweep(float2* d, int tid, float sgn, int mb_hi, int mb_lo)
{
  const float ang = sgn * (TWO_PI / (float)T_N);
  for (int mbits = mb_hi; mbits >= mb_lo; mbits -= 2) {
    const int M = 1 << mbits;
#pragma unroll 8
    for (int v = tid; v < T_N/4; v += NT) {
      const int j = v & (M-1);
      const int base = ((v >> mbits) << (mbits+2)) | j;
      const int i0 = pad(base), i1 = pad(base+M), i2 = pad(base+2*M), i3 = pad(base+3*M);
      float2 a0=d[i0], a1=d[i1], a2=d[i2], a3=d[i3];
      float2 t0=f2add(a0,a2), t1=f2sub(a0,a2), t2=f2add(a1,a3), t3=f2sub(a1,a3);
      float2 y0=f2add(t0,t2), y2=f2sub(t0,t2);
      float2 y1=make_float2(t1.x - sgn*t3.y, t1.y + sgn*t3.x);
      float2 y3=make_float2(t1.x + sgn*t3.y, t1.y - sgn*t3.x);
      float s1,c1;
      __sincosf(ang * (float)(j << (12-mbits)), &s1, &c1);
      float c2=c1*c1-s1*s1, s2=2.f*c1*s1;
      float c3=c1*c2-s1*s2, s3=c1*s2+s1*c2;
      d[i0]=y0;
      d[i1]=cmul_cs(y1,c1,s1);
      d[i2]=cmul_cs(y2,c2,s2);
      d[i3]=cmul_cs(y3,c3,s3);
    }
    __syncthreads();
  }
}
__device__ void fold_store8(const float2* d, const float* __restrict__ phi, float* outp, int tid)
{
  const int k = tid >> 3, g = tid & 7;
  float acc = 0.f;
  for (int f = g; f < FOLD_F; f += 8) {
    float2 u = d[pad(f)];
    float w = phi[f] * ((f == 0) ? 1.f : 2.f);
    float sv, cv;
    __sincosf((TWO_PI/64.f) * (float)((f*k) & 63), &sv, &cv);
    acc += w * (u.x*cv - u.y*sv);
  }
  acc += __shfl_xor(acc, 1);
  acc += __shfl_xor(acc, 2);
  acc += __shfl_xor(acc, 4);
  if (g == 0) outp[k] = acc * INV_N;
}

// K1: xh = FFT(x) + S0 fold.
__global__ void __launch_bounds__(NT) k_fft_x(const float* __restrict__ x, const float* __restrict__ phi,
                                              float2* __restrict__ xh, float* __restrict__ out)
{
  extern __shared__ char smem[];
  float2* d = (float2*)smem;
  const int tid = threadIdx.x;
  const int b = blockIdx.x;
  const float* xr = x + b * T_N;
  for (int i = tid; i < T_N; i += NT) d[pad(i)] = make_float2(xr[i], 0.f);
  __syncthreads();
  dif_sweep(d, tid, -1.f, 12, 0);
  for (int p = tid; p < T_N; p += NT) {
    int r = rev4_14(p);
    if (p < r) { int ip = pad(p), ir = pad(r); float2 t = d[ip]; d[ip] = d[ir]; d[ir] = t; }
  }
  __syncthreads();
  float2* xrow = xh + (size_t)b * T_N;
  for (int i = tid; i < T_N; i += NT) xrow[i] = d[pad(i)];
  fold_store8(d, phi, out + b * 64, tid);
}

// Order-1 full-size body (j1 < 16).
__device__ __forceinline__ void o1_full_body(v2f* d, int tid, int b, int j1,
    const float2* __restrict__ xh, const float* __restrict__ psi1,
    const float* __restrict__ phi, float2* __restrict__ u1h, float* __restrict__ out)
{
  const float2* xrow = xh + (size_t)b * T_N;
  const float* prow = psi1 + j1 * T_N;
  const float c = 5734.4f * exp2f(-0.125f * (float)j1);
  const int lo = max(0, (int)(0.36f * c));
  const int hi = min(T_N, (int)(1.64f * c) + 2);
#pragma unroll
  for (int s = 0; s < T_N/NT2; ++s) {
    int i = tid + s*NT2;
    v2f z; z.x = 0.f; z.y = 0.f;
    if (i >= lo && i < hi) {
      float2 v = xrow[i];
      float p = prow[i];
      z.x = v.x*p; z.y = v.y*p;
    }
    d[pad(i)] = z;
  }
  __syncthreads();
  const int k_lo = lo >> 10, k_hi = (hi + 1023) >> 10;
  const int K1 = pow2ceil16(k_hi - k_lo);
  const int k0 = min(k_lo, 16 - K1);
  stage1_dispatch(d, tid, k0, K1, 0, NT2);
  stage2_dispatch(d, tid, 0, 16);
  super_dif16<+1, 4, 2>(d, tid);     __syncthreads();
  fused_mid4(d, tid);                __syncthreads();
  super_dit16<-1, 4, 2>(d, tid);     __syncthreads();
  super_dit16<-1, 64, 6>(d, tid);    __syncthreads();
  super_dit16<-1, 1024, 10>(d, tid); __syncthreads();
  const int sb = SBTAB[j1 >> 3];
  float2* urow = u1h + (size_t)(b * N1 + j1) * USTRIDE;
  for (int i = tid; i < sb; i += NT2) {
    v2f u = d[pad(i)];
    urow[i] = make_float2(u.x, u.y);
  }
  fold_store16(d, phi, out + 1024 + (size_t)(b * N1 + j1) * 64, tid);
}

// Decimated order-1 body: demodulated band [lo,hi) at slots [0,W).
template<int LOGN>
__device__ __forceinline__ void o1_dec_body(v2f* sm, int sub, int t, int j1, int b,
    const float2* __restrict__ xh, const float* __restrict__ psi1,
    const float* __restrict__ phi, float2* __restrict__ u1h, float* __restrict__ out)
{
  constexpr int N = 1<<LOGN, SEGT = N/16;
  const bool valid = (j1 < 64);
  const int jc = valid ? j1 : 63;
  v2f* ds = sm + sub*N + ((sub*N)>>4);
  int lo = 0, W = 0;
  if (valid) {
    const float c = 5734.4f * exp2f(-0.125f*(float)j1);
    lo = max(0, (int)(0.36f*c));
    const int hi = min(T_N, (int)(1.64f*c)+2);
    W = hi - lo;
  }
  const float2* xrow = xh + (size_t)b * T_N;
  const float* prow = psi1 + jc * T_N;
#pragma unroll
  for (int s = 0; s < 16; ++s) {
    int f = t + s*SEGT;
    v2f z; z.x = 0.f; z.y = 0.f;
    if (f < W) { float2 xv = xrow[lo+f]; float p = prow[lo+f]; z.x = xv.x*p; z.y = xv.y*p; }
    ds[f + (f>>4)] = z;
  }
  __syncthreads();
  o2_body<LOGN, 7, false>(ds, t);       // bins [0, 7*N/16) >= sb
  if (valid) {
    const int sb = SBTAB[j1>>3];
    const float R = (float)(T_N >> LOGN);
    float2* urow = u1h + (size_t)(b*N1 + j1) * USTRIDE;
    for (int i = t; i < sb; i += SEGT) {
      v2f u = ds[i + (i>>4)];
      urow[i] = make_float2(R*u.x, R*u.y);
    }
    fold_generic<SEGT/64>(ds, phi, out + 1024 + (size_t)(b*N1 + j1)*64, t, 1.f/(float)N);
  }
}

// K2 (merged order-1): blocks [0, 16*B) full pipelines (heavy, first);
// blocks [16*B, 25*B) decimated groups.
__global__ void __launch_bounds__(NT2, 4) k_o1(const float2* __restrict__ xh, const float* __restrict__ psi1,
                                               const float* __restrict__ phi, float2* __restrict__ u1h,
                                               float* __restrict__ out)
{
  extern __shared__ char smem[];
  v2f* sm = (v2f*)smem;
  if (blockIdx.x < B_SZ*16) {
    o1_full_body(sm, threadIdx.x, blockIdx.x >> 4, blockIdx.x & 15, xh, psi1, phi, u1h, out);
    return;
  }
  const int ix = blockIdx.x - B_SZ*16;
  const int grp = ix % 9, b = ix / 9;
  if (grp < 4) {
    o1_dec_body<13>(sm, threadIdx.x >> 9, threadIdx.x & 511, 16 + grp*2 + (threadIdx.x >> 9),
                    b, xh, psi1, phi, u1h, out);
  } else if (grp < 6) {
    o1_dec_body<12>(sm, threadIdx.x >> 8, threadIdx.x & 255, 24 + (grp-4)*4 + (threadIdx.x >> 8),
                    b, xh, psi1, phi, u1h, out);
  } else if (grp == 6) {
    o1_dec_body<11>(sm, threadIdx.x >> 7, threadIdx.x & 127, 32 + (threadIdx.x >> 7),
                    b, xh, psi1, phi, u1h, out);
  } else {
    o1_dec_body<10>(sm, threadIdx.x >> 6, threadIdx.x & 63, 40 + (grp-7)*16 + (threadIdx.x >> 6),
                    b, xh, psi1, phi, u1h, out);
  }
}

// Order-2 full-size body (j2 in {1,2}).
__device__ __forceinline__ void o2_16k_body(v2f* d, int tid, int b, int cls_p,
    const float2* __restrict__ u1h, const float* __restrict__ psi2,
    const float* __restrict__ phi, float* __restrict__ out)
{
  const int j2 = (cls_p < 8) ? 1 : 2;
  const int j1 = cls_p - ((cls_p < 8) ? 0 : 8);
  const int W = WTAB[j2];
  const float2* urow = u1h + (size_t)(b * N1 + j1) * USTRIDE;
  const float* prow = psi2 + j2 * T_N;
#pragma unroll
  for (int s = 0; s < T_N/NT2; ++s) {
    int i = tid + s*NT2;
    v2f z; z.x = 0.f; z.y = 0.f;
    if (i < W) {
      float2 u;
      if (i <= T_N/2) u = urow[i];
      else { float2 t = urow[T_N - i]; u = make_float2(t.x, -t.y); }
      float ps = prow[i];
      z.x = u.x*ps; z.y = u.y*ps;
    }
    d[pad(i)] = z;
  }
  __syncthreads();
  const int K1 = pow2ceil16((W + 1023) >> 10);
  stage1_dispatch(d, tid, 0, K1, 0, W);
  stage2_dispatch(d, tid, 0, 16);
  super_dif16<+1, 4, 2>(d, tid);      __syncthreads();
  fused_mid4(d, tid);                 __syncthreads();
  super_dit16<-1, 4, 2>(d, tid);      __syncthreads();
  super_dit16_m64_prune<-1>(d, tid);  __syncthreads();
  super_dit16_m1024_bin256<-1>(d, tid); __syncthreads();
  const int p = pair_index(j1, j2);
  fold_store16(d, phi, out + 66560 + (size_t)(b * NPAIR + p) * 64, tid);
}

// Decimated order-2 body (S2 fold only).
template<int LOGN>
__device__ __forceinline__ void o2_cls_body(v2f* sm, int sub, int t, int b, int j1, int j2, bool valid,
    const float2* __restrict__ u1h, const float* __restrict__ psi2,
    const float* __restrict__ phi, float* __restrict__ out)
{
  constexpr int N = 1<<LOGN, SEGT = N/16;
  v2f* ds = sm + sub*N + ((sub*N)>>4);
  const int W = valid ? WTAB[j2 & 7] : 0;
  const float2* urow = u1h + (size_t)(b * N1 + j1) * USTRIDE;
  const float* prow = psi2 + j2 * T_N;
#pragma unroll
  for (int s = 0; s < 16; ++s) {
    int f = t + s*SEGT;
    v2f z; z.x = 0.f; z.y = 0.f;
    if (f < W) { float2 u = urow[f]; float ps = prow[f]; z.x = u.x*ps; z.y = u.y*ps; }
    ds[f + (f>>4)] = z;
  }
  __syncthreads();
  constexpr int RM = ((1<<(LOGN-4)) >= 256) ? 1 : (256 >> (LOGN-4));
  constexpr bool JL = ((1<<(LOGN-4)) > 256);
  o2_body<LOGN, RM, JL>(ds, t);
  if (valid) {
    const int p = pair_index(j1, j2);
    fold_generic<SEGT/64>(ds, phi, out + 66560 + (size_t)(b * NPAIR + p) * 64, t, 1.f/(float)N);
  }
}

// K3 (merged order-2): blocks [0, 24*B) full 16k pipelines (heavy, first);
// blocks [24*B, 56*B) decimated groups (32 per batch).
__global__ void __launch_bounds__(NT2, 4) k_o2(const float2* __restrict__ u1h, const float* __restrict__ psi2,
                                               const float* __restrict__ phi, float* __restrict__ out)
{
  extern __shared__ char smem[];
  v2f* sm = (v2f*)smem;
  if (blockIdx.x < B_SZ*24) {
    o2_16k_body(sm, threadIdx.x, blockIdx.x / 24, blockIdx.x % 24, u1h, psi2, phi, out);
    return;
  }
  const int ix = blockIdx.x - B_SZ*24;
  const int grp = ix & 31, b = ix >> 5;
  if (grp < 12) {
    const int sub = threadIdx.x >> 9, t = threadIdx.x & 511;
    o2_cls_body<13>(sm, sub, t, b, grp*2 + sub, 3, true, u1h, psi2, phi, out);
  } else if (grp < 20) {
    const int sub = threadIdx.x >> 8, t = threadIdx.x & 255;
    o2_cls_body<12>(sm, sub, t, b, (grp-12)*4 + sub, 4, true, u1h, psi2, phi, out);
  } else if (grp < 25) {
    const int sub = threadIdx.x >> 7, t = threadIdx.x & 127;
    o2_cls_body<11>(sm, sub, t, b, (grp-20)*8 + sub, 5, true, u1h, psi2, phi, out);
  } else {
    const int sub = threadIdx.x >> 6, t = threadIdx.x & 63;
    const int cls_p = (grp-25)*16 + sub;
    const bool valid = (cls_p < 104);
    const int j2 = (cls_p < 48) ? 6 : 7;
    const int j1 = cls_p - ((cls_p < 48) ? 0 : 48);
    o2_cls_body<10>(sm, sub, t, b, j1, j2, valid, u1h, psi2, phi, out);
  }
}

extern "C" void kernel_launch(void* const* d_in, const int* in_sizes, int n_in,
                              void* d_out, int out_size, void* d_ws, size_t ws_size,
                              hipStream_t stream)
{
  const float* x    = (const float*)d_in[0];
  const float* psi1 = (const float*)d_in[1];
  const float* psi2 = (const float*)d_in[2];
  const float* phi  = (const float*)d_in[3];
  float* out = (float*)d_out;

  float2* xh  = (float2*)d_ws;
  float2* u1h = xh + (size_t)B_SZ * T_N;

  const size_t lds = (size_t)(T_N + (T_N >> 4)) * sizeof(float2);  // 139264 B

  (void)hipFuncSetAttribute((const void*)k_fft_x, hipFuncAttributeMaxDynamicSharedMemorySize, (int)lds);
  (void)hipFuncSetAttribute((const void*)k_o1,    hipFuncAttributeMaxDynamicSharedMemorySize, (int)lds);
  (void)hipFuncSetAttribute((const void*)k_o2,    hipFuncAttributeMaxDynamicSharedMemorySize, (int)lds);

  hipLaunchKernelGGL(k_fft_x, dim3(B_SZ),                dim3(NT),  lds, stream, x, phi, xh, out);
  hipLaunchKernelGGL(k_o1,    dim3(B_SZ*16 + B_SZ*9),    dim3(NT2), lds, stream, xh, psi1, phi, u1h, out);
  hipLaunchKernelGGL(k_o2,    dim3(B_SZ*24 + B_SZ*32),   dim3(NT2), lds, stream, u1h, psi2, phi, out);
}

// Round 11
// 243.123 us; speedup vs baseline: 3.5879x; 1.0437x over previous
//
#include <hip/hip_runtime.h>
#include <math.h>

// Wavelet scattering, T=16384.  Radix-16 register-blocked in-LDS FFTs with
// per-octave decimated pipelines.  R11: decimation factors tightened to the
// true aliasing criterion (envelope spectrum width = sqrt(2)*sigma_filter,
// need N'-binmax >= ~5 sigma_env and N' >= band width for the exact inverse):
// every decimated class drops one octave vs R10; o1 q=1 and o2 j2=2 leave
// the 16k path.  final_prune RMAX=13 for o1 (13*M1 >= sb per class).

#define T_N   16384
#define NT    512
#define NT2   1024
#define B_SZ  16
#define N1    64
#define NPAIR 224
#define FOLD_F 256
#define USTRIDE 8208
#define INV_N (1.0f/16384.0f)
#define TWO_PI 6.283185307179586f

typedef float v2f __attribute__((ext_vector_type(2)));

__device__ __forceinline__ int pad(int i) { return i + (i >> 4); }

__device__ __forceinline__ v2f cmulw(v2f a, v2f w){
  v2f n; n.x = -a.y; n.y = a.x;
  return w.x * a + w.y * n;
}
__device__ __forceinline__ constexpr int br4(int x){
  return ((x&1)<<3)|((x&2)<<1)|((x&4)>>1)|((x&8)>>3);
}
template<int LB>
__device__ __forceinline__ constexpr int brN(int x){
  int r=0;
  for(int i=0;i<LB;++i){ r=(r<<1)|((x>>i)&1); }
  return r;
}
__device__ __forceinline__ int rev4_14(int p){
  unsigned r = __brev((unsigned)p) >> 18;
  return (int)(((r & 0x2AAAu) >> 1) | ((r & 0x1555u) << 1));
}
__device__ __forceinline__ int pow2ceil16(int k){
  return (k<=1)?1:(k<=2)?2:(k<=4)?4:(k<=8)?8:16;
}

// tw[r] = w^r via depth-4 product tree.
__device__ __forceinline__ void twiddle_tree(v2f w, v2f* tw){
  tw[0].x = 1.f; tw[0].y = 0.f;
  tw[1] = w;
  tw[2] = cmulw(w, w);
  tw[4] = cmulw(tw[2], tw[2]);
  tw[8] = cmulw(tw[4], tw[4]);
  tw[3] = cmulw(tw[2], w);
  tw[5] = cmulw(tw[4], w);
  tw[6] = cmulw(tw[4], tw[2]);
  tw[7] = cmulw(tw[4], tw[3]);
  tw[9]  = cmulw(tw[8], w);
  tw[10] = cmulw(tw[8], tw[2]);
  tw[11] = cmulw(tw[8], tw[3]);
  tw[12] = cmulw(tw[8], tw[4]);
  tw[13] = cmulw(tw[8], tw[5]);
  tw[14] = cmulw(tw[8], tw[6]);
  tw[15] = cmulw(tw[8], tw[7]);
}

// Generic fully-unrolled DFT of size 2^LOGNN (<=16); y[r] lands at a[brN(r)].
template<int SGN, int LOGNN>
__device__ __forceinline__ void dft_reg(v2f* a){
  constexpr int NN = 1<<LOGNN;
  static constexpr float C16[16] = {
    1.f, 0.98078528f, 0.92387953f, 0.83146961f, 0.70710678f, 0.55557023f,
    0.38268343f, 0.19509032f, 0.f, -0.19509032f, -0.38268343f, -0.55557023f,
    -0.70710678f, -0.83146961f, -0.92387953f, -0.98078528f };
  static constexpr float S16[16] = {
    0.f, 0.19509032f, 0.38268343f, 0.55557023f, 0.70710678f, 0.83146961f,
    0.92387953f, 0.98078528f, 1.f, 0.98078528f, 0.92387953f, 0.83146961f,
    0.70710678f, 0.55557023f, 0.38268343f, 0.19509032f };
#pragma unroll
  for (int m = NN/2; m >= 1; m >>= 1) {
#pragma unroll
    for (int base = 0; base < NN; base += 2*m) {
#pragma unroll
      for (int j = 0; j < m; ++j) {
        v2f u = a[base+j], v = a[base+j+m];
        a[base+j] = u + v;
        v2f w = u - v;
        const int ti = (j*16)/m;
        v2f tw; tw.x = C16[ti]; tw.y = (float)SGN * S16[ti];
        a[base+j+m] = cmulw(w, tw);
      }
    }
  }
}
template<int SGN>
__device__ __forceinline__ void dft16(v2f* a){ dft_reg<SGN,4>(a); }

// Full DIF super-stage radix-16 at stride M.
template<int SGN, int M, int LOGM>
__device__ __forceinline__ void super_dif16(v2f* d, int g)
{
  const int j = g & (M-1);
  const int base = ((g >> LOGM) << (LOGM+4)) | j;
  v2f* dp = d + pad(base);
  v2f a[16];
#pragma unroll
  for (int k = 0; k < 16; ++k) a[k] = dp[k*M + ((k*M)>>4)];
  dft16<SGN>(a);
  float sj, cj;
  __sincosf((float)SGN * (TWO_PI / (16.f*(float)M)) * (float)j, &sj, &cj);
  v2f w; w.x = cj; w.y = sj;
  v2f tw[16];
  twiddle_tree(w, tw);
  dp[0] = a[0];
#pragma unroll
  for (int r = 1; r < 16; ++r)
    dp[r*M + ((r*M)>>4)] = cmulw(a[br4(r)], tw[r]);
}

// SPARSE DIF super-stage: only taps [k0,k0+K) possibly nonzero (rest zeros).
template<int SGN, int M, int LOGM, int K>
__device__ __forceinline__ void super_dif16_sparse(v2f* d, int g, int k0)
{
  static constexpr float CW[16] = { 1.f, 0.92387953f, 0.70710678f, 0.38268343f,
    0.f, -0.38268343f, -0.70710678f, -0.92387953f, -1.f, -0.92387953f,
    -0.70710678f, -0.38268343f, 0.f, 0.38268343f, 0.70710678f, 0.92387953f };
  static constexpr float SW[16] = { 0.f, 0.38268343f, 0.70710678f, 0.92387953f,
    1.f, 0.92387953f, 0.70710678f, 0.38268343f, 0.f, -0.38268343f,
    -0.70710678f, -0.92387953f, -1.f, -0.92387953f, -0.70710678f, -0.38268343f };
  const int j = g & (M-1);
  const int base = ((g >> LOGM) << (LOGM+4)) | j;
  v2f* dp = d + pad(base);
  v2f a[K];
#pragma unroll
  for (int m = 0; m < K; ++m) {
    const int k = k0 + m;
    a[m] = dp[k*M + ((k*M)>>4)];
  }
  v2f y[16];
  if constexpr (K == 1) {
#pragma unroll
    for (int r = 0; r < 16; ++r) y[r] = a[0];
  } else if constexpr (K == 2) {
#pragma unroll
    for (int r0 = 0; r0 < 8; ++r0) {
      v2f w; w.x = CW[r0]; w.y = (float)SGN * SW[r0];
      v2f b1 = cmulw(a[1], w);
      y[r0]   = a[0] + b1;
      y[r0+8] = a[0] - b1;
    }
  } else if constexpr (K == 4) {
#pragma unroll
    for (int r0 = 0; r0 < 4; ++r0) {
      v2f z1, z2, z3;
      { v2f w; w.x = CW[r0];        w.y = (float)SGN*SW[r0];        z1 = cmulw(a[1], w); }
      { v2f w; w.x = CW[(2*r0)&15]; w.y = (float)SGN*SW[(2*r0)&15]; z2 = cmulw(a[2], w); }
      { v2f w; w.x = CW[(3*r0)&15]; w.y = (float)SGN*SW[(3*r0)&15]; z3 = cmulw(a[3], w); }
      v2f e0 = a[0]+z2, e1 = a[0]-z2, o0 = z1+z3, o1 = z1-z3;
      v2f io; io.x = -(float)SGN*o1.y; io.y = (float)SGN*o1.x;
      y[r0]    = e0 + o0;
      y[r0+4]  = e1 + io;
      y[r0+8]  = e0 - o0;
      y[r0+12] = e1 - io;
    }
  } else { // K == 8
#pragma unroll
    for (int r0 = 0; r0 < 2; ++r0) {
      v2f z[8];
      z[0] = a[0];
#pragma unroll
      for (int m = 1; m < 8; ++m) {
        v2f w; w.x = CW[(m*r0)&15]; w.y = (float)SGN*SW[(m*r0)&15];
        z[m] = cmulw(a[m], w);
      }
      v2f E[4], O[4];
      {
        v2f e0=z[0]+z[4], e1=z[0]-z[4], o0=z[2]+z[6], o1=z[2]-z[6];
        v2f io; io.x=-(float)SGN*o1.y; io.y=(float)SGN*o1.x;
        E[0]=e0+o0; E[1]=e1+io; E[2]=e0-o0; E[3]=e1-io;
      }
      {
        v2f e0=z[1]+z[5], e1=z[1]-z[5], o0=z[3]+z[7], o1=z[3]-z[7];
        v2f io; io.x=-(float)SGN*o1.y; io.y=(float)SGN*o1.x;
        O[0]=e0+o0; O[1]=e1+io; O[2]=e0-o0; O[3]=e1-io;
      }
      constexpr float RT = 0.70710678f;
#pragma unroll
      for (int r1 = 0; r1 < 4; ++r1) {
        v2f w8;
        if (r1 == 0)      { w8.x = 1.f;  w8.y = 0.f; }
        else if (r1 == 1) { w8.x = RT;   w8.y = (float)SGN*RT; }
        else if (r1 == 2) { w8.x = 0.f;  w8.y = (float)SGN; }
        else              { w8.x = -RT;  w8.y = (float)SGN*RT; }
        v2f t = cmulw(O[r1], w8);
        y[2*r1 + r0]     = E[r1] + t;
        y[2*r1 + r0 + 8] = E[r1] - t;
      }
    }
  }
  float sj, cj;
  __sincosf((float)SGN * (TWO_PI / (16.f*(float)M)) * (float)(j + k0*M), &sj, &cj);
  v2f w; w.x = cj; w.y = sj;
  v2f tw[16];
  twiddle_tree(w, tw);
  dp[0] = y[0];
#pragma unroll
  for (int r = 1; r < 16; ++r)
    dp[r*M + ((r*M)>>4)] = cmulw(y[r], tw[r]);
}

// Runtime dispatch (16k pipelines), barriers included.
__device__ __forceinline__ void stage1_dispatch(v2f* d, int tid, int k0, int K1, int jlo, int jhi)
{
  if (K1 == 16)     super_dif16<+1, 1024, 10>(d, tid);
  else if (K1 == 8) super_dif16_sparse<+1,1024,10,8>(d, tid, k0);
  else if (K1 == 4) super_dif16_sparse<+1,1024,10,4>(d, tid, k0);
  else if (K1 == 2) super_dif16_sparse<+1,1024,10,2>(d, tid, k0);
  else { if (tid >= jlo && tid < jhi) super_dif16_sparse<+1,1024,10,1>(d, tid, k0); }
  __syncthreads();
}
__device__ __forceinline__ void stage2_dispatch(v2f* d, int tid, int k0, int K2)
{
  if (K2 == 16)     super_dif16<+1, 64, 6>(d, tid);
  else if (K2 == 8) super_dif16_sparse<+1,64,6,8>(d, tid, k0);
  else if (K2 == 4) super_dif16_sparse<+1,64,6,4>(d, tid, k0);
  else if (K2 == 2) super_dif16_sparse<+1,64,6,2>(d, tid, k0);
  else              super_dif16_sparse<+1,64,6,1>(d, tid, k0);
  __syncthreads();
}

// Full DIT super-stage radix-16 at stride M.
template<int SGN, int M, int LOGM>
__device__ __forceinline__ void super_dit16(v2f* d, int g)
{
  const int j = g & (M-1);
  const int base = ((g >> LOGM) << (LOGM+4)) | j;
  v2f* dp = d + pad(base);
  float sj, cj;
  __sincosf((float)SGN * (TWO_PI / (16.f*(float)M)) * (float)j, &sj, &cj);
  v2f w; w.x = cj; w.y = sj;
  v2f tw[16];
  twiddle_tree(w, tw);
  v2f a[16];
  a[0] = dp[0];
#pragma unroll
  for (int k = 1; k < 16; ++k)
    a[k] = cmulw(dp[k*M + ((k*M)>>4)], tw[k]);
  dft16<SGN>(a);
#pragma unroll
  for (int r = 0; r < 16; ++r) dp[r*M + ((r*M)>>4)] = a[br4(r)];
}

// PRUNED DIT16 at M=64 (r<4) — 16k pipeline.
template<int SGN>
__device__ __forceinline__ void super_dit16_m64_prune(v2f* d, int g)
{
  constexpr int M = 64;
  constexpr int PSTR = M + (M>>4);
  const int j = g & 63;
  const int base = ((g >> 6) << 10) | j;
  v2f* dp = d + pad(base);
  float sj, cj;
  __sincosf((float)SGN * (TWO_PI / 1024.f) * (float)j, &sj, &cj);
  v2f w; w.x = cj; w.y = sj;
  v2f tw[16];
  twiddle_tree(w, tw);
  v2f a[16];
  a[0] = dp[0];
#pragma unroll
  for (int k = 1; k < 16; ++k)
    a[k] = cmulw(dp[k*M + ((k*M)>>4)], tw[k]);
  v2f Y[4][4];
#pragma unroll
  for (int c = 0; c < 4; ++c) {
    v2f s0=a[c], s1=a[c+4], s2=a[c+8], s3=a[c+12];
    v2f e0 = s0+s2, e1 = s0-s2, o0 = s1+s3, o1 = s1-s3;
    v2f io1; io1.x = -(float)SGN * o1.y; io1.y = (float)SGN * o1.x;
    Y[c][0] = e0 + o0;
    Y[c][1] = e1 + io1;
    Y[c][2] = e0 - o0;
    Y[c][3] = e1 - io1;
  }
  static constexpr float WC[10] = {1.f,0.92387953f,0.70710678f,0.38268343f,0.f,
                                   -0.38268343f,-0.70710678f,-0.92387953f,-1.f,-0.92387953f};
  static constexpr float WS[10] = {0.f,0.38268343f,0.70710678f,0.92387953f,1.f,
                                   0.92387953f,0.70710678f,0.38268343f,0.f,-0.38268343f};
#pragma unroll
  for (int r = 0; r < 4; ++r) {
    v2f acc = Y[0][r];
#pragma unroll
    for (int c = 1; c < 4; ++c) {
      v2f wc; wc.x = WC[r*c]; wc.y = (float)SGN * WS[r*c];
      acc += cmulw(Y[c][r], wc);
    }
    dp[r*PSTR] = acc;
  }
}

// PRUNED final DIT16 at M=1024: bins j<256 — 16k pipeline.
template<int SGN>
__device__ __forceinline__ void super_dit16_m1024_bin256(v2f* d, int tid)
{
  if (tid < 256) {
    const int j = tid;
    v2f* dp = d + pad(j);
    float sj, cj;
    __sincosf((float)SGN * (TWO_PI / 16384.f) * (float)j, &sj, &cj);
    v2f w; w.x = cj; w.y = sj;
    v2f tw[16];
    twiddle_tree(w, tw);
    v2f acc = dp[0];
#pragma unroll
    for (int k = 1; k < 16; ++k)
      acc += cmulw(dp[k*1024 + ((k*1024)>>4)], tw[k]);
    dp[0] = acc;
  }
}

// Generic output-pruned final DIT16 at M1 = 2^LOGM1: outputs r < RMAX.
// Streams each output (reads b[16] first; column j is owned by thread j).
template<int SGN, int LOGM1, int RMAX, bool JLIM>
__device__ __forceinline__ void final_prune(v2f* ds, int t)
{
  static constexpr float CW[16] = { 1.f, 0.92387953f, 0.70710678f, 0.38268343f,
    0.f, -0.38268343f, -0.70710678f, -0.92387953f, -1.f, -0.92387953f,
    -0.70710678f, -0.38268343f, 0.f, 0.38268343f, 0.70710678f, 0.92387953f };
  static constexpr float SW[16] = { 0.f, 0.38268343f, 0.70710678f, 0.92387953f,
    1.f, 0.92387953f, 0.70710678f, 0.38268343f, 0.f, -0.38268343f,
    -0.70710678f, -0.92387953f, -1.f, -0.92387953f, -0.70710678f, -0.38268343f };
  constexpr int M1 = 1<<LOGM1;
  const int j = t;
  if (JLIM && j >= 256) return;
  v2f* dp = ds + j + (j>>4);
  float sj, cj;
  __sincosf((float)SGN * (TWO_PI / (16.f*(float)M1)) * (float)j, &sj, &cj);
  v2f w; w.x = cj; w.y = sj;
  v2f tw[16];
  twiddle_tree(w, tw);
  v2f b[16];
  b[0] = dp[0];
#pragma unroll
  for (int k = 1; k < 16; ++k)
    b[k] = cmulw(dp[k*M1 + ((k*M1)>>4)], tw[k]);
#pragma unroll
  for (int r = 0; r < RMAX; ++r) {
    v2f acc = b[0];
#pragma unroll
    for (int k = 1; k < 16; ++k) {
      v2f wc; wc.x = CW[(r*k)&15]; wc.y = (float)SGN*SW[(r*k)&15];
      acc += cmulw(b[k], wc);
    }
    dp[r*M1 + ((r*M1)>>4)] = acc;
  }
}

// DIF chain descending (barrier after each stage).
template<int SGN, int LOGM>
__device__ __forceinline__ void dif_chain(v2f* ds, int t){
  super_dif16<SGN, (1<<LOGM), LOGM>(ds, t);
  __syncthreads();
  if constexpr (LOGM > 4) dif_chain<SGN, LOGM-4>(ds, t);
}
// DIT chain ascending up to (excluding) LOGTOP.
template<int SGN, int LOGM, int LOGTOP>
__device__ __forceinline__ void dit_chain(v2f* ds, int t){
  super_dit16<SGN, (1<<LOGM), LOGM>(ds, t);
  __syncthreads();
  if constexpr (LOGM + 4 < LOGTOP) dit_chain<SGN, LOGM+4, LOGTOP>(ds, t);
}

// Generic mid: per contiguous-16 (thread t): inverse DFT_MM -> |.|/T -> fwd DFT_MM.
template<int LOGMM>
__device__ __forceinline__ void mid_generic(v2f* ds, int t)
{
  constexpr int MM = 1<<LOGMM;
  v2f* dp = ds + 17*t;
#pragma unroll
  for (int q = 0; q < 16/MM; ++q) {
    v2f a[MM];
#pragma unroll
    for (int i = 0; i < MM; ++i) a[i] = dp[q*MM+i];
    dft_reg<+1,LOGMM>(a);
    v2f m[MM];
#pragma unroll
    for (int r = 0; r < MM; ++r) {
      v2f y = a[brN<LOGMM>(r)];
      m[r].x = INV_N * sqrtf(y.x*y.x + y.y*y.y);
      m[r].y = 0.f;
    }
    dft_reg<-1,LOGMM>(m);
#pragma unroll
    for (int k = 0; k < MM; ++k) dp[q*MM+k] = m[brN<LOGMM>(k)];
  }
}

// mid4 specialization used by 16k pipelines.
__device__ __forceinline__ void fused_mid4(v2f* d, int t)
{
  v2f* dp = d + 17*t;
#pragma unroll
  for (int q = 0; q < 4; ++q) {
    v2f a0=dp[4*q], a1=dp[4*q+1], a2=dp[4*q+2], a3=dp[4*q+3];
    v2f t0=a0+a2, t1=a0-a2, t2=a1+a3, t3=a1-a3;
    v2f it3; it3.x = -t3.y; it3.y = t3.x;
    v2f y0=t0+t2, y2=t0-t2, y1=t1+it3, y3=t1-it3;
    float m0 = INV_N * sqrtf(y0.x*y0.x + y0.y*y0.y);
    float m1 = INV_N * sqrtf(y1.x*y1.x + y1.y*y1.y);
    float m2 = INV_N * sqrtf(y2.x*y2.x + y2.y*y2.y);
    float m3 = INV_N * sqrtf(y3.x*y3.x + y3.y*y3.y);
    float p0=m0+m2, p1=m0-m2, p2=m1+m3, p3=m1-m3;
    v2f o0; o0.x = p0+p2; o0.y = 0.f;
    v2f o1; o1.x = p1;    o1.y = -p3;
    v2f o2; o2.x = p0-p2; o2.y = 0.f;
    v2f o3; o3.x = p1;    o3.y = p3;
    dp[4*q]=o0; dp[4*q+1]=o1; dp[4*q+2]=o2; dp[4*q+3]=o3;
  }
}

// Generic decimated pipeline body for LOGN in {10,11,12,13}.
template<int LOGN, int RMAX, bool JL>
__device__ __forceinline__ void o2_body(v2f* ds, int t)
{
  constexpr int LOGM1 = LOGN-4;
  super_dif16_sparse<+1, (1<<LOGM1), LOGM1, 8>(ds, t, 0);
  __syncthreads();
  dif_chain<+1, LOGM1-4>(ds, t);
  constexpr int LOGMM = ((LOGM1-5)%4)+1;
  mid_generic<LOGMM>(ds, t);
  __syncthreads();
  dit_chain<-1, LOGMM, LOGM1>(ds, t);
  final_prune<-1, LOGM1, RMAX, JL>(ds, t);
  __syncthreads();
}

// Generic fold: SEGT = 64*PERK threads, scale applied at write.
template<int PERK>
__device__ __forceinline__ void fold_generic(const v2f* ds, const float* __restrict__ phi,
                                             float* outp, int t, float scale)
{
  const int k = t / PERK, g = t % PERK;
  float sv, cv, ss, cs;
  __sincosf((TWO_PI/64.f) * (float)((g*k) & 63), &sv, &cv);
  __sincosf((TWO_PI/64.f) * (float)((PERK*k) & 63), &ss, &cs);
  float acc = 0.f;
#pragma unroll
  for (int m = 0; m < 256/PERK; ++m) {
    const int f = g + PERK*m;
    v2f u = ds[f + (f>>4)];
    float wgt = phi[f] * ((f == 0) ? 1.f : 2.f);
    acc += wgt * (u.x*cv - u.y*sv);
    float nc = cv*cs - sv*ss, ns = cv*ss + sv*cs;
    cv = nc; sv = ns;
  }
#pragma unroll
  for (int o = 1; o < PERK; o <<= 1) acc += __shfl_xor(acc, o);
  if (g == 0) outp[k] = acc * scale;
}

// phi-fold for full-size (1024-thread) pipelines.
__device__ void fold_store16(const v2f* d, const float* __restrict__ phi, float* outp, int tid)
{
  const int k = tid >> 4, g = tid & 15;
  float sv, cv;
  __sincosf((TWO_PI/64.f) * (float)((g*k) & 63), &sv, &cv);
  const int km = k & 3;
  const float strRe = (km==0) ? 1.f : (km==2 ? -1.f : 0.f);
  const float strIm = (km==1) ? 1.f : (km==3 ? -1.f : 0.f);
  float acc = 0.f;
#pragma unroll
  for (int m = 0; m < 16; ++m) {
    const int f = g + 16*m;
    v2f u = d[pad(f)];
    float wgt = phi[f] * ((f == 0) ? 1.f : 2.f);
    acc += wgt * (u.x*cv - u.y*sv);
    float nc = cv*strRe - sv*strIm;
    float ns = cv*strIm + sv*strRe;
    cv = nc; sv = ns;
  }
  acc += __shfl_xor(acc, 1);
  acc += __shfl_xor(acc, 2);
  acc += __shfl_xor(acc, 4);
  acc += __shfl_xor(acc, 8);
  if (g == 0) outp[k] = acc * INV_N;
}

// Reference pair index (j1-major, valid j2 > j1/8).
__device__ __forceinline__ int pair_index(int j1, int j2)
{
  const int q = j1 >> 3;
  return 8*(7*q - (q*(q-1))/2) + (j1 & 7)*(7 - q) + (j2 - q - 1);
}

// psi2 band widths W(j2) = ceil(4.5 * 5734.4 * 2^-j2)
__device__ __constant__ int WTAB[8]  = {16384, 12903, 6452, 3226, 1613, 807, 404, 202};
// U1h store bound per j1-octave q: W(q+1) capped at 8193
__device__ __constant__ int SBTAB[8] = {8193, 6452, 3226, 1613, 807, 404, 202, 0};

// ---- radix-4 float2 path for k_fft_x ----
__device__ __forceinline__ float2 f2add(float2 a, float2 b){ return make_float2(a.x+b.x, a.y+b.y); }
__device__ __forceinline__ float2 f2sub(float2 a, float2 b){ return make_float2(a.x-b.x, a.y-b.y); }
__device__ __forceinline__ float2 cmul_cs(float2 a, float c, float s){
  return make_float2(a.x*c - a.y*s, a.x*s + a.y*c);
}
__device__ void dif_sweep(float2* d, int tid, float sgn, int mb_hi, int mb_lo)
{
  const float ang = sgn * (TWO_PI / (float)T_N);
  for (int mbits = mb_hi; mbits >= mb_lo; mbits -= 2) {
    const int M = 1 << mbits;
#pragma unroll 8
    for (int v = tid; v < T_N/4; v += NT) {
      const int j = v & (M-1);
      const int base = ((v >> mbits) << (mbits+2)) | j;
      const int i0 = pad(base), i1 = pad(base+M), i2 = pad(base+2*M), i3 = pad(base+3*M);
      float2 a0=d[i0], a1=d[i1], a2=d[i2], a3=d[i3];
      float2 t0=f2add(a0,a2), t1=f2sub(a0,a2), t2=f2add(a1,a3), t3=f2sub(a1,a3);
      float2 y0=f2add(t0,t2), y2=f2sub(t0,t2);
      float2 y1=make_float2(t1.x - sgn*t3.y, t1.y + sgn*t3.x);
      float2 y3=make_float2(t1.x + sgn*t3.y, t1.y - sgn*t3.x);
      float s1,c1;
      __sincosf(ang * (float)(j << (12-mbits)), &s1, &c1);
      float c2=c1*c1-s1*s1, s2=2.f*c1*s1;
      float c3=c1*c2-s1*s2, s3=c1*s2+s1*c2;
      d[i0]=y0;
      d[i1]=cmul_cs(y1,c1,s1);
      d[i2]=cmul_cs(y2,c2,s2);
      d[i3]=cmul_cs(y3,c3,s3);
    }
    __syncthreads();
  }
}
__device__ void fold_store8(const float2* d, const float* __restrict__ phi, float* outp, int tid)
{
  const int k = tid >> 3, g = tid & 7;
  float acc = 0.f;
  for (int f = g; f < FOLD_F; f += 8) {
    float2 u = d[pad(f)];
    float w = phi[f] * ((f == 0) ? 1.f : 2.f);
    float sv, cv;
    __sincosf((TWO_PI/64.f) * (float)((f*k) & 63), &sv, &cv);
    acc += w * (u.x*cv - u.y*sv);
  }
  acc += __shfl_xor(acc, 1);
  acc += __shfl_xor(acc, 2);
  acc += __shfl_xor(acc, 4);
  if (g == 0) outp[k] = acc * INV_N;
}

// K1: xh = FFT(x) + S0 fold.
__global__ void __launch_bounds__(NT) k_fft_x(const float* __restrict__ x, const float* __restrict__ phi,
                                              float2* __restrict__ xh, float* __restrict__ out)
{
  extern __shared__ char smem[];
  float2* d = (float2*)smem;
  const int tid = threadIdx.x;
  const int b = blockIdx.x;
  const float* xr = x + b * T_N;
  for (int i = tid; i < T_N; i += NT) d[pad(i)] = make_float2(xr[i], 0.f);
  __syncthreads();
  dif_sweep(d, tid, -1.f, 12, 0);
  for (int p = tid; p < T_N; p += NT) {
    int r = rev4_14(p);
    if (p < r) { int ip = pad(p), ir = pad(r); float2 t = d[ip]; d[ip] = d[ir]; d[ir] = t; }
  }
  __syncthreads();
  float2* xrow = xh + (size_t)b * T_N;
  for (int i = tid; i < T_N; i += NT) xrow[i] = d[pad(i)];
  fold_store8(d, phi, out + b * 64, tid);
}

// Order-1 full-size body (j1 < 8).
__device__ __forceinline__ void o1_full_body(v2f* d, int tid, int b, int j1,
    const float2* __restrict__ xh, const float* __restrict__ psi1,
    const float* __restrict__ phi, float2* __restrict__ u1h, float* __restrict__ out)
{
  const float2* xrow = xh + (size_t)b * T_N;
  const float* prow = psi1 + j1 * T_N;
  const float c = 5734.4f * exp2f(-0.125f * (float)j1);
  const int lo = max(0, (int)(0.36f * c));
  const int hi = min(T_N, (int)(1.64f * c) + 2);
#pragma unroll
  for (int s = 0; s < T_N/NT2; ++s) {
    int i = tid + s*NT2;
    v2f z; z.x = 0.f; z.y = 0.f;
    if (i >= lo && i < hi) {
      float2 v = xrow[i];
      float p = prow[i];
      z.x = v.x*p; z.y = v.y*p;
    }
    d[pad(i)] = z;
  }
  __syncthreads();
  const int k_lo = lo >> 10, k_hi = (hi + 1023) >> 10;
  const int K1 = pow2ceil16(k_hi - k_lo);
  const int k0 = min(k_lo, 16 - K1);
  stage1_dispatch(d, tid, k0, K1, 0, NT2);
  stage2_dispatch(d, tid, 0, 16);
  super_dif16<+1, 4, 2>(d, tid);     __syncthreads();
  fused_mid4(d, tid);                __syncthreads();
  super_dit16<-1, 4, 2>(d, tid);     __syncthreads();
  super_dit16<-1, 64, 6>(d, tid);    __syncthreads();
  super_dit16<-1, 1024, 10>(d, tid); __syncthreads();
  const int sb = SBTAB[j1 >> 3];
  float2* urow = u1h + (size_t)(b * N1 + j1) * USTRIDE;
  for (int i = tid; i < sb; i += NT2) {
    v2f u = d[pad(i)];
    urow[i] = make_float2(u.x, u.y);
  }
  fold_store16(d, phi, out + 1024 + (size_t)(b * N1 + j1) * 64, tid);
}

// Decimated order-1 body: demodulated band [lo,hi) at slots [0,W).
// RMAX=13: bins [0, 13*M1) >= sb for every class (q=1: 6656>=6452, ...).
template<int LOGN>
__device__ __forceinline__ void o1_dec_body(v2f* sm, int sub, int t, int j1, int b,
    const float2* __restrict__ xh, const float* __restrict__ psi1,
    const float* __restrict__ phi, float2* __restrict__ u1h, float* __restrict__ out)
{
  constexpr int N = 1<<LOGN, SEGT = N/16;
  const bool valid = (j1 < 64);
  const int jc = valid ? j1 : 63;
  v2f* ds = sm + sub*N + ((sub*N)>>4);
  int lo = 0, W = 0;
  if (valid) {
    const float c = 5734.4f * exp2f(-0.125f*(float)j1);
    lo = max(0, (int)(0.36f*c));
    const int hi = min(T_N, (int)(1.64f*c)+2);
    W = hi - lo;
  }
  const float2* xrow = xh + (size_t)b * T_N;
  const float* prow = psi1 + jc * T_N;
#pragma unroll
  for (int s = 0; s < 16; ++s) {
    int f = t + s*SEGT;
    v2f z; z.x = 0.f; z.y = 0.f;
    if (f < W) { float2 xv = xrow[lo+f]; float p = prow[lo+f]; z.x = xv.x*p; z.y = xv.y*p; }
    ds[f + (f>>4)] = z;
  }
  __syncthreads();
  o2_body<LOGN, 13, false>(ds, t);
  if (valid) {
    const int sb = SBTAB[j1>>3];
    const float R = (float)(T_N >> LOGN);
    float2* urow = u1h + (size_t)(b*N1 + j1) * USTRIDE;
    for (int i = t; i < sb; i += SEGT) {
      v2f u = ds[i + (i>>4)];
      urow[i] = make_float2(R*u.x, R*u.y);
    }
    fold_generic<SEGT/64>(ds, phi, out + 1024 + (size_t)(b*N1 + j1)*64, t, 1.f/(float)N);
  }
}

// K2 (merged order-1): blocks [0, 8*B) full 16k pipelines (q=0, heavy first);
// then 9 decimated groups per batch:
// grp 0-3: q=1 N'=8192 PPB=2 | 4-5: q=2 4096x4 | 6: q=3 2048x8 | 7-8: q>=4 1024x16.
__global__ void __launch_bounds__(NT2, 4) k_o1(const float2* __restrict__ xh, const float* __restrict__ psi1,
                                               const float* __restrict__ phi, float2* __restrict__ u1h,
                                               float* __restrict__ out)
{
  extern __shared__ char smem[];
  v2f* sm = (v2f*)smem;
  if (blockIdx.x < B_SZ*8) {
    o1_full_body(sm, threadIdx.x, blockIdx.x >> 3, blockIdx.x & 7, xh, psi1, phi, u1h, out);
    return;
  }
  const int ix = blockIdx.x - B_SZ*8;
  const int grp = ix % 9, b = ix / 9;
  if (grp < 4) {
    o1_dec_body<13>(sm, threadIdx.x >> 9, threadIdx.x & 511, 8 + grp*2 + (threadIdx.x >> 9),
                    b, xh, psi1, phi, u1h, out);
  } else if (grp < 6) {
    o1_dec_body<12>(sm, threadIdx.x >> 8, threadIdx.x & 255, 16 + (grp-4)*4 + (threadIdx.x >> 8),
                    b, xh, psi1, phi, u1h, out);
  } else if (grp == 6) {
    o1_dec_body<11>(sm, threadIdx.x >> 7, threadIdx.x & 127, 24 + (threadIdx.x >> 7),
                    b, xh, psi1, phi, u1h, out);
  } else {
    o1_dec_body<10>(sm, threadIdx.x >> 6, threadIdx.x & 63, 32 + (grp-7)*16 + (threadIdx.x >> 6),
                    b, xh, psi1, phi, u1h, out);
  }
}

// Order-2 full-size body (j2 = 1 only; j1 < 8).
__device__ __forceinline__ void o2_16k_body(v2f* d, int tid, int b, int j1,
    const float2* __restrict__ u1h, const float* __restrict__ psi2,
    const float* __restrict__ phi, float* __restrict__ out)
{
  const int W = WTAB[1];
  const float2* urow = u1h + (size_t)(b * N1 + j1) * USTRIDE;
  const float* prow = psi2 + 1 * T_N;
#pragma unroll
  for (int s = 0; s < T_N/NT2; ++s) {
    int i = tid + s*NT2;
    v2f z; z.x = 0.f; z.y = 0.f;
    if (i < W) {
      float2 u;
      if (i <= T_N/2) u = urow[i];
      else { float2 t = urow[T_N - i]; u = make_float2(t.x, -t.y); }
      float ps = prow[i];
      z.x = u.x*ps; z.y = u.y*ps;
    }
    d[pad(i)] = z;
  }
  __syncthreads();
  const int K1 = pow2ceil16((W + 1023) >> 10);
  stage1_dispatch(d, tid, 0, K1, 0, W);
  stage2_dispatch(d, tid, 0, 16);
  super_dif16<+1, 4, 2>(d, tid);      __syncthreads();
  fused_mid4(d, tid);                 __syncthreads();
  super_dit16<-1, 4, 2>(d, tid);      __syncthreads();
  super_dit16_m64_prune<-1>(d, tid);  __syncthreads();
  super_dit16_m1024_bin256<-1>(d, tid); __syncthreads();
  const int p = pair_index(j1, 1);
  fold_store16(d, phi, out + 66560 + (size_t)(b * NPAIR + p) * 64, tid);
}

// Decimated order-2 body (S2 fold only).
template<int LOGN>
__device__ __forceinline__ void o2_cls_body(v2f* sm, int sub, int t, int b, int j1, int j2, bool valid,
    const float2* __restrict__ u1h, const float* __restrict__ psi2,
    const float* __restrict__ phi, float* __restrict__ out)
{
  constexpr int N = 1<<LOGN, SEGT = N/16;
  v2f* ds = sm + sub*N + ((sub*N)>>4);
  const int W = valid ? WTAB[j2 & 7] : 0;
  const float2* urow = u1h + (size_t)(b * N1 + j1) * USTRIDE;
  const float* prow = psi2 + j2 * T_N;
#pragma unroll
  for (int s = 0; s < 16; ++s) {
    int f = t + s*SEGT;
    v2f z; z.x = 0.f; z.y = 0.f;
    if (f < W) { float2 u = urow[f]; float ps = prow[f]; z.x = u.x*ps; z.y = u.y*ps; }
    ds[f + (f>>4)] = z;
  }
  __syncthreads();
  constexpr int RM = ((1<<(LOGN-4)) >= 256) ? 1 : (256 >> (LOGN-4));
  constexpr bool JL = ((1<<(LOGN-4)) > 256);
  o2_body<LOGN, RM, JL>(ds, t);
  if (valid) {
    const int p = pair_index(j1, j2);
    fold_generic<SEGT/64>(ds, phi, out + 66560 + (size_t)(b * NPAIR + p) * 64, t, 1.f/(float)N);
  }
}

// K3 (merged order-2): blocks [0, 8*B) full 16k pipelines (j2=1, heavy first);
// then 28 decimated groups per batch:
// grp 0-7: j2=2 N'=8192 PPB=2 | 8-13: j2=3 4096x4 | 14-17: j2=4 2048x8
// | 18-20: j2=5 1024x16 (valid j1<40) | 21-27: j2 in {6,7} 1024x16.
__global__ void __launch_bounds__(NT2, 4) k_o2(const float2* __restrict__ u1h, const float* __restrict__ psi2,
                                               const float* __restrict__ phi, float* __restrict__ out)
{
  extern __shared__ char smem[];
  v2f* sm = (v2f*)smem;
  if (blockIdx.x < B_SZ*8) {
    o2_16k_body(sm, threadIdx.x, blockIdx.x >> 3, blockIdx.x & 7, u1h, psi2, phi, out);
    return;
  }
  const int ix = blockIdx.x - B_SZ*8;
  const int grp = ix % 28, b = ix / 28;
  if (grp < 8) {
    const int sub = threadIdx.x >> 9, t = threadIdx.x & 511;
    o2_cls_body<13>(sm, sub, t, b, grp*2 + sub, 2, true, u1h, psi2, phi, out);
  } else if (grp < 14) {
    const int sub = threadIdx.x >> 8, t = threadIdx.x & 255;
    o2_cls_body<12>(sm, sub, t, b, (grp-8)*4 + sub, 3, true, u1h, psi2, phi, out);
  } else if (grp < 18) {
    const int sub = threadIdx.x >> 7, t = threadIdx.x & 127;
    o2_cls_body<11>(sm, sub, t, b, (grp-14)*8 + sub, 4, true, u1h, psi2, phi, out);
  } else if (grp < 21) {
    const int sub = threadIdx.x >> 6, t = threadIdx.x & 63;
    const int j1 = (grp-18)*16 + sub;
    o2_cls_body<10>(sm, sub, t, b, j1, 5, j1 < 40, u1h, psi2, phi, out);
  } else {
    const int sub = threadIdx.x >> 6, t = threadIdx.x & 63;
    const int cls_p = (grp-21)*16 + sub;
    const bool valid = (cls_p < 104);
    const int j2 = (cls_p < 48) ? 6 : 7;
    const int j1 = cls_p - ((cls_p < 48) ? 0 : 48);
    o2_cls_body<10>(sm, sub, t, b, j1, j2, valid, u1h, psi2, phi, out);
  }
}

extern "C" void kernel_launch(void* const* d_in, const int* in_sizes, int n_in,
                              void* d_out, int out_size, void* d_ws, size_t ws_size,
                              hipStream_t stream)
{
  const float* x    = (const float*)d_in[0];
  const float* psi1 = (const float*)d_in[1];
  const float* psi2 = (const float*)d_in[2];
  const float* phi  = (const float*)d_in[3];
  float* out = (float*)d_out;

  float2* xh  = (float2*)d_ws;
  float2* u1h = xh + (size_t)B_SZ * T_N;

  const size_t lds = (size_t)(T_N + (T_N >> 4)) * sizeof(float2);  // 139264 B

  (void)hipFuncSetAttribute((const void*)k_fft_x, hipFuncAttributeMaxDynamicSharedMemorySize, (int)lds);
  (void)hipFuncSetAttribute((const void*)k_o1,    hipFuncAttributeMaxDynamicSharedMemorySize, (int)lds);
  (void)hipFuncSetAttribute((const void*)k_o2,    hipFuncAttributeMaxDynamicSharedMemorySize, (int)lds);

  hipLaunchKernelGGL(k_fft_x, dim3(B_SZ),               dim3(NT),  lds, stream, x, phi, xh, out);
  hipLaunchKernelGGL(k_o1,    dim3(B_SZ*8 + B_SZ*9),    dim3(NT2), lds, stream, xh, psi1, phi, u1h, out);
  hipLaunchKernelGGL(k_o2,    dim3(B_SZ*8 + B_SZ*28),   dim3(NT2), lds, stream, u1h, psi2, phi, out);
}

// Round 12
// 236.753 us; speedup vs baseline: 3.6844x; 1.0269x over previous
//
#include <hip/hip_runtime.h>
#include <math.h>

// Wavelet scattering, T=16384.  Radix-16 register-blocked in-LDS FFTs with
// per-octave decimated pipelines.  R12: per-class block sizing — decimated
// classes run in 512-thread / 69.6KB blocks (2 blocks/CU, two independent
// barrier domains) instead of packed 1024-thread / 139KB blocks (1/CU).
// Heavy 16k classes keep 1024thr/139KB.  5 launches:
// fft_x -> o1_heavy -> o1_light -> o2_heavy -> o2_light.

#define T_N   16384
#define NT    512
#define NT2   1024
#define B_SZ  16
#define N1    64
#define NPAIR 224
#define FOLD_F 256
#define USTRIDE 8208
#define INV_N (1.0f/16384.0f)
#define TWO_PI 6.283185307179586f

typedef float v2f __attribute__((ext_vector_type(2)));

__device__ __forceinline__ int pad(int i) { return i + (i >> 4); }

__device__ __forceinline__ v2f cmulw(v2f a, v2f w){
  v2f n; n.x = -a.y; n.y = a.x;
  return w.x * a + w.y * n;
}
__device__ __forceinline__ constexpr int br4(int x){
  return ((x&1)<<3)|((x&2)<<1)|((x&4)>>1)|((x&8)>>3);
}
template<int LB>
__device__ __forceinline__ constexpr int brN(int x){
  int r=0;
  for(int i=0;i<LB;++i){ r=(r<<1)|((x>>i)&1); }
  return r;
}
__device__ __forceinline__ int rev4_14(int p){
  unsigned r = __brev((unsigned)p) >> 18;
  return (int)(((r & 0x2AAAu) >> 1) | ((r & 0x1555u) << 1));
}
__device__ __forceinline__ int pow2ceil16(int k){
  return (k<=1)?1:(k<=2)?2:(k<=4)?4:(k<=8)?8:16;
}

// tw[r] = w^r via depth-4 product tree.
__device__ __forceinline__ void twiddle_tree(v2f w, v2f* tw){
  tw[0].x = 1.f; tw[0].y = 0.f;
  tw[1] = w;
  tw[2] = cmulw(w, w);
  tw[4] = cmulw(tw[2], tw[2]);
  tw[8] = cmulw(tw[4], tw[4]);
  tw[3] = cmulw(tw[2], w);
  tw[5] = cmulw(tw[4], w);
  tw[6] = cmulw(tw[4], tw[2]);
  tw[7] = cmulw(tw[4], tw[3]);
  tw[9]  = cmulw(tw[8], w);
  tw[10] = cmulw(tw[8], tw[2]);
  tw[11] = cmulw(tw[8], tw[3]);
  tw[12] = cmulw(tw[8], tw[4]);
  tw[13] = cmulw(tw[8], tw[5]);
  tw[14] = cmulw(tw[8], tw[6]);
  tw[15] = cmulw(tw[8], tw[7]);
}

// Generic fully-unrolled DFT of size 2^LOGNN (<=16); y[r] lands at a[brN(r)].
template<int SGN, int LOGNN>
__device__ __forceinline__ void dft_reg(v2f* a){
  constexpr int NN = 1<<LOGNN;
  static constexpr float C16[16] = {
    1.f, 0.98078528f, 0.92387953f, 0.83146961f, 0.70710678f, 0.55557023f,
    0.38268343f, 0.19509032f, 0.f, -0.19509032f, -0.38268343f, -0.55557023f,
    -0.70710678f, -0.83146961f, -0.92387953f, -0.98078528f };
  static constexpr float S16[16] = {
    0.f, 0.19509032f, 0.38268343f, 0.55557023f, 0.70710678f, 0.83146961f,
    0.92387953f, 0.98078528f, 1.f, 0.98078528f, 0.92387953f, 0.83146961f,
    0.70710678f, 0.55557023f, 0.38268343f, 0.19509032f };
#pragma unroll
  for (int m = NN/2; m >= 1; m >>= 1) {
#pragma unroll
    for (int base = 0; base < NN; base += 2*m) {
#pragma unroll
      for (int j = 0; j < m; ++j) {
        v2f u = a[base+j], v = a[base+j+m];
        a[base+j] = u + v;
        v2f w = u - v;
        const int ti = (j*16)/m;
        v2f tw; tw.x = C16[ti]; tw.y = (float)SGN * S16[ti];
        a[base+j+m] = cmulw(w, tw);
      }
    }
  }
}
template<int SGN>
__device__ __forceinline__ void dft16(v2f* a){ dft_reg<SGN,4>(a); }

// Full DIF super-stage radix-16 at stride M.
template<int SGN, int M, int LOGM>
__device__ __forceinline__ void super_dif16(v2f* d, int g)
{
  const int j = g & (M-1);
  const int base = ((g >> LOGM) << (LOGM+4)) | j;
  v2f* dp = d + pad(base);
  v2f a[16];
#pragma unroll
  for (int k = 0; k < 16; ++k) a[k] = dp[k*M + ((k*M)>>4)];
  dft16<SGN>(a);
  float sj, cj;
  __sincosf((float)SGN * (TWO_PI / (16.f*(float)M)) * (float)j, &sj, &cj);
  v2f w; w.x = cj; w.y = sj;
  v2f tw[16];
  twiddle_tree(w, tw);
  dp[0] = a[0];
#pragma unroll
  for (int r = 1; r < 16; ++r)
    dp[r*M + ((r*M)>>4)] = cmulw(a[br4(r)], tw[r]);
}

// SPARSE DIF super-stage: only taps [k0,k0+K) possibly nonzero (rest zeros).
template<int SGN, int M, int LOGM, int K>
__device__ __forceinline__ void super_dif16_sparse(v2f* d, int g, int k0)
{
  static constexpr float CW[16] = { 1.f, 0.92387953f, 0.70710678f, 0.38268343f,
    0.f, -0.38268343f, -0.70710678f, -0.92387953f, -1.f, -0.92387953f,
    -0.70710678f, -0.38268343f, 0.f, 0.38268343f, 0.70710678f, 0.92387953f };
  static constexpr float SW[16] = { 0.f, 0.38268343f, 0.70710678f, 0.92387953f,
    1.f, 0.92387953f, 0.70710678f, 0.38268343f, 0.f, -0.38268343f,
    -0.70710678f, -0.92387953f, -1.f, -0.92387953f, -0.70710678f, -0.38268343f };
  const int j = g & (M-1);
  const int base = ((g >> LOGM) << (LOGM+4)) | j;
  v2f* dp = d + pad(base);
  v2f a[K];
#pragma unroll
  for (int m = 0; m < K; ++m) {
    const int k = k0 + m;
    a[m] = dp[k*M + ((k*M)>>4)];
  }
  v2f y[16];
  if constexpr (K == 1) {
#pragma unroll
    for (int r = 0; r < 16; ++r) y[r] = a[0];
  } else if constexpr (K == 2) {
#pragma unroll
    for (int r0 = 0; r0 < 8; ++r0) {
      v2f w; w.x = CW[r0]; w.y = (float)SGN * SW[r0];
      v2f b1 = cmulw(a[1], w);
      y[r0]   = a[0] + b1;
      y[r0+8] = a[0] - b1;
    }
  } else if constexpr (K == 4) {
#pragma unroll
    for (int r0 = 0; r0 < 4; ++r0) {
      v2f z1, z2, z3;
      { v2f w; w.x = CW[r0];        w.y = (float)SGN*SW[r0];        z1 = cmulw(a[1], w); }
      { v2f w; w.x = CW[(2*r0)&15]; w.y = (float)SGN*SW[(2*r0)&15]; z2 = cmulw(a[2], w); }
      { v2f w; w.x = CW[(3*r0)&15]; w.y = (float)SGN*SW[(3*r0)&15]; z3 = cmulw(a[3], w); }
      v2f e0 = a[0]+z2, e1 = a[0]-z2, o0 = z1+z3, o1 = z1-z3;
      v2f io; io.x = -(float)SGN*o1.y; io.y = (float)SGN*o1.x;
      y[r0]    = e0 + o0;
      y[r0+4]  = e1 + io;
      y[r0+8]  = e0 - o0;
      y[r0+12] = e1 - io;
    }
  } else { // K == 8
#pragma unroll
    for (int r0 = 0; r0 < 2; ++r0) {
      v2f z[8];
      z[0] = a[0];
#pragma unroll
      for (int m = 1; m < 8; ++m) {
        v2f w; w.x = CW[(m*r0)&15]; w.y = (float)SGN*SW[(m*r0)&15];
        z[m] = cmulw(a[m], w);
      }
      v2f E[4], O[4];
      {
        v2f e0=z[0]+z[4], e1=z[0]-z[4], o0=z[2]+z[6], o1=z[2]-z[6];
        v2f io; io.x=-(float)SGN*o1.y; io.y=(float)SGN*o1.x;
        E[0]=e0+o0; E[1]=e1+io; E[2]=e0-o0; E[3]=e1-io;
      }
      {
        v2f e0=z[1]+z[5], e1=z[1]-z[5], o0=z[3]+z[7], o1=z[3]-z[7];
        v2f io; io.x=-(float)SGN*o1.y; io.y=(float)SGN*o1.x;
        O[0]=e0+o0; O[1]=e1+io; O[2]=e0-o0; O[3]=e1-io;
      }
      constexpr float RT = 0.70710678f;
#pragma unroll
      for (int r1 = 0; r1 < 4; ++r1) {
        v2f w8;
        if (r1 == 0)      { w8.x = 1.f;  w8.y = 0.f; }
        else if (r1 == 1) { w8.x = RT;   w8.y = (float)SGN*RT; }
        else if (r1 == 2) { w8.x = 0.f;  w8.y = (float)SGN; }
        else              { w8.x = -RT;  w8.y = (float)SGN*RT; }
        v2f t = cmulw(O[r1], w8);
        y[2*r1 + r0]     = E[r1] + t;
        y[2*r1 + r0 + 8] = E[r1] - t;
      }
    }
  }
  float sj, cj;
  __sincosf((float)SGN * (TWO_PI / (16.f*(float)M)) * (float)(j + k0*M), &sj, &cj);
  v2f w; w.x = cj; w.y = sj;
  v2f tw[16];
  twiddle_tree(w, tw);
  dp[0] = y[0];
#pragma unroll
  for (int r = 1; r < 16; ++r)
    dp[r*M + ((r*M)>>4)] = cmulw(y[r], tw[r]);
}

// Runtime dispatch (16k pipelines), barriers included.
__device__ __forceinline__ void stage1_dispatch(v2f* d, int tid, int k0, int K1, int jlo, int jhi)
{
  if (K1 == 16)     super_dif16<+1, 1024, 10>(d, tid);
  else if (K1 == 8) super_dif16_sparse<+1,1024,10,8>(d, tid, k0);
  else if (K1 == 4) super_dif16_sparse<+1,1024,10,4>(d, tid, k0);
  else if (K1 == 2) super_dif16_sparse<+1,1024,10,2>(d, tid, k0);
  else { if (tid >= jlo && tid < jhi) super_dif16_sparse<+1,1024,10,1>(d, tid, k0); }
  __syncthreads();
}
__device__ __forceinline__ void stage2_dispatch(v2f* d, int tid, int k0, int K2)
{
  if (K2 == 16)     super_dif16<+1, 64, 6>(d, tid);
  else if (K2 == 8) super_dif16_sparse<+1,64,6,8>(d, tid, k0);
  else if (K2 == 4) super_dif16_sparse<+1,64,6,4>(d, tid, k0);
  else if (K2 == 2) super_dif16_sparse<+1,64,6,2>(d, tid, k0);
  else              super_dif16_sparse<+1,64,6,1>(d, tid, k0);
  __syncthreads();
}

// Full DIT super-stage radix-16 at stride M.
template<int SGN, int M, int LOGM>
__device__ __forceinline__ void super_dit16(v2f* d, int g)
{
  const int j = g & (M-1);
  const int base = ((g >> LOGM) << (LOGM+4)) | j;
  v2f* dp = d + pad(base);
  float sj, cj;
  __sincosf((float)SGN * (TWO_PI / (16.f*(float)M)) * (float)j, &sj, &cj);
  v2f w; w.x = cj; w.y = sj;
  v2f tw[16];
  twiddle_tree(w, tw);
  v2f a[16];
  a[0] = dp[0];
#pragma unroll
  for (int k = 1; k < 16; ++k)
    a[k] = cmulw(dp[k*M + ((k*M)>>4)], tw[k]);
  dft16<SGN>(a);
#pragma unroll
  for (int r = 0; r < 16; ++r) dp[r*M + ((r*M)>>4)] = a[br4(r)];
}

// PRUNED DIT16 at M=64 (r<4) — 16k pipeline.
template<int SGN>
__device__ __forceinline__ void super_dit16_m64_prune(v2f* d, int g)
{
  constexpr int M = 64;
  constexpr int PSTR = M + (M>>4);
  const int j = g & 63;
  const int base = ((g >> 6) << 10) | j;
  v2f* dp = d + pad(base);
  float sj, cj;
  __sincosf((float)SGN * (TWO_PI / 1024.f) * (float)j, &sj, &cj);
  v2f w; w.x = cj; w.y = sj;
  v2f tw[16];
  twiddle_tree(w, tw);
  v2f a[16];
  a[0] = dp[0];
#pragma unroll
  for (int k = 1; k < 16; ++k)
    a[k] = cmulw(dp[k*M + ((k*M)>>4)], tw[k]);
  v2f Y[4][4];
#pragma unroll
  for (int c = 0; c < 4; ++c) {
    v2f s0=a[c], s1=a[c+4], s2=a[c+8], s3=a[c+12];
    v2f e0 = s0+s2, e1 = s0-s2, o0 = s1+s3, o1 = s1-s3;
    v2f io1; io1.x = -(float)SGN * o1.y; io1.y = (float)SGN * o1.x;
    Y[c][0] = e0 + o0;
    Y[c][1] = e1 + io1;
    Y[c][2] = e0 - o0;
    Y[c][3] = e1 - io1;
  }
  static constexpr float WC[10] = {1.f,0.92387953f,0.70710678f,0.38268343f,0.f,
                                   -0.38268343f,-0.70710678f,-0.92387953f,-1.f,-0.92387953f};
  static constexpr float WS[10] = {0.f,0.38268343f,0.70710678f,0.92387953f,1.f,
                                   0.92387953f,0.70710678f,0.38268343f,0.f,-0.38268343f};
#pragma unroll
  for (int r = 0; r < 4; ++r) {
    v2f acc = Y[0][r];
#pragma unroll
    for (int c = 1; c < 4; ++c) {
      v2f wc; wc.x = WC[r*c]; wc.y = (float)SGN * WS[r*c];
      acc += cmulw(Y[c][r], wc);
    }
    dp[r*PSTR] = acc;
  }
}

// PRUNED final DIT16 at M=1024: bins j<256 — 16k pipeline.
template<int SGN>
__device__ __forceinline__ void super_dit16_m1024_bin256(v2f* d, int tid)
{
  if (tid < 256) {
    const int j = tid;
    v2f* dp = d + pad(j);
    float sj, cj;
    __sincosf((float)SGN * (TWO_PI / 16384.f) * (float)j, &sj, &cj);
    v2f w; w.x = cj; w.y = sj;
    v2f tw[16];
    twiddle_tree(w, tw);
    v2f acc = dp[0];
#pragma unroll
    for (int k = 1; k < 16; ++k)
      acc += cmulw(dp[k*1024 + ((k*1024)>>4)], tw[k]);
    dp[0] = acc;
  }
}

// Generic output-pruned final DIT16 at M1 = 2^LOGM1: outputs r < RMAX.
template<int SGN, int LOGM1, int RMAX, bool JLIM>
__device__ __forceinline__ void final_prune(v2f* ds, int t)
{
  static constexpr float CW[16] = { 1.f, 0.92387953f, 0.70710678f, 0.38268343f,
    0.f, -0.38268343f, -0.70710678f, -0.92387953f, -1.f, -0.92387953f,
    -0.70710678f, -0.38268343f, 0.f, 0.38268343f, 0.70710678f, 0.92387953f };
  static constexpr float SW[16] = { 0.f, 0.38268343f, 0.70710678f, 0.92387953f,
    1.f, 0.92387953f, 0.70710678f, 0.38268343f, 0.f, -0.38268343f,
    -0.70710678f, -0.92387953f, -1.f, -0.92387953f, -0.70710678f, -0.38268343f };
  constexpr int M1 = 1<<LOGM1;
  const int j = t;
  if (JLIM && j >= 256) return;
  v2f* dp = ds + j + (j>>4);
  float sj, cj;
  __sincosf((float)SGN * (TWO_PI / (16.f*(float)M1)) * (float)j, &sj, &cj);
  v2f w; w.x = cj; w.y = sj;
  v2f tw[16];
  twiddle_tree(w, tw);
  v2f b[16];
  b[0] = dp[0];
#pragma unroll
  for (int k = 1; k < 16; ++k)
    b[k] = cmulw(dp[k*M1 + ((k*M1)>>4)], tw[k]);
#pragma unroll
  for (int r = 0; r < RMAX; ++r) {
    v2f acc = b[0];
#pragma unroll
    for (int k = 1; k < 16; ++k) {
      v2f wc; wc.x = CW[(r*k)&15]; wc.y = (float)SGN*SW[(r*k)&15];
      acc += cmulw(b[k], wc);
    }
    dp[r*M1 + ((r*M1)>>4)] = acc;
  }
}

// DIF chain descending (barrier after each stage).
template<int SGN, int LOGM>
__device__ __forceinline__ void dif_chain(v2f* ds, int t){
  super_dif16<SGN, (1<<LOGM), LOGM>(ds, t);
  __syncthreads();
  if constexpr (LOGM > 4) dif_chain<SGN, LOGM-4>(ds, t);
}
// DIT chain ascending up to (excluding) LOGTOP.
template<int SGN, int LOGM, int LOGTOP>
__device__ __forceinline__ void dit_chain(v2f* ds, int t){
  super_dit16<SGN, (1<<LOGM), LOGM>(ds, t);
  __syncthreads();
  if constexpr (LOGM + 4 < LOGTOP) dit_chain<SGN, LOGM+4, LOGTOP>(ds, t);
}

// Generic mid: per contiguous-16 (thread t): inverse DFT_MM -> |.|/T -> fwd DFT_MM.
template<int LOGMM>
__device__ __forceinline__ void mid_generic(v2f* ds, int t)
{
  constexpr int MM = 1<<LOGMM;
  v2f* dp = ds + 17*t;
#pragma unroll
  for (int q = 0; q < 16/MM; ++q) {
    v2f a[MM];
#pragma unroll
    for (int i = 0; i < MM; ++i) a[i] = dp[q*MM+i];
    dft_reg<+1,LOGMM>(a);
    v2f m[MM];
#pragma unroll
    for (int r = 0; r < MM; ++r) {
      v2f y = a[brN<LOGMM>(r)];
      m[r].x = INV_N * sqrtf(y.x*y.x + y.y*y.y);
      m[r].y = 0.f;
    }
    dft_reg<-1,LOGMM>(m);
#pragma unroll
    for (int k = 0; k < MM; ++k) dp[q*MM+k] = m[brN<LOGMM>(k)];
  }
}

// mid4 specialization used by 16k pipelines.
__device__ __forceinline__ void fused_mid4(v2f* d, int t)
{
  v2f* dp = d + 17*t;
#pragma unroll
  for (int q = 0; q < 4; ++q) {
    v2f a0=dp[4*q], a1=dp[4*q+1], a2=dp[4*q+2], a3=dp[4*q+3];
    v2f t0=a0+a2, t1=a0-a2, t2=a1+a3, t3=a1-a3;
    v2f it3; it3.x = -t3.y; it3.y = t3.x;
    v2f y0=t0+t2, y2=t0-t2, y1=t1+it3, y3=t1-it3;
    float m0 = INV_N * sqrtf(y0.x*y0.x + y0.y*y0.y);
    float m1 = INV_N * sqrtf(y1.x*y1.x + y1.y*y1.y);
    float m2 = INV_N * sqrtf(y2.x*y2.x + y2.y*y2.y);
    float m3 = INV_N * sqrtf(y3.x*y3.x + y3.y*y3.y);
    float p0=m0+m2, p1=m0-m2, p2=m1+m3, p3=m1-m3;
    v2f o0; o0.x = p0+p2; o0.y = 0.f;
    v2f o1; o1.x = p1;    o1.y = -p3;
    v2f o2; o2.x = p0-p2; o2.y = 0.f;
    v2f o3; o3.x = p1;    o3.y = p3;
    dp[4*q]=o0; dp[4*q+1]=o1; dp[4*q+2]=o2; dp[4*q+3]=o3;
  }
}

// Generic decimated pipeline body for LOGN in {10,11,12,13}.
template<int LOGN, int RMAX, bool JL>
__device__ __forceinline__ void o2_body(v2f* ds, int t)
{
  constexpr int LOGM1 = LOGN-4;
  super_dif16_sparse<+1, (1<<LOGM1), LOGM1, 8>(ds, t, 0);
  __syncthreads();
  dif_chain<+1, LOGM1-4>(ds, t);
  constexpr int LOGMM = ((LOGM1-5)%4)+1;
  mid_generic<LOGMM>(ds, t);
  __syncthreads();
  dit_chain<-1, LOGMM, LOGM1>(ds, t);
  final_prune<-1, LOGM1, RMAX, JL>(ds, t);
  __syncthreads();
}

// Generic fold: SEGT = 64*PERK threads, scale applied at write.
template<int PERK>
__device__ __forceinline__ void fold_generic(const v2f* ds, const float* __restrict__ phi,
                                             float* outp, int t, float scale)
{
  const int k = t / PERK, g = t % PERK;
  float sv, cv, ss, cs;
  __sincosf((TWO_PI/64.f) * (float)((g*k) & 63), &sv, &cv);
  __sincosf((TWO_PI/64.f) * (float)((PERK*k) & 63), &ss, &cs);
  float acc = 0.f;
#pragma unroll
  for (int m = 0; m < 256/PERK; ++m) {
    const int f = g + PERK*m;
    v2f u = ds[f + (f>>4)];
    float wgt = phi[f] * ((f == 0) ? 1.f : 2.f);
    acc += wgt * (u.x*cv - u.y*sv);
    float nc = cv*cs - sv*ss, ns = cv*ss + sv*cs;
    cv = nc; sv = ns;
  }
#pragma unroll
  for (int o = 1; o < PERK; o <<= 1) acc += __shfl_xor(acc, o);
  if (g == 0) outp[k] = acc * scale;
}

// phi-fold for full-size (1024-thread) pipelines.
__device__ void fold_store16(const v2f* d, const float* __restrict__ phi, float* outp, int tid)
{
  const int k = tid >> 4, g = tid & 15;
  float sv, cv;
  __sincosf((TWO_PI/64.f) * (float)((g*k) & 63), &sv, &cv);
  const int km = k & 3;
  const float strRe = (km==0) ? 1.f : (km==2 ? -1.f : 0.f);
  const float strIm = (km==1) ? 1.f : (km==3 ? -1.f : 0.f);
  float acc = 0.f;
#pragma unroll
  for (int m = 0; m < 16; ++m) {
    const int f = g + 16*m;
    v2f u = d[pad(f)];
    float wgt = phi[f] * ((f == 0) ? 1.f : 2.f);
    acc += wgt * (u.x*cv - u.y*sv);
    float nc = cv*strRe - sv*strIm;
    float ns = cv*strIm + sv*strRe;
    cv = nc; sv = ns;
  }
  acc += __shfl_xor(acc, 1);
  acc += __shfl_xor(acc, 2);
  acc += __shfl_xor(acc, 4);
  acc += __shfl_xor(acc, 8);
  if (g == 0) outp[k] = acc * INV_N;
}

// Reference pair index (j1-major, valid j2 > j1/8).
__device__ __forceinline__ int pair_index(int j1, int j2)
{
  const int q = j1 >> 3;
  return 8*(7*q - (q*(q-1))/2) + (j1 & 7)*(7 - q) + (j2 - q - 1);
}

// psi2 band widths W(j2) = ceil(4.5 * 5734.4 * 2^-j2)
__device__ __constant__ int WTAB[8]  = {16384, 12903, 6452, 3226, 1613, 807, 404, 202};
// U1h store bound per j1-octave q: W(q+1) capped at 8193
__device__ __constant__ int SBTAB[8] = {8193, 6452, 3226, 1613, 807, 404, 202, 0};

// ---- radix-4 float2 path for k_fft_x ----
__device__ __forceinline__ float2 f2add(float2 a, float2 b){ return make_float2(a.x+b.x, a.y+b.y); }
__device__ __forceinline__ float2 f2sub(float2 a, float2 b){ return make_float2(a.x-b.x, a.y-b.y); }
__device__ __forceinline__ float2 cmul_cs(float2 a, float c, float s){
  return make_float2(a.x*c - a.y*s, a.x*s + a.y*c);
}
__device__ void dif_sweep(float2* d, int tid, float sgn, int mb_hi, int mb_lo)
{
  const float ang = sgn * (TWO_PI / (float)T_N);
  for (int mbits = mb_hi; mbits >= mb_lo; mbits -= 2) {
    const int M = 1 << mbits;
#pragma unroll 8
    for (int v = tid; v < T_N/4; v += NT) {
      const int j = v & (M-1);
      const int base = ((v >> mbits) << (mbits+2)) | j;
      const int i0 = pad(base), i1 = pad(base+M), i2 = pad(base+2*M), i3 = pad(base+3*M);
      float2 a0=d[i0], a1=d[i1], a2=d[i2], a3=d[i3];
      float2 t0=f2add(a0,a2), t1=f2sub(a0,a2), t2=f2add(a1,a3), t3=f2sub(a1,a3);
      float2 y0=f2add(t0,t2), y2=f2sub(t0,t2);
      float2 y1=make_float2(t1.x - sgn*t3.y, t1.y + sgn*t3.x);
      float2 y3=make_float2(t1.x + sgn*t3.y, t1.y - sgn*t3.x);
      float s1,c1;
      __sincosf(ang * (float)(j << (12-mbits)), &s1, &c1);
      float c2=c1*c1-s1*s1, s2=2.f*c1*s1;
      float c3=c1*c2-s1*s2, s3=c1*s2+s1*c2;
      d[i0]=y0;
      d[i1]=cmul_cs(y1,c1,s1);
      d[i2]=cmul_cs(y2,c2,s2);
      d[i3]=cmul_cs(y3,c3,s3);
    }
    __syncthreads();
  }
}
__device__ void fold_store8(const float2* d, const float* __restrict__ phi, float* outp, int tid)
{
  const int k = tid >> 3, g = tid & 7;
  float acc = 0.f;
  for (int f = g; f < FOLD_F; f += 8) {
    float2 u = d[pad(f)];
    float w = phi[f] * ((f == 0) ? 1.f : 2.f);
    float sv, cv;
    __sincosf((TWO_PI/64.f) * (float)((f*k) & 63), &sv, &cv);
    acc += w * (u.x*cv - u.y*sv);
  }
  acc += __shfl_xor(acc, 1);
  acc += __shfl_xor(acc, 2);
  acc += __shfl_xor(acc, 4);
  if (g == 0) outp[k] = acc * INV_N;
}

// K1: xh = FFT(x) + S0 fold.
__global__ void __launch_bounds__(NT) k_fft_x(const float* __restrict__ x, const float* __restrict__ phi,
                                              float2* __restrict__ xh, float* __restrict__ out)
{
  extern __shared__ char smem[];
  float2* d = (float2*)smem;
  const int tid = threadIdx.x;
  const int b = blockIdx.x;
  const float* xr = x + b * T_N;
  for (int i = tid; i < T_N; i += NT) d[pad(i)] = make_float2(xr[i], 0.f);
  __syncthreads();
  dif_sweep(d, tid, -1.f, 12, 0);
  for (int p = tid; p < T_N; p += NT) {
    int r = rev4_14(p);
    if (p < r) { int ip = pad(p), ir = pad(r); float2 t = d[ip]; d[ip] = d[ir]; d[ir] = t; }
  }
  __syncthreads();
  float2* xrow = xh + (size_t)b * T_N;
  for (int i = tid; i < T_N; i += NT) xrow[i] = d[pad(i)];
  fold_store8(d, phi, out + b * 64, tid);
}

// Order-1 full-size body (j1 < 8).
__device__ __forceinline__ void o1_full_body(v2f* d, int tid, int b, int j1,
    const float2* __restrict__ xh, const float* __restrict__ psi1,
    const float* __restrict__ phi, float2* __restrict__ u1h, float* __restrict__ out)
{
  const float2* xrow = xh + (size_t)b * T_N;
  const float* prow = psi1 + j1 * T_N;
  const float c = 5734.4f * exp2f(-0.125f * (float)j1);
  const int lo = max(0, (int)(0.36f * c));
  const int hi = min(T_N, (int)(1.64f * c) + 2);
#pragma unroll
  for (int s = 0; s < T_N/NT2; ++s) {
    int i = tid + s*NT2;
    v2f z; z.x = 0.f; z.y = 0.f;
    if (i >= lo && i < hi) {
      float2 v = xrow[i];
      float p = prow[i];
      z.x = v.x*p; z.y = v.y*p;
    }
    d[pad(i)] = z;
  }
  __syncthreads();
  const int k_lo = lo >> 10, k_hi = (hi + 1023) >> 10;
  const int K1 = pow2ceil16(k_hi - k_lo);
  const int k0 = min(k_lo, 16 - K1);
  stage1_dispatch(d, tid, k0, K1, 0, NT2);
  stage2_dispatch(d, tid, 0, 16);
  super_dif16<+1, 4, 2>(d, tid);     __syncthreads();
  fused_mid4(d, tid);                __syncthreads();
  super_dit16<-1, 4, 2>(d, tid);     __syncthreads();
  super_dit16<-1, 64, 6>(d, tid);    __syncthreads();
  super_dit16<-1, 1024, 10>(d, tid); __syncthreads();
  const int sb = SBTAB[j1 >> 3];
  float2* urow = u1h + (size_t)(b * N1 + j1) * USTRIDE;
  for (int i = tid; i < sb; i += NT2) {
    v2f u = d[pad(i)];
    urow[i] = make_float2(u.x, u.y);
  }
  fold_store16(d, phi, out + 1024 + (size_t)(b * N1 + j1) * 64, tid);
}

// Decimated order-1 body: demodulated band [lo,hi) at slots [0,W).
// RMAX=13: bins [0, 13*M1) >= sb for every class.
template<int LOGN>
__device__ __forceinline__ void o1_dec_body(v2f* sm, int sub, int t, int j1, int b,
    const float2* __restrict__ xh, const float* __restrict__ psi1,
    const float* __restrict__ phi, float2* __restrict__ u1h, float* __restrict__ out)
{
  constexpr int N = 1<<LOGN, SEGT = N/16;
  v2f* ds = sm + sub*N + ((sub*N)>>4);
  const float c = 5734.4f * exp2f(-0.125f*(float)j1);
  const int lo = max(0, (int)(0.36f*c));
  const int hi = min(T_N, (int)(1.64f*c)+2);
  const int W = hi - lo;
  const float2* xrow = xh + (size_t)b * T_N;
  const float* prow = psi1 + j1 * T_N;
#pragma unroll
  for (int s = 0; s < 16; ++s) {
    int f = t + s*SEGT;
    v2f z; z.x = 0.f; z.y = 0.f;
    if (f < W) { float2 xv = xrow[lo+f]; float p = prow[lo+f]; z.x = xv.x*p; z.y = xv.y*p; }
    ds[f + (f>>4)] = z;
  }
  __syncthreads();
  o2_body<LOGN, 13, false>(ds, t);
  const int sb = SBTAB[j1>>3];
  const float R = (float)(T_N >> LOGN);
  float2* urow = u1h + (size_t)(b*N1 + j1) * USTRIDE;
  for (int i = t; i < sb; i += SEGT) {
    v2f u = ds[i + (i>>4)];
    urow[i] = make_float2(R*u.x, R*u.y);
  }
  fold_generic<SEGT/64>(ds, phi, out + 1024 + (size_t)(b*N1 + j1)*64, t, 1.f/(float)N);
}

// K2a (order-1 heavy): q=0 full 16k pipelines. 8 per batch.
__global__ void __launch_bounds__(NT2, 4) k_o1h(const float2* __restrict__ xh, const float* __restrict__ psi1,
                                                const float* __restrict__ phi, float2* __restrict__ u1h,
                                                float* __restrict__ out)
{
  extern __shared__ char smem[];
  o1_full_body((v2f*)smem, threadIdx.x, blockIdx.x >> 3, blockIdx.x & 7, xh, psi1, phi, u1h, out);
}

// K2b (order-1 light): 512-thread blocks, 69.6KB LDS, 2 blocks/CU.
// 18 groups per batch, grp-major (heavy classes first):
// grp 0-7: q=1 N'=8192 (1 ppl/blk) | 8-11: q=2 4096 (2) | 12-13: q=3 2048 (4)
// | 14-17: q>=4 1024 (8).
__global__ void __launch_bounds__(NT, 4) k_o1l(const float2* __restrict__ xh, const float* __restrict__ psi1,
                                               const float* __restrict__ phi, float2* __restrict__ u1h,
                                               float* __restrict__ out)
{
  extern __shared__ char smem[];
  v2f* sm = (v2f*)smem;
  const int grp = blockIdx.x / B_SZ, b = blockIdx.x % B_SZ;
  if (grp < 8) {
    o1_dec_body<13>(sm, 0, threadIdx.x, 8 + grp, b, xh, psi1, phi, u1h, out);
  } else if (grp < 12) {
    const int sub = threadIdx.x >> 8;
    o1_dec_body<12>(sm, sub, threadIdx.x & 255, 16 + (grp-8)*2 + sub, b, xh, psi1, phi, u1h, out);
  } else if (grp < 14) {
    const int sub = threadIdx.x >> 7;
    o1_dec_body<11>(sm, sub, threadIdx.x & 127, 24 + (grp-12)*4 + sub, b, xh, psi1, phi, u1h, out);
  } else {
    const int sub = threadIdx.x >> 6;
    o1_dec_body<10>(sm, sub, threadIdx.x & 63, 32 + (grp-14)*8 + sub, b, xh, psi1, phi, u1h, out);
  }
}

// Order-2 full-size body (j2 = 1; j1 < 8).
__device__ __forceinline__ void o2_16k_body(v2f* d, int tid, int b, int j1,
    const float2* __restrict__ u1h, const float* __restrict__ psi2,
    const float* __restrict__ phi, float* __restrict__ out)
{
  const int W = WTAB[1];
  const float2* urow = u1h + (size_t)(b * N1 + j1) * USTRIDE;
  const float* prow = psi2 + 1 * T_N;
#pragma unroll
  for (int s = 0; s < T_N/NT2; ++s) {
    int i = tid + s*NT2;
    v2f z; z.x = 0.f; z.y = 0.f;
    if (i < W) {
      float2 u;
      if (i <= T_N/2) u = urow[i];
      else { float2 t = urow[T_N - i]; u = make_float2(t.x, -t.y); }
      float ps = prow[i];
      z.x = u.x*ps; z.y = u.y*ps;
    }
    d[pad(i)] = z;
  }
  __syncthreads();
  const int K1 = pow2ceil16((W + 1023) >> 10);
  stage1_dispatch(d, tid, 0, K1, 0, W);
  stage2_dispatch(d, tid, 0, 16);
  super_dif16<+1, 4, 2>(d, tid);      __syncthreads();
  fused_mid4(d, tid);                 __syncthreads();
  super_dit16<-1, 4, 2>(d, tid);      __syncthreads();
  super_dit16_m64_prune<-1>(d, tid);  __syncthreads();
  super_dit16_m1024_bin256<-1>(d, tid); __syncthreads();
  const int p = pair_index(j1, 1);
  fold_store16(d, phi, out + 66560 + (size_t)(b * NPAIR + p) * 64, tid);
}

// Decimated order-2 body (S2 fold only).
template<int LOGN>
__device__ __forceinline__ void o2_cls_body(v2f* sm, int sub, int t, int b, int j1, int j2,
    const float2* __restrict__ u1h, const float* __restrict__ psi2,
    const float* __restrict__ phi, float* __restrict__ out)
{
  constexpr int N = 1<<LOGN, SEGT = N/16;
  v2f* ds = sm + sub*N + ((sub*N)>>4);
  const int W = WTAB[j2 & 7];
  const float2* urow = u1h + (size_t)(b * N1 + j1) * USTRIDE;
  const float* prow = psi2 + j2 * T_N;
#pragma unroll
  for (int s = 0; s < 16; ++s) {
    int f = t + s*SEGT;
    v2f z; z.x = 0.f; z.y = 0.f;
    if (f < W) { float2 u = urow[f]; float ps = prow[f]; z.x = u.x*ps; z.y = u.y*ps; }
    ds[f + (f>>4)] = z;
  }
  __syncthreads();
  constexpr int RM = ((1<<(LOGN-4)) >= 256) ? 1 : (256 >> (LOGN-4));
  constexpr bool JL = ((1<<(LOGN-4)) > 256);
  o2_body<LOGN, RM, JL>(ds, t);
  const int p = pair_index(j1, j2);
  fold_generic<SEGT/64>(ds, phi, out + 66560 + (size_t)(b * NPAIR + p) * 64, t, 1.f/(float)N);
}

// K3a (order-2 heavy): j2=1 full 16k pipelines. 8 per batch.
__global__ void __launch_bounds__(NT2, 4) k_o2h(const float2* __restrict__ u1h, const float* __restrict__ psi2,
                                                const float* __restrict__ phi, float* __restrict__ out)
{
  extern __shared__ char smem[];
  o2_16k_body((v2f*)smem, threadIdx.x, blockIdx.x >> 3, blockIdx.x & 7, u1h, psi2, phi, out);
}

// K3b (order-2 light): 512-thread blocks, 69.6KB LDS, 2 blocks/CU.
// 54 groups per batch, grp-major (heavy classes first):
// grp 0-15: j2=2 N'=8192 (1 ppl/blk, j1=grp) | 16-27: j2=3 4096 (2)
// | 28-35: j2=4 2048 (4) | 36-40: j2=5 1024 (8) | 41-46: j2=6 1024 (8)
// | 47-53: j2=7 1024 (8).
__global__ void __launch_bounds__(NT, 4) k_o2l(const float2* __restrict__ u1h, const float* __restrict__ psi2,
                                               const float* __restrict__ phi, float* __restrict__ out)
{
  extern __shared__ char smem[];
  v2f* sm = (v2f*)smem;
  const int grp = blockIdx.x / B_SZ, b = blockIdx.x % B_SZ;
  if (grp < 16) {
    o2_cls_body<13>(sm, 0, threadIdx.x, b, grp, 2, u1h, psi2, phi, out);
  } else if (grp < 28) {
    const int sub = threadIdx.x >> 8;
    o2_cls_body<12>(sm, sub, threadIdx.x & 255, b, (grp-16)*2 + sub, 3, u1h, psi2, phi, out);
  } else if (grp < 36) {
    const int sub = threadIdx.x >> 7;
    o2_cls_body<11>(sm, sub, threadIdx.x & 127, b, (grp-28)*4 + sub, 4, u1h, psi2, phi, out);
  } else if (grp < 41) {
    const int sub = threadIdx.x >> 6;
    o2_cls_body<10>(sm, sub, threadIdx.x & 63, b, (grp-36)*8 + sub, 5, u1h, psi2, phi, out);
  } else if (grp < 47) {
    const int sub = threadIdx.x >> 6;
    o2_cls_body<10>(sm, sub, threadIdx.x & 63, b, (grp-41)*8 + sub, 6, u1h, psi2, phi, out);
  } else {
    const int sub = threadIdx.x >> 6;
    o2_cls_body<10>(sm, sub, threadIdx.x & 63, b, (grp-47)*8 + sub, 7, u1h, psi2, phi, out);
  }
}

extern "C" void kernel_launch(void* const* d_in, const int* in_sizes, int n_in,
                              void* d_out, int out_size, void* d_ws, size_t ws_size,
                              hipStream_t stream)
{
  const float* x    = (const float*)d_in[0];
  const float* psi1 = (const float*)d_in[1];
  const float* psi2 = (const float*)d_in[2];
  const float* phi  = (const float*)d_in[3];
  float* out = (float*)d_out;

  float2* xh  = (float2*)d_ws;
  float2* u1h = xh + (size_t)B_SZ * T_N;

  const size_t lds_h = (size_t)(T_N + (T_N >> 4)) * sizeof(float2);    // 139264 B
  const size_t lds_l = (size_t)(8192 + (8192 >> 4)) * sizeof(float2);  // 69632 B

  (void)hipFuncSetAttribute((const void*)k_fft_x, hipFuncAttributeMaxDynamicSharedMemorySize, (int)lds_h);
  (void)hipFuncSetAttribute((const void*)k_o1h,   hipFuncAttributeMaxDynamicSharedMemorySize, (int)lds_h);
  (void)hipFuncSetAttribute((const void*)k_o1l,   hipFuncAttributeMaxDynamicSharedMemorySize, (int)lds_l);
  (void)hipFuncSetAttribute((const void*)k_o2h,   hipFuncAttributeMaxDynamicSharedMemorySize, (int)lds_h);
  (void)hipFuncSetAttribute((const void*)k_o2l,   hipFuncAttributeMaxDynamicSharedMemorySize, (int)lds_l);

  hipLaunchKernelGGL(k_fft_x, dim3(B_SZ),      dim3(NT),  lds_h, stream, x, phi, xh, out);
  hipLaunchKernelGGL(k_o1h,   dim3(B_SZ * 8),  dim3(NT2), lds_h, stream, xh, psi1, phi, u1h, out);
  hipLaunchKernelGGL(k_o1l,   dim3(B_SZ * 18), dim3(NT),  lds_l, stream, xh, psi1, phi, u1h, out);
  hipLaunchKernelGGL(k_o2h,   dim3(B_SZ * 8),  dim3(NT2), lds_h, stream, u1h, psi2, phi, out);
  hipLaunchKernelGGL(k_o2l,   dim3(B_SZ * 54), dim3(NT),  lds_l, stream, u1h, psi2, phi, out);
}